// Round 5
// baseline (70138.617 us; speedup 1.0000x reference)
//
#include <hip/hip_runtime.h>
#include <hip/hip_cooperative_groups.h>

namespace cg = cooperative_groups;

#define BBAT 32
#define SE 200
#define TT 400
#define MM 80
#define EE 512
#define HH 1024
#define IN0 592
#define KT 1616
#define XSTR 1640      // inp row stride in bf16 elems
#define W1STR 1032
#define NBLK 256
#define NTHR 512

typedef __attribute__((ext_vector_type(4))) float f32x4;
typedef __attribute__((ext_vector_type(8))) short s16x8;

// LDS offsets (bytes)
#define OFF_W0    0          // 16*1640*2 = 52480
#define OFF_W1I   52480      // 16*1032*2 = 33024
#define OFF_W1H   85504      // 33024
#define OFF_GRED  118528     // 8*512 f32 = 16384
#define OFF_GSUM  134912     // 512 f32
#define OFF_GS1P  136960     // 512 f32
#define OFF_C0    139008     // 128 f32
#define OFF_C1    139520     // 128 f32
#define OFF_APOOL 140032     // smw 256 + red 64 + shC 512
#define LDS_TOTAL 143360

// ws offsets (bytes)
#define WS_H1F  275456
#define WS_ESC  406528
#define WS_BAR  432640       // 1200 x u32 one-shot barrier slots

__device__ __forceinline__ float sigmf(float x){ return 1.0f/(1.0f+expf(-x)); }

__device__ __forceinline__ unsigned short f2bf(float v){
  unsigned int u = __float_as_uint(v);
  u += 0x7fffu + ((u >> 16) & 1u);
  return (unsigned short)(u >> 16);
}

// Fast one-shot grid barrier. Slot must be pre-zeroed. All blocks resident
// (cooperative launch). Release: per-thread threadfence (drains each wave's
// stores + L2 writeback). Acquire: spin acquire-loads + threadfence.
__device__ __forceinline__ void gbar(unsigned* slot){
  __threadfence();
  __syncthreads();
  if (threadIdx.x == 0){
    unsigned prev = __hip_atomic_fetch_add(slot, 1u, __ATOMIC_ACQ_REL, __HIP_MEMORY_SCOPE_AGENT);
    if (prev != (unsigned)(NBLK-1)){
      while (__hip_atomic_load(slot, __ATOMIC_ACQUIRE, __HIP_MEMORY_SCOPE_AGENT) < (unsigned)NBLK)
        __builtin_amdgcn_s_sleep(1);
    }
    __threadfence();
  }
  __syncthreads();
}

__device__ __forceinline__ float bsum(float v, float* red){
  #pragma unroll
  for (int o = 32; o; o >>= 1) v += __shfl_down(v, o);
  __syncthreads();
  if ((threadIdx.x & 63) == 0) red[threadIdx.x >> 6] = v;
  __syncthreads();
  float s = 0.f;
  #pragma unroll
  for (int w2 = 0; w2 < 8; ++w2) s += red[w2];
  return s;
}
__device__ __forceinline__ float bmax(float v, float* red){
  #pragma unroll
  for (int o = 32; o; o >>= 1) v = fmaxf(v, __shfl_down(v, o));
  __syncthreads();
  if ((threadIdx.x & 63) == 0) red[threadIdx.x >> 6] = v;
  __syncthreads();
  float s = -3.4e38f;
  #pragma unroll
  for (int w2 = 0; w2 < 8; ++w2) s = fmaxf(s, red[w2]);
  return s;
}

// out[32b x 16r] = X(bf16 global)[32 x 32*NCH] @ W(bf16 LDS)[16 x 32*NCH]^T
template<int NCH>
__device__ __forceinline__ void gemm_mfma(
    const unsigned short* __restrict__ Wl, const int wstr,
    const unsigned short* __restrict__ Xg, const int xstr,
    float* __restrict__ Gred, float* __restrict__ gout)
{
  const int tid = threadIdx.x;
  const int w = tid >> 6, lane = tid & 63;
  const int row = lane & 15, kg = lane >> 4;
  f32x4 acc0 = {0.f,0.f,0.f,0.f}, acc1 = {0.f,0.f,0.f,0.f};
  const unsigned short* xp0 = Xg + (size_t)row * xstr + (kg << 3);
  const unsigned short* xp1 = xp0 + (size_t)16 * xstr;
  const unsigned short* wp  = Wl + row * wstr + (kg << 3);
  constexpr int NI = (NCH + 7) >> 3;
  #pragma unroll
  for (int i = 0; i < NI; ++i) {
    const int c = (i << 3) + w;
    if ((NCH & 7) == 0 || c < NCH) {
      s16x8 a0 = *(const s16x8*)(xp0 + (c << 5));
      s16x8 a1 = *(const s16x8*)(xp1 + (c << 5));
      s16x8 bw = *(const s16x8*)(wp  + (c << 5));
      acc0 = __builtin_amdgcn_mfma_f32_16x16x32_bf16(a0, bw, acc0, 0, 0, 0);
      acc1 = __builtin_amdgcn_mfma_f32_16x16x32_bf16(a1, bw, acc1, 0, 0, 0);
    }
  }
  float* gw = Gred + (w << 9) + row;
  #pragma unroll
  for (int v = 0; v < 4; ++v) {
    gw[((kg << 2) + v) << 4]        = acc0[v];
    gw[((kg << 2) + v + 16) << 4]   = acc1[v];
  }
  __syncthreads();
  float s = 0.f;
  #pragma unroll
  for (int w8 = 0; w8 < 8; ++w8) s += Gred[(w8 << 9) + tid];
  gout[tid] = s;
}

__global__ void __launch_bounds__(NTHR) decoder_kernel(
    const float* __restrict__ enc, const float* __restrict__ audio,
    const float* __restrict__ Wih0, const float* __restrict__ Whh0,
    const float* __restrict__ bih0, const float* __restrict__ bhh0,
    const float* __restrict__ Wih1, const float* __restrict__ Whh1,
    const float* __restrict__ bih1, const float* __restrict__ bhh1,
    const float* __restrict__ Wa, const float* __restrict__ ba,
    const float* __restrict__ Wfc, const float* __restrict__ bfc,
    float* __restrict__ out, float* __restrict__ ws)
{
  cg::grid_group grid = cg::this_grid();
  extern __shared__ char lds[];
  unsigned short* W0  = (unsigned short*)(lds + OFF_W0);
  unsigned short* W1I = (unsigned short*)(lds + OFF_W1I);
  unsigned short* W1H = (unsigned short*)(lds + OFF_W1H);
  float* Gred = (float*)(lds + OFF_GRED);
  float* Gsum = (float*)(lds + OFF_GSUM);
  float* Gs1p = (float*)(lds + OFF_GS1P);
  float* c0l  = (float*)(lds + OFF_C0);
  float* c1l  = (float*)(lds + OFF_C1);
  float* smw  = (float*)(lds + OFF_APOOL);
  float* red  = smw + 256;
  float* shC  = smw + 320;

  const int blk = blockIdx.x, tid = threadIdx.x;
  const int j = blk;

  unsigned short* inp = (unsigned short*)ws;        // 2 x [32][XSTR] bf16
  unsigned short* h1b = inp + 2*BBAT*XSTR;          // [32][1024] bf16
  float* h1f = (float*)((char*)ws + WS_H1F);        // [32][1024] f32
  float* esc = (float*)((char*)ws + WS_ESC);        // [32][200] f32
  unsigned* bar = (unsigned*)((char*)ws + WS_BAR);  // 1200 slots

  // ---- prologue ----
  for (int i = tid; i < 16*XSTR; i += NTHR) {
    int r = i / XSTR, k = i - r*XSTR;
    int n = (r & 3)*HH + 4*j + (r >> 2);
    float v = 0.f;
    if (k < IN0) v = Wih0[(size_t)n*IN0 + k];
    else if (k < KT) v = Whh0[(size_t)n*HH + (k - IN0)];
    W0[i] = f2bf(v);
  }
  for (int i = tid; i < 16*W1STR; i += NTHR) {
    int r = i / W1STR, k = i - r*W1STR;
    int n = (r & 3)*HH + 4*j + (r >> 2);
    W1I[i] = (k < HH) ? f2bf(Wih1[(size_t)n*HH + k]) : (unsigned short)0;
    W1H[i] = (k < HH) ? f2bf(Whh1[(size_t)n*HH + k]) : (unsigned short)0;
  }
  if (tid < 128) { c0l[tid] = 0.f; c1l[tid] = 0.f; }
  for (int i = blk*NTHR + tid; i < 2*BBAT*XSTR; i += NBLK*NTHR) inp[i] = 0;
  for (int i = blk*NTHR + tid; i < BBAT*HH; i += NBLK*NTHR) { h1b[i] = 0; h1f[i] = 0.f; }
  for (int i = blk*NTHR + tid; i < 3*TT; i += NBLK*NTHR) bar[i] = 0u;
  for (int row = blk; row < BBAT*SE; row += NBLK) {
    float pp = tanhf(enc[(size_t)row*EE + tid]) * Wa[HH + tid];   // EE == NTHR
    pp = bsum(pp, red);
    if (tid == 0) esc[row] = pp;
  }
  grid.sync();   // single heavyweight sync: covers bar zeroing + init

  int cur = 0;
  for (int t = 0; t < TT; ++t) {
    unsigned short* inpA = inp + cur*BBAT*XSTR;
    unsigned short* inpN = inp + (cur^1)*BBAT*XSTR;

    // ===== Phase A: Whh1@h1 partial (MFMA) + attention->ctx + FC pred(t-1) =====
    gemm_mfma<32>(W1H, W1STR, h1b, HH, Gred, Gs1p);
    {
      const int b = blk & 31, esl = blk >> 5;
      if (t > 0) {
        float pp = 0.f;
        for (int i2 = tid; i2 < HH; i2 += NTHR) pp += tanhf(h1f[b*HH + i2]) * Wa[i2];
        float sdot = bsum(pp, red) + ba[0];
        float sc = (tid < SE) ? esc[b*SE + tid] + sdot : -3.4e38f;
        float mx = bmax(sc, red);
        float ex = (tid < SE) ? expf(sc - mx) : 0.f;
        float den = bsum(ex, red);
        if (tid < SE) smw[tid] = ex / den;
      } else {
        if (tid < SE) smw[tid] = 1.0f / (float)SE;
      }
      __syncthreads();
      const int sg = tid >> 6, el = tid & 63;
      const int e = esl*64 + el;
      float a = 0.f;
      for (int s2 = sg*25; s2 < sg*25 + 25; ++s2)
        a = fmaf(smw[s2], enc[((size_t)b*SE + s2)*EE + e], a);
      shC[sg*64 + el] = a;
      __syncthreads();
      if (tid < 64) {
        float r8 = 0.f;
        #pragma unroll
        for (int s3 = 0; s3 < 8; ++s3) r8 += shC[s3*64 + tid];
        inpA[(size_t)b*XSTR + MM + esl*64 + tid] = f2bf(r8);
      }
      if (esl == 0 && tid < MM)
        inpA[(size_t)b*XSTR + tid] = f2bf(audio[((size_t)b*TT + t)*MM + tid]);
    }
    if (t > 0) {   // FC pred(t-1)
      const int w = tid >> 6, lane = tid & 63;
      for (int u = w; u < 10; u += 8) {
        int idx = j*10 + u;
        int b = idx / MM, m = idx - b*MM;
        float pp = 0.f;
        #pragma unroll
        for (int cq = 0; cq < 4; ++cq) {
          float4 hv = *(const float4*)(h1f + (size_t)b*HH + cq*256 + lane*4);
          float4 wv = *(const float4*)(Wfc + (size_t)m*HH + cq*256 + lane*4);
          pp = fmaf(hv.x,wv.x, fmaf(hv.y,wv.y, fmaf(hv.z,wv.z, fmaf(hv.w,wv.w, pp))));
        }
        #pragma unroll
        for (int o2 = 32; o2; o2 >>= 1) pp += __shfl_down(pp, o2);
        if (lane == 0) out[((size_t)b*TT + (t-1))*MM + m] = pp + bfc[m];
      }
    }
    gbar(bar + t*3 + 0);

    // ===== Phase B: LSTM0 =====
    gemm_mfma<51>(W0, XSTR, inpA, XSTR, Gred, Gsum);
    __syncthreads();
    if (tid < 128) {
      const int b = tid & 31, p = tid >> 5;
      const int o = (b << 4) + (p << 2);
      f32x4 gv = *(const f32x4*)(Gsum + o);
      const int nb = 4*j + p;
      float gi = gv[0] + bih0[nb]        + bhh0[nb];
      float gf = gv[1] + bih0[HH + nb]   + bhh0[HH + nb];
      float gg = gv[2] + bih0[2*HH + nb] + bhh0[2*HH + nb];
      float go = gv[3] + bih0[3*HH + nb] + bhh0[3*HH + nb];
      float cn = sigmf(gf) * c0l[p*32 + b] + sigmf(gi) * tanhf(gg);
      c0l[p*32 + b] = cn;
      inpN[(size_t)b*XSTR + IN0 + nb] = f2bf(sigmf(go) * tanhf(cn));
    }
    gbar(bar + t*3 + 1);

    // ===== Phase C: LSTM1 =====
    gemm_mfma<32>(W1I, W1STR, inpN + IN0, XSTR, Gred, Gsum);
    __syncthreads();
    if (tid < 128) {
      const int b = tid & 31, p = tid >> 5;
      const int o = (b << 4) + (p << 2);
      f32x4 gv = *(const f32x4*)(Gsum + o);
      f32x4 g1 = *(const f32x4*)(Gs1p + o);
      const int nb = 4*j + p;
      float gi = gv[0] + g1[0] + bih1[nb]        + bhh1[nb];
      float gf = gv[1] + g1[1] + bih1[HH + nb]   + bhh1[HH + nb];
      float gg = gv[2] + g1[2] + bih1[2*HH + nb] + bhh1[2*HH + nb];
      float go = gv[3] + g1[3] + bih1[3*HH + nb] + bhh1[3*HH + nb];
      float cn = sigmf(gf) * c1l[p*32 + b] + sigmf(gi) * tanhf(gg);
      c1l[p*32 + b] = cn;
      float hn = sigmf(go) * tanhf(cn);
      h1b[(size_t)b*HH + nb] = f2bf(hn);
      h1f[(size_t)b*HH + nb] = hn;
    }
    gbar(bar + t*3 + 2);
    cur ^= 1;
  }

  // ---- epilogue: FC pred for t = TT-1 ----
  {
    const int w = tid >> 6, lane = tid & 63;
    for (int u = w; u < 10; u += 8) {
      int idx = j*10 + u;
      int b = idx / MM, m = idx - b*MM;
      float pp = 0.f;
      #pragma unroll
      for (int cq = 0; cq < 4; ++cq) {
        float4 hv = *(const float4*)(h1f + (size_t)b*HH + cq*256 + lane*4);
        float4 wv = *(const float4*)(Wfc + (size_t)m*HH + cq*256 + lane*4);
        pp = fmaf(hv.x,wv.x, fmaf(hv.y,wv.y, fmaf(hv.z,wv.z, fmaf(hv.w,wv.w, pp))));
      }
      #pragma unroll
      for (int o2 = 32; o2; o2 >>= 1) pp += __shfl_down(pp, o2);
      if (lane == 0) out[((size_t)b*TT + (TT-1))*MM + m] = pp + bfc[m];
    }
  }
}

extern "C" void kernel_launch(void* const* d_in, const int* in_sizes, int n_in,
                              void* d_out, int out_size, void* d_ws, size_t ws_size,
                              hipStream_t stream) {
  const float* enc  = (const float*)d_in[0];
  const float* audio= (const float*)d_in[1];
  const float* Wih0 = (const float*)d_in[2];
  const float* Whh0 = (const float*)d_in[3];
  const float* bih0 = (const float*)d_in[4];
  const float* bhh0 = (const float*)d_in[5];
  const float* Wih1 = (const float*)d_in[6];
  const float* Whh1 = (const float*)d_in[7];
  const float* bih1 = (const float*)d_in[8];
  const float* bhh1 = (const float*)d_in[9];
  const float* Wa   = (const float*)d_in[10];
  const float* ba   = (const float*)d_in[11];
  const float* Wfc  = (const float*)d_in[12];
  const float* bfc  = (const float*)d_in[13];
  float* out = (float*)d_out;
  float* ws  = (float*)d_ws;

  (void)hipFuncSetAttribute((const void*)decoder_kernel,
                            hipFuncAttributeMaxDynamicSharedMemorySize, LDS_TOTAL);

  void* args[] = { &enc,&audio,&Wih0,&Whh0,&bih0,&bhh0,&Wih1,&Whh1,&bih1,&bhh1,
                   &Wa,&ba,&Wfc,&bfc,&out,&ws };
  hipLaunchCooperativeKernel((const void*)decoder_kernel, dim3(NBLK), dim3(NTHR),
                             args, LDS_TOTAL, stream);
}

// Round 6
// 16845.938 us; speedup vs baseline: 4.1635x; 4.1635x over previous
//
#include <hip/hip_runtime.h>
#include <hip/hip_cooperative_groups.h>

namespace cg = cooperative_groups;

#define BBAT 32
#define SE 200
#define TT 400
#define MM 80
#define EE 512
#define HH 1024
#define IN0 592
#define KT 1616
#define XSTR 1640      // inp row stride in bf16 elems (3280 B, 8B-aligned everywhere we st64)
#define W1STR 1032
#define NBLK 256
#define NTHR 512

typedef __attribute__((ext_vector_type(4))) float f32x4;
typedef __attribute__((ext_vector_type(8))) short s16x8;
typedef unsigned long long u64;

// LDS offsets (bytes)
#define OFF_W0    0          // 16*1640*2 = 52480
#define OFF_W1I   52480      // 16*1032*2 = 33024
#define OFF_W1H   85504      // 33024
#define OFF_GRED  118528     // 8*512 f32 = 16384
#define OFF_GSUM  134912     // 512 f32
#define OFF_GS1P  136960     // 512 f32
#define OFF_C0    139008     // 128 f32
#define OFF_C1    139520     // 128 f32
#define OFF_APOOL 140032     // smw 256 + red 64 + shC 512
#define LDS_TOTAL 143360

// ws offsets (bytes)
#define WS_H1F  275456
#define WS_ESC  406528
#define WS_BAR  432640       // 1200 x u32 one-shot barrier slots

__device__ __forceinline__ float sigmf(float x){ return 1.0f/(1.0f+expf(-x)); }

__device__ __forceinline__ unsigned short f2bf(float v){
  unsigned int u = __float_as_uint(v);
  u += 0x7fffu + ((u >> 16) & 1u);
  return (unsigned short)(u >> 16);
}

// ---- agent-scope coherent (L2-bypassing) accessors; RELAXED => no cache fences ----
__device__ __forceinline__ void st64a(void* p, u64 v){
  __hip_atomic_store((u64*)p, v, __ATOMIC_RELAXED, __HIP_MEMORY_SCOPE_AGENT);
}
__device__ __forceinline__ u64 ld64a(const void* p){
  return __hip_atomic_load((const u64*)p, __ATOMIC_RELAXED, __HIP_MEMORY_SCOPE_AGENT);
}
__device__ __forceinline__ float2 ld2f(const float* p){
  u64 q = ld64a(p);
  float2 r; r.x = __uint_as_float((unsigned)q); r.y = __uint_as_float((unsigned)(q >> 32));
  return r;
}
__device__ __forceinline__ s16x8 ldA(const unsigned short* p){
  union { u64 q[2]; s16x8 v; } u;
  u.q[0] = ld64a(p); u.q[1] = ld64a(p + 4);
  return u.v;
}
__device__ __forceinline__ u64 pk2f(float a, float b){
  return ((u64)__float_as_uint(b) << 32) | (u64)__float_as_uint(a);
}

// Fence-free one-shot grid barrier. Correctness: __syncthreads() drains every
// wave's vmcnt (sc1 write-through stores are then AT the coherence point);
// arrive/spin are relaxed agent atomics at the same coherence point.
__device__ __forceinline__ void gbar(unsigned* slot){
  __builtin_amdgcn_s_waitcnt(0);
  __syncthreads();
  if (threadIdx.x == 0){
    __hip_atomic_fetch_add(slot, 1u, __ATOMIC_RELAXED, __HIP_MEMORY_SCOPE_AGENT);
    while (__hip_atomic_load(slot, __ATOMIC_RELAXED, __HIP_MEMORY_SCOPE_AGENT) < (unsigned)NBLK)
      __builtin_amdgcn_s_sleep(1);
  }
  __syncthreads();
}

__device__ __forceinline__ float bsum(float v, float* red){
  #pragma unroll
  for (int o = 32; o; o >>= 1) v += __shfl_down(v, o);
  __syncthreads();
  if ((threadIdx.x & 63) == 0) red[threadIdx.x >> 6] = v;
  __syncthreads();
  float s = 0.f;
  #pragma unroll
  for (int w2 = 0; w2 < 8; ++w2) s += red[w2];
  return s;
}
__device__ __forceinline__ float bmax(float v, float* red){
  #pragma unroll
  for (int o = 32; o; o >>= 1) v = fmaxf(v, __shfl_down(v, o));
  __syncthreads();
  if ((threadIdx.x & 63) == 0) red[threadIdx.x >> 6] = v;
  __syncthreads();
  float s = -3.4e38f;
  #pragma unroll
  for (int w2 = 0; w2 < 8; ++w2) s = fmaxf(s, red[w2]);
  return s;
}

// out[32b x 16r] = X(bf16 global, sc1 loads)[32 x 32*NCH] @ W(bf16 LDS)[16 x 32*NCH]^T
template<int NCH>
__device__ __forceinline__ void gemm_mfma(
    const unsigned short* __restrict__ Wl, const int wstr,
    const unsigned short* __restrict__ Xg, const int xstr,
    float* __restrict__ Gred, float* __restrict__ gout)
{
  const int tid = threadIdx.x;
  const int w = tid >> 6, lane = tid & 63;
  const int row = lane & 15, kg = lane >> 4;
  f32x4 acc0 = {0.f,0.f,0.f,0.f}, acc1 = {0.f,0.f,0.f,0.f};
  const unsigned short* xp0 = Xg + (size_t)row * xstr + (kg << 3);
  const unsigned short* xp1 = xp0 + (size_t)16 * xstr;
  const unsigned short* wp  = Wl + row * wstr + (kg << 3);
  constexpr int NI = (NCH + 7) >> 3;
  #pragma unroll
  for (int i = 0; i < NI; ++i) {
    const int c = (i << 3) + w;
    if ((NCH & 7) == 0 || c < NCH) {
      s16x8 a0 = ldA(xp0 + (c << 5));
      s16x8 a1 = ldA(xp1 + (c << 5));
      s16x8 bw = *(const s16x8*)(wp  + (c << 5));
      acc0 = __builtin_amdgcn_mfma_f32_16x16x32_bf16(a0, bw, acc0, 0, 0, 0);
      acc1 = __builtin_amdgcn_mfma_f32_16x16x32_bf16(a1, bw, acc1, 0, 0, 0);
    }
  }
  float* gw = Gred + (w << 9) + row;
  #pragma unroll
  for (int v = 0; v < 4; ++v) {
    gw[((kg << 2) + v) << 4]        = acc0[v];
    gw[((kg << 2) + v + 16) << 4]   = acc1[v];
  }
  __syncthreads();
  float s = 0.f;
  #pragma unroll
  for (int w8 = 0; w8 < 8; ++w8) s += Gred[(w8 << 9) + tid];
  gout[tid] = s;   // Gsum[b*16 + 4p+g]; caller syncs before reading
}

__global__ void __launch_bounds__(NTHR) decoder_kernel(
    const float* __restrict__ enc, const float* __restrict__ audio,
    const float* __restrict__ Wih0, const float* __restrict__ Whh0,
    const float* __restrict__ bih0, const float* __restrict__ bhh0,
    const float* __restrict__ Wih1, const float* __restrict__ Whh1,
    const float* __restrict__ bih1, const float* __restrict__ bhh1,
    const float* __restrict__ Wa, const float* __restrict__ ba,
    const float* __restrict__ Wfc, const float* __restrict__ bfc,
    float* __restrict__ out, float* __restrict__ ws)
{
  cg::grid_group grid = cg::this_grid();
  extern __shared__ char lds[];
  unsigned short* W0  = (unsigned short*)(lds + OFF_W0);
  unsigned short* W1I = (unsigned short*)(lds + OFF_W1I);
  unsigned short* W1H = (unsigned short*)(lds + OFF_W1H);
  float* Gred = (float*)(lds + OFF_GRED);
  float* Gsum = (float*)(lds + OFF_GSUM);
  float* Gs1p = (float*)(lds + OFF_GS1P);
  float* c0l  = (float*)(lds + OFF_C0);
  float* c1l  = (float*)(lds + OFF_C1);
  float* smw  = (float*)(lds + OFF_APOOL);
  float* red  = smw + 256;
  float* shC  = smw + 320;

  const int blk = blockIdx.x, tid = threadIdx.x;
  const int j = blk;                                // owns h-columns [4j, 4j+4)

  unsigned short* inp = (unsigned short*)ws;        // 2 x [32][XSTR] bf16
  unsigned short* h1b = inp + 2*BBAT*XSTR;          // [32][1024] bf16
  float* h1f = (float*)((char*)ws + WS_H1F);        // [32][1024] f32
  float* esc = (float*)((char*)ws + WS_ESC);        // [32][200] f32
  unsigned* bar = (unsigned*)((char*)ws + WS_BAR);  // 1200 slots

  // ---- prologue (plain stores; made globally visible by the one cg sync) ----
  for (int i = tid; i < 16*XSTR; i += NTHR) {
    int r = i / XSTR, k = i - r*XSTR;
    int n = (r & 3)*HH + 4*j + (r >> 2);
    float v = 0.f;
    if (k < IN0) v = Wih0[(size_t)n*IN0 + k];
    else if (k < KT) v = Whh0[(size_t)n*HH + (k - IN0)];
    W0[i] = f2bf(v);
  }
  for (int i = tid; i < 16*W1STR; i += NTHR) {
    int r = i / W1STR, k = i - r*W1STR;
    int n = (r & 3)*HH + 4*j + (r >> 2);
    W1I[i] = (k < HH) ? f2bf(Wih1[(size_t)n*HH + k]) : (unsigned short)0;
    W1H[i] = (k < HH) ? f2bf(Whh1[(size_t)n*HH + k]) : (unsigned short)0;
  }
  if (tid < 128) { c0l[tid] = 0.f; c1l[tid] = 0.f; }
  for (int i = blk*NTHR + tid; i < 2*BBAT*XSTR; i += NBLK*NTHR) inp[i] = 0;
  for (int i = blk*NTHR + tid; i < BBAT*HH; i += NBLK*NTHR) { h1b[i] = 0; h1f[i] = 0.f; }
  for (int i = blk*NTHR + tid; i < 3*TT; i += NBLK*NTHR) bar[i] = 0u;
  for (int row = blk; row < BBAT*SE; row += NBLK) {
    float pp = tanhf(enc[(size_t)row*EE + tid]) * Wa[HH + tid];   // EE == NTHR
    pp = bsum(pp, red);
    if (tid == 0) esc[row] = pp;
  }
  grid.sync();   // single heavyweight sync (flushes prologue + barrier zeros)

  int cur = 0;
  for (int t = 0; t < TT; ++t) {
    unsigned short* inpA = inp + cur*BBAT*XSTR;
    unsigned short* inpN = inp + (cur^1)*BBAT*XSTR;

    // ===== Phase A: Whh1@h1 partial (MFMA) + attention->ctx + FC pred(t-1) =====
    gemm_mfma<32>(W1H, W1STR, h1b, HH, Gred, Gs1p);
    {
      const int b = blk & 31, esl = blk >> 5;
      if (t > 0) {
        float2 hv = ld2f(h1f + (size_t)b*HH + tid*2);
        float pp = tanhf(hv.x)*Wa[tid*2] + tanhf(hv.y)*Wa[tid*2 + 1];
        float sdot = bsum(pp, red) + ba[0];
        float sc = (tid < SE) ? esc[b*SE + tid] + sdot : -3.4e38f;
        float mx = bmax(sc, red);
        float ex = (tid < SE) ? expf(sc - mx) : 0.f;
        float den = bsum(ex, red);
        if (tid < SE) smw[tid] = ex / den;
      } else {
        if (tid < SE) smw[tid] = 1.0f / (float)SE;
      }
      __syncthreads();
      const int sg = tid >> 6, el = tid & 63;
      const int e = esl*64 + el;
      float a = 0.f;
      for (int s2 = sg*25; s2 < sg*25 + 25; ++s2)
        a = fmaf(smw[s2], enc[((size_t)b*SE + s2)*EE + e], a);
      shC[sg*64 + el] = a;
      __syncthreads();
      if (tid < 64) {
        float r8 = 0.f;
        #pragma unroll
        for (int s3 = 0; s3 < 8; ++s3) r8 += shC[s3*64 + tid];
        red[tid] = r8;
      }
      __syncthreads();
      if (tid < 16) {
        u64 cp = 0;
        #pragma unroll
        for (int q = 0; q < 4; ++q) cp |= (u64)f2bf(red[4*tid + q]) << (16*q);
        st64a(inpA + (size_t)b*XSTR + MM + esl*64 + 4*tid, cp);
      }
      if (esl == 0 && tid < 20) {
        u64 xp = 0;
        #pragma unroll
        for (int q = 0; q < 4; ++q)
          xp |= (u64)f2bf(audio[((size_t)b*TT + t)*MM + 4*tid + q]) << (16*q);
        st64a(inpA + (size_t)b*XSTR + 4*tid, xp);
      }
    }
    if (t > 0) {   // FC pred(t-1)
      const int w = tid >> 6, lane = tid & 63;
      for (int u = w; u < 10; u += 8) {
        int idx = j*10 + u;
        int b = idx / MM, m = idx - b*MM;
        float pp = 0.f;
        #pragma unroll
        for (int cq = 0; cq < 4; ++cq) {
          float2 h0v = ld2f(h1f + (size_t)b*HH + cq*256 + lane*4);
          float2 h1v = ld2f(h1f + (size_t)b*HH + cq*256 + lane*4 + 2);
          float4 wv = *(const float4*)(Wfc + (size_t)m*HH + cq*256 + lane*4);
          pp = fmaf(h0v.x,wv.x, fmaf(h0v.y,wv.y, fmaf(h1v.x,wv.z, fmaf(h1v.y,wv.w, pp))));
        }
        #pragma unroll
        for (int o2 = 32; o2; o2 >>= 1) pp += __shfl_down(pp, o2);
        if (lane == 0) out[((size_t)b*TT + (t-1))*MM + m] = pp + bfc[m];
      }
    }
    gbar(bar + t*3 + 0);

    // ===== Phase B: LSTM0 =====
    gemm_mfma<51>(W0, XSTR, inpA, XSTR, Gred, Gsum);
    __syncthreads();
    if (tid < BBAT) {
      const int b = tid;
      u64 hp = 0;
      #pragma unroll
      for (int p = 0; p < 4; ++p) {
        f32x4 gv = *(const f32x4*)(Gsum + (b << 4) + (p << 2));
        const int nb = 4*j + p;
        float gi = gv[0] + bih0[nb]        + bhh0[nb];
        float gf = gv[1] + bih0[HH + nb]   + bhh0[HH + nb];
        float gg = gv[2] + bih0[2*HH + nb] + bhh0[2*HH + nb];
        float go = gv[3] + bih0[3*HH + nb] + bhh0[3*HH + nb];
        float cn = sigmf(gf) * c0l[p*32 + b] + sigmf(gi) * tanhf(gg);
        c0l[p*32 + b] = cn;
        hp |= (u64)f2bf(sigmf(go) * tanhf(cn)) << (16*p);
      }
      st64a(inpN + (size_t)b*XSTR + IN0 + 4*j, hp);
    }
    gbar(bar + t*3 + 1);

    // ===== Phase C: LSTM1 =====
    gemm_mfma<32>(W1I, W1STR, inpN + IN0, XSTR, Gred, Gsum);
    __syncthreads();
    if (tid < BBAT) {
      const int b = tid;
      u64 hp = 0;
      float hf[4];
      #pragma unroll
      for (int p = 0; p < 4; ++p) {
        f32x4 gv = *(const f32x4*)(Gsum + (b << 4) + (p << 2));
        f32x4 g1 = *(const f32x4*)(Gs1p + (b << 4) + (p << 2));
        const int nb = 4*j + p;
        float gi = gv[0] + g1[0] + bih1[nb]        + bhh1[nb];
        float gf = gv[1] + g1[1] + bih1[HH + nb]   + bhh1[HH + nb];
        float gg = gv[2] + g1[2] + bih1[2*HH + nb] + bhh1[2*HH + nb];
        float go = gv[3] + g1[3] + bih1[3*HH + nb] + bhh1[3*HH + nb];
        float cn = sigmf(gf) * c1l[p*32 + b] + sigmf(gi) * tanhf(gg);
        c1l[p*32 + b] = cn;
        float hn = sigmf(go) * tanhf(cn);
        hf[p] = hn;
        hp |= (u64)f2bf(hn) << (16*p);
      }
      st64a(h1b + (size_t)b*HH + 4*j, hp);
      st64a(h1f + (size_t)b*HH + 4*j,     pk2f(hf[0], hf[1]));
      st64a(h1f + (size_t)b*HH + 4*j + 2, pk2f(hf[2], hf[3]));
    }
    gbar(bar + t*3 + 2);
    cur ^= 1;
  }

  // ---- epilogue: FC pred for t = TT-1 ----
  {
    const int w = tid >> 6, lane = tid & 63;
    for (int u = w; u < 10; u += 8) {
      int idx = j*10 + u;
      int b = idx / MM, m = idx - b*MM;
      float pp = 0.f;
      #pragma unroll
      for (int cq = 0; cq < 4; ++cq) {
        float2 h0v = ld2f(h1f + (size_t)b*HH + cq*256 + lane*4);
        float2 h1v = ld2f(h1f + (size_t)b*HH + cq*256 + lane*4 + 2);
        float4 wv = *(const float4*)(Wfc + (size_t)m*HH + cq*256 + lane*4);
        pp = fmaf(h0v.x,wv.x, fmaf(h0v.y,wv.y, fmaf(h1v.x,wv.z, fmaf(h1v.y,wv.w, pp))));
      }
      #pragma unroll
      for (int o2 = 32; o2; o2 >>= 1) pp += __shfl_down(pp, o2);
      if (lane == 0) out[((size_t)b*TT + (TT-1))*MM + m] = pp + bfc[m];
    }
  }
}

extern "C" void kernel_launch(void* const* d_in, const int* in_sizes, int n_in,
                              void* d_out, int out_size, void* d_ws, size_t ws_size,
                              hipStream_t stream) {
  const float* enc  = (const float*)d_in[0];
  const float* audio= (const float*)d_in[1];
  const float* Wih0 = (const float*)d_in[2];
  const float* Whh0 = (const float*)d_in[3];
  const float* bih0 = (const float*)d_in[4];
  const float* bhh0 = (const float*)d_in[5];
  const float* Wih1 = (const float*)d_in[6];
  const float* Whh1 = (const float*)d_in[7];
  const float* bih1 = (const float*)d_in[8];
  const float* bhh1 = (const float*)d_in[9];
  const float* Wa   = (const float*)d_in[10];
  const float* ba   = (const float*)d_in[11];
  const float* Wfc  = (const float*)d_in[12];
  const float* bfc  = (const float*)d_in[13];
  float* out = (float*)d_out;
  float* ws  = (float*)d_ws;

  (void)hipFuncSetAttribute((const void*)decoder_kernel,
                            hipFuncAttributeMaxDynamicSharedMemorySize, LDS_TOTAL);

  void* args[] = { &enc,&audio,&Wih0,&Whh0,&bih0,&bhh0,&Wih1,&Whh1,&bih1,&bhh1,
                   &Wa,&ba,&Wfc,&bfc,&out,&ws };
  hipLaunchCooperativeKernel((const void*)decoder_kernel, dim3(NBLK), dim3(NTHR),
                             args, LDS_TOTAL, stream);
}

// Round 8
// 13198.193 us; speedup vs baseline: 5.3143x; 1.2764x over previous
//
#include <hip/hip_runtime.h>
#include <hip/hip_cooperative_groups.h>

namespace cg = cooperative_groups;

#define BBAT 32
#define SE 200
#define TT 400
#define MM 80
#define EE 512
#define HH 1024
#define IN0 592
#define KT 1616
#define XSTR 1640      // inp row stride in bf16 elems (3280 B)
#define W1STR 1032
#define NBLK 256
#define NTHR 512

// barrier tree: 16 groups x 16 blocks, 17 padded slots (16 u32 each) per barrier
#define NGRP 16
#define GSZ  16
#define BSLOTS 272     // 17*16 u32 per barrier instance

typedef __attribute__((ext_vector_type(4))) float f32x4;
typedef __attribute__((ext_vector_type(8))) short s16x8;
typedef unsigned long long u64;

// LDS offsets (bytes)
#define OFF_W0    0          // 16*1640*2 = 52480
#define OFF_W1I   52480      // 16*1032*2 = 33024
#define OFF_W1H   85504      // 33024
#define OFF_GRED  118528     // 8*512 f32 = 16384
#define OFF_GSUM  134912     // 512 f32
#define OFF_GS1P  136960     // 512 f32
#define OFF_C0    139008     // 128 f32
#define OFF_C1    139520     // 128 f32
#define OFF_APOOL 140032     // smw 256 + red 64 + shC 512
#define LDS_TOTAL 143360

// ws offsets (bytes)
#define WS_H1F   275456
#define WS_ESC   406528
#define WS_BAR   432640      // 1200 barriers x 272 u32 = 1,305,600 B

__device__ __forceinline__ float sigmf(float x){ return 1.0f/(1.0f+expf(-x)); }

__device__ __forceinline__ unsigned short f2bf(float v){
  unsigned int u = __float_as_uint(v);
  u += 0x7fffu + ((u >> 16) & 1u);
  return (unsigned short)(u >> 16);
}

// ---- agent-scope coherent accessors; RELAXED => no cache-maintenance ops ----
__device__ __forceinline__ void st64a(void* p, u64 v){
  __hip_atomic_store((u64*)p, v, __ATOMIC_RELAXED, __HIP_MEMORY_SCOPE_AGENT);
}
__device__ __forceinline__ u64 ld64a(const void* p){
  return __hip_atomic_load((const u64*)p, __ATOMIC_RELAXED, __HIP_MEMORY_SCOPE_AGENT);
}
__device__ __forceinline__ float2 ld2f(const float* p){
  u64 q = ld64a(p);
  float2 r; r.x = __uint_as_float((unsigned)q); r.y = __uint_as_float((unsigned)(q >> 32));
  return r;
}
__device__ __forceinline__ s16x8 ldA(const unsigned short* p){
  union { u64 q[2]; s16x8 v; } u;
  u.q[0] = ld64a(p); u.q[1] = ld64a(p + 4);
  return u.v;
}
__device__ __forceinline__ u64 pk2f(float a, float b){
  return ((u64)__float_as_uint(b) << 32) | (u64)__float_as_uint(a);
}

// One-shot tree grid barrier (R6-proven RMW mechanism, tree-structured).
// slots: [g*16] for g<16 = group counters, [16*16] = root. All pre-zeroed.
// Visibility: s_waitcnt(0)+syncthreads drains every wave's sc1 write-through
// stores to the coherence point BEFORE the arrive-RMW issues; root==NGRP
// implies all 256 arrive-RMWs executed, hence all data globally readable.
__device__ __forceinline__ void gbar(unsigned* slots){
  __builtin_amdgcn_s_waitcnt(0);
  __syncthreads();
  if (threadIdx.x == 0){
    const unsigned g = blockIdx.x >> 4;
    unsigned prev = __hip_atomic_fetch_add(slots + g*16, 1u, __ATOMIC_RELAXED, __HIP_MEMORY_SCOPE_AGENT);
    if (prev == (unsigned)(GSZ-1))
      __hip_atomic_fetch_add(slots + NGRP*16, 1u, __ATOMIC_RELAXED, __HIP_MEMORY_SCOPE_AGENT);
    while (__hip_atomic_load(slots + NGRP*16, __ATOMIC_RELAXED, __HIP_MEMORY_SCOPE_AGENT) < (unsigned)NGRP)
      __builtin_amdgcn_s_sleep(1);
  }
  __syncthreads();
}

__device__ __forceinline__ float bsum(float v, float* red){
  #pragma unroll
  for (int o = 32; o; o >>= 1) v += __shfl_down(v, o);
  __syncthreads();
  if ((threadIdx.x & 63) == 0) red[threadIdx.x >> 6] = v;
  __syncthreads();
  float s = 0.f;
  #pragma unroll
  for (int w2 = 0; w2 < 8; ++w2) s += red[w2];
  return s;
}
__device__ __forceinline__ float bmax(float v, float* red){
  #pragma unroll
  for (int o = 32; o; o >>= 1) v = fmaxf(v, __shfl_down(v, o));
  __syncthreads();
  if ((threadIdx.x & 63) == 0) red[threadIdx.x >> 6] = v;
  __syncthreads();
  float s = -3.4e38f;
  #pragma unroll
  for (int w2 = 0; w2 < 8; ++w2) s = fmaxf(s, red[w2]);
  return s;
}

// out[32b x 16r] = X(bf16, fine-grained)[32 x 32*NCH] @ W(bf16 LDS)[16 x 32*NCH]^T
// Two-pass: batch-issue ALL A-frag loads (static reg arrays), then MFMA.
template<int NCH>
__device__ __forceinline__ void gemm_mfma(
    const unsigned short* __restrict__ Wl, const int wstr,
    const unsigned short* __restrict__ Xg, const int xstr,
    float* __restrict__ Gred, float* __restrict__ gout)
{
  const int tid = threadIdx.x;
  const int w = tid >> 6, lane = tid & 63;
  const int row = lane & 15, kg = lane >> 4;
  f32x4 acc0 = {0.f,0.f,0.f,0.f}, acc1 = {0.f,0.f,0.f,0.f};
  const unsigned short* xp0 = Xg + (size_t)row * xstr + (kg << 3);
  const unsigned short* xp1 = xp0 + (size_t)16 * xstr;
  const unsigned short* wp  = Wl + row * wstr + (kg << 3);
  constexpr int NI = (NCH + 7) >> 3;
  s16x8 a0[NI], a1[NI];
  #pragma unroll
  for (int i = 0; i < NI; ++i) {
    const int c = (i << 3) + w;
    if ((NCH & 7) == 0 || c < NCH) {
      a0[i] = ldA(xp0 + (c << 5));
      a1[i] = ldA(xp1 + (c << 5));
    }
  }
  #pragma unroll
  for (int i = 0; i < NI; ++i) {
    const int c = (i << 3) + w;
    if ((NCH & 7) == 0 || c < NCH) {
      s16x8 bw = *(const s16x8*)(wp + (c << 5));
      acc0 = __builtin_amdgcn_mfma_f32_16x16x32_bf16(a0[i], bw, acc0, 0, 0, 0);
      acc1 = __builtin_amdgcn_mfma_f32_16x16x32_bf16(a1[i], bw, acc1, 0, 0, 0);
    }
  }
  float* gw = Gred + (w << 9) + row;
  #pragma unroll
  for (int v = 0; v < 4; ++v) {
    gw[((kg << 2) + v) << 4]        = acc0[v];
    gw[((kg << 2) + v + 16) << 4]   = acc1[v];
  }
  __syncthreads();
  float s = 0.f;
  #pragma unroll
  for (int w8 = 0; w8 < 8; ++w8) s += Gred[(w8 << 9) + tid];
  gout[tid] = s;   // caller syncs before reading
}

__global__ void __launch_bounds__(NTHR, 2) decoder_kernel(
    const float* __restrict__ enc, const float* __restrict__ audio,
    const float* __restrict__ Wih0, const float* __restrict__ Whh0,
    const float* __restrict__ bih0, const float* __restrict__ bhh0,
    const float* __restrict__ Wih1, const float* __restrict__ Whh1,
    const float* __restrict__ bih1, const float* __restrict__ bhh1,
    const float* __restrict__ Wa, const float* __restrict__ ba,
    const float* __restrict__ Wfc, const float* __restrict__ bfc,
    float* __restrict__ out, float* __restrict__ ws)
{
  cg::grid_group grid = cg::this_grid();
  extern __shared__ char lds[];
  unsigned short* W0  = (unsigned short*)(lds + OFF_W0);
  unsigned short* W1I = (unsigned short*)(lds + OFF_W1I);
  unsigned short* W1H = (unsigned short*)(lds + OFF_W1H);
  float* Gred = (float*)(lds + OFF_GRED);
  float* Gsum = (float*)(lds + OFF_GSUM);
  float* Gs1p = (float*)(lds + OFF_GS1P);
  float* c0l  = (float*)(lds + OFF_C0);
  float* c1l  = (float*)(lds + OFF_C1);
  float* smw  = (float*)(lds + OFF_APOOL);
  float* red  = smw + 256;
  float* shC  = smw + 320;

  const int blk = blockIdx.x, tid = threadIdx.x;
  const int j = blk;                                // owns h-columns [4j, 4j+4)

  unsigned short* inp = (unsigned short*)ws;        // 2 x [32][XSTR] bf16
  unsigned short* h1b = inp + 2*BBAT*XSTR;          // [32][1024] bf16
  float* h1f = (float*)((char*)ws + WS_H1F);        // [32][1024] f32
  float* esc = (float*)((char*)ws + WS_ESC);        // [32][200] f32
  unsigned* bars = (unsigned*)((char*)ws + WS_BAR); // 1200 x 272 u32

  // ---- prologue (plain stores; flushed by the one cg grid.sync) ----
  for (int i = tid; i < 16*XSTR; i += NTHR) {
    int r = i / XSTR, k = i - r*XSTR;
    int n = (r & 3)*HH + 4*j + (r >> 2);
    float v = 0.f;
    if (k < IN0) v = Wih0[(size_t)n*IN0 + k];
    else if (k < KT) v = Whh0[(size_t)n*HH + (k - IN0)];
    W0[i] = f2bf(v);
  }
  for (int i = tid; i < 16*W1STR; i += NTHR) {
    int r = i / W1STR, k = i - r*W1STR;
    int n = (r & 3)*HH + 4*j + (r >> 2);
    W1I[i] = (k < HH) ? f2bf(Wih1[(size_t)n*HH + k]) : (unsigned short)0;
    W1H[i] = (k < HH) ? f2bf(Whh1[(size_t)n*HH + k]) : (unsigned short)0;
  }
  if (tid < 128) { c0l[tid] = 0.f; c1l[tid] = 0.f; }
  for (int i = blk*NTHR + tid; i < 2*BBAT*XSTR; i += NBLK*NTHR) inp[i] = 0;
  for (int i = blk*NTHR + tid; i < BBAT*HH; i += NBLK*NTHR) { h1b[i] = 0; h1f[i] = 0.f; }
  for (int i = blk*NTHR + tid; i < 3*TT*BSLOTS; i += NBLK*NTHR) bars[i] = 0u;
  for (int row = blk; row < BBAT*SE; row += NBLK) {
    float pp = tanhf(enc[(size_t)row*EE + tid]) * Wa[HH + tid];   // EE == NTHR
    pp = bsum(pp, red);
    if (tid == 0) esc[row] = pp;
  }
  grid.sync();   // single heavyweight sync (flushes prologue + barrier zeros)

  int cur = 0;
  for (int t = 0; t < TT; ++t) {
    unsigned short* inpA = inp + cur*BBAT*XSTR;
    unsigned short* inpN = inp + (cur^1)*BBAT*XSTR;

    // ===== Phase A: attention -> ctx + audio pack + FC pred(t-1) =====
    {
      const int b = blk & 31, esl = blk >> 5;
      if (t > 0) {
        float2 hv = ld2f(h1f + (size_t)b*HH + tid*2);
        float pp = tanhf(hv.x)*Wa[tid*2] + tanhf(hv.y)*Wa[tid*2 + 1];
        float sdot = bsum(pp, red) + ba[0];
        float sc = (tid < SE) ? esc[b*SE + tid] + sdot : -3.4e38f;
        float mx = bmax(sc, red);
        float ex = (tid < SE) ? expf(sc - mx) : 0.f;
        float den = bsum(ex, red);
        if (tid < SE) smw[tid] = ex / den;
      } else {
        if (tid < SE) smw[tid] = 1.0f / (float)SE;
      }
      __syncthreads();
      const int sg = tid >> 6, el = tid & 63;
      const int e = esl*64 + el;
      float a = 0.f;
      for (int s2 = sg*25; s2 < sg*25 + 25; ++s2)
        a = fmaf(smw[s2], enc[((size_t)b*SE + s2)*EE + e], a);
      shC[sg*64 + el] = a;
      __syncthreads();
      if (tid < 64) {
        float r8 = 0.f;
        #pragma unroll
        for (int s3 = 0; s3 < 8; ++s3) r8 += shC[s3*64 + tid];
        red[tid] = r8;
      }
      __syncthreads();
      if (tid < 16) {
        u64 cp = 0;
        #pragma unroll
        for (int q = 0; q < 4; ++q) cp |= (u64)f2bf(red[4*tid + q]) << (16*q);
        st64a(inpA + (size_t)b*XSTR + MM + esl*64 + 4*tid, cp);
      }
      if (esl == 0 && tid < 20) {
        u64 xp = 0;
        #pragma unroll
        for (int q = 0; q < 4; ++q)
          xp |= (u64)f2bf(audio[((size_t)b*TT + t)*MM + 4*tid + q]) << (16*q);
        st64a(inpA + (size_t)b*XSTR + 4*tid, xp);
      }
    }
    if (t > 0) {   // FC pred(t-1)
      const int w = tid >> 6, lane = tid & 63;
      for (int u = w; u < 10; u += 8) {
        int idx = j*10 + u;
        int b = idx / MM, m = idx - b*MM;
        float pp = 0.f;
        #pragma unroll
        for (int cq = 0; cq < 4; ++cq) {
          float2 h0v = ld2f(h1f + (size_t)b*HH + cq*256 + lane*4);
          float2 h1v = ld2f(h1f + (size_t)b*HH + cq*256 + lane*4 + 2);
          float4 wv = *(const float4*)(Wfc + (size_t)m*HH + cq*256 + lane*4);
          pp = fmaf(h0v.x,wv.x, fmaf(h0v.y,wv.y, fmaf(h1v.x,wv.z, fmaf(h1v.y,wv.w, pp))));
        }
        #pragma unroll
        for (int o2 = 32; o2; o2 >>= 1) pp += __shfl_down(pp, o2);
        if (lane == 0) out[((size_t)b*TT + (t-1))*MM + m] = pp + bfc[m];
      }
    }
    gbar(bars + (3*t + 0)*BSLOTS);

    // ===== Phase B: LSTM0 gemm + epilogue, then Whh1@h1 partial =====
    gemm_mfma<51>(W0, XSTR, inpA, XSTR, Gred, Gsum);
    __syncthreads();
    if (tid < BBAT) {
      const int b = tid;
      u64 hp = 0;
      #pragma unroll
      for (int p = 0; p < 4; ++p) {
        f32x4 gv = *(const f32x4*)(Gsum + (b << 4) + (p << 2));
        const int nb = 4*j + p;
        float gi = gv[0] + bih0[nb]        + bhh0[nb];
        float gf = gv[1] + bih0[HH + nb]   + bhh0[HH + nb];
        float gg = gv[2] + bih0[2*HH + nb] + bhh0[2*HH + nb];
        float go = gv[3] + bih0[3*HH + nb] + bhh0[3*HH + nb];
        float cn = sigmf(gf) * c0l[p*32 + b] + sigmf(gi) * tanhf(gg);
        c0l[p*32 + b] = cn;
        hp |= (u64)f2bf(sigmf(go) * tanhf(cn)) << (16*p);
      }
      st64a(inpN + (size_t)b*XSTR + IN0 + 4*j, hp);
    }
    __syncthreads();   // Gsum consumed + Gred free before next gemm reuses it
    gemm_mfma<32>(W1H, W1STR, h1b, HH, Gred, Gs1p);   // h1(t-1) partial, used in C
    gbar(bars + (3*t + 1)*BSLOTS);

    // ===== Phase C: LSTM1 =====
    gemm_mfma<32>(W1I, W1STR, inpN + IN0, XSTR, Gred, Gsum);
    __syncthreads();
    if (tid < BBAT) {
      const int b = tid;
      u64 hp = 0;
      float hf[4];
      #pragma unroll
      for (int p = 0; p < 4; ++p) {
        f32x4 gv = *(const f32x4*)(Gsum + (b << 4) + (p << 2));
        f32x4 g1 = *(const f32x4*)(Gs1p + (b << 4) + (p << 2));
        const int nb = 4*j + p;
        float gi = gv[0] + g1[0] + bih1[nb]        + bhh1[nb];
        float gf = gv[1] + g1[1] + bih1[HH + nb]   + bhh1[HH + nb];
        float gg = gv[2] + g1[2] + bih1[2*HH + nb] + bhh1[2*HH + nb];
        float go = gv[3] + g1[3] + bih1[3*HH + nb] + bhh1[3*HH + nb];
        float cn = sigmf(gf) * c1l[p*32 + b] + sigmf(gi) * tanhf(gg);
        c1l[p*32 + b] = cn;
        float hn = sigmf(go) * tanhf(cn);
        hf[p] = hn;
        hp |= (u64)f2bf(hn) << (16*p);
      }
      st64a(h1b + (size_t)b*HH + 4*j, hp);
      st64a(h1f + (size_t)b*HH + 4*j,     pk2f(hf[0], hf[1]));
      st64a(h1f + (size_t)b*HH + 4*j + 2, pk2f(hf[2], hf[3]));
    }
    gbar(bars + (3*t + 2)*BSLOTS);
    cur ^= 1;
  }

  // ---- epilogue: FC pred for t = TT-1 ----
  {
    const int w = tid >> 6, lane = tid & 63;
    for (int u = w; u < 10; u += 8) {
      int idx = j*10 + u;
      int b = idx / MM, m = idx - b*MM;
      float pp = 0.f;
      #pragma unroll
      for (int cq = 0; cq < 4; ++cq) {
        float2 h0v = ld2f(h1f + (size_t)b*HH + cq*256 + lane*4);
        float2 h1v = ld2f(h1f + (size_t)b*HH + cq*256 + lane*4 + 2);
        float4 wv = *(const float4*)(Wfc + (size_t)m*HH + cq*256 + lane*4);
        pp = fmaf(h0v.x,wv.x, fmaf(h0v.y,wv.y, fmaf(h1v.x,wv.z, fmaf(h1v.y,wv.w, pp))));
      }
      #pragma unroll
      for (int o2 = 32; o2; o2 >>= 1) pp += __shfl_down(pp, o2);
      if (lane == 0) out[((size_t)b*TT + (TT-1))*MM + m] = pp + bfc[m];
    }
  }
}

extern "C" void kernel_launch(void* const* d_in, const int* in_sizes, int n_in,
                              void* d_out, int out_size, void* d_ws, size_t ws_size,
                              hipStream_t stream) {
  const float* enc  = (const float*)d_in[0];
  const float* audio= (const float*)d_in[1];
  const float* Wih0 = (const float*)d_in[2];
  const float* Whh0 = (const float*)d_in[3];
  const float* bih0 = (const float*)d_in[4];
  const float* bhh0 = (const float*)d_in[5];
  const float* Wih1 = (const float*)d_in[6];
  const float* Whh1 = (const float*)d_in[7];
  const float* bih1 = (const float*)d_in[8];
  const float* bhh1 = (const float*)d_in[9];
  const float* Wa   = (const float*)d_in[10];
  const float* ba   = (const float*)d_in[11];
  const float* Wfc  = (const float*)d_in[12];
  const float* bfc  = (const float*)d_in[13];
  float* out = (float*)d_out;
  float* ws  = (float*)d_ws;

  (void)hipFuncSetAttribute((const void*)decoder_kernel,
                            hipFuncAttributeMaxDynamicSharedMemorySize, LDS_TOTAL);

  void* args[] = { &enc,&audio,&Wih0,&Whh0,&bih0,&bhh0,&Wih1,&Whh1,&bih1,&bhh1,
                   &Wa,&ba,&Wfc,&bfc,&out,&ws };
  hipLaunchCooperativeKernel((const void*)decoder_kernel, dim3(NBLK), dim3(NTHR),
                             args, LDS_TOTAL, stream);
}

// Round 9
// 10668.444 us; speedup vs baseline: 6.5744x; 1.2371x over previous
//
#include <hip/hip_runtime.h>
#include <hip/hip_cooperative_groups.h>

namespace cg = cooperative_groups;

#define BBAT 32
#define SE 200
#define TT 400
#define MM 80
#define EE 512
#define HH 1024
#define IN0 592
#define KT 1616
#define XSTR 1640      // inp row stride in bf16 elems (3280 B)
#define W1STR 1032
#define NBLK 256
#define NTHR 512

// barrier tree: 16 groups x 16 blocks, 17 padded slots (16 u32 each)
#define NGRP 16
#define GSZ  16
#define BSLOTS 272

typedef __attribute__((ext_vector_type(4))) float f32x4;
typedef __attribute__((ext_vector_type(8))) short s16x8;
typedef unsigned long long u64;

// LDS offsets (bytes)
#define OFF_W0    0          // 16*1640*2 = 52480
#define OFF_W1I   52480      // 33024
#define OFF_W1H   85504      // 33024
#define OFF_GRED  118528     // 16384
#define OFF_GSUM  134912     // 2048
#define OFF_GS1P  136960     // 2048
#define OFF_C0    139008     // 512
#define OFF_C1    139520     // 512
#define OFF_APOOL 140032     // smw 256 + red 64 + shC 512 f32
#define LDS_TOTAL 143360

// ws offsets (bytes)
#define WS_H1B   209920      // 2 x [32][1024] bf16 (t-parity double buffer)
#define WS_H1F   340992      // [32][1024] f32
#define WS_ESC   472064      // [32][200] f32
#define WS_PAR   497664      // [32][256] f32 score partials
#define WS_BAR   530432      // 1200 x 272 u32

__device__ __forceinline__ float sigmf(float x){ return 1.0f/(1.0f+expf(-x)); }

__device__ __forceinline__ unsigned short f2bf(float v){
  unsigned int u = __float_as_uint(v);
  u += 0x7fffu + ((u >> 16) & 1u);
  return (unsigned short)(u >> 16);
}

// ---- agent-scope coherent accessors; RELAXED => no cache-maintenance ops ----
__device__ __forceinline__ void st64a(void* p, u64 v){
  __hip_atomic_store((u64*)p, v, __ATOMIC_RELAXED, __HIP_MEMORY_SCOPE_AGENT);
}
__device__ __forceinline__ u64 ld64a(const void* p){
  return __hip_atomic_load((const u64*)p, __ATOMIC_RELAXED, __HIP_MEMORY_SCOPE_AGENT);
}
__device__ __forceinline__ void st32a(float* p, float v){
  __hip_atomic_store((unsigned*)p, __float_as_uint(v), __ATOMIC_RELAXED, __HIP_MEMORY_SCOPE_AGENT);
}
__device__ __forceinline__ float2 ld2f(const float* p){
  u64 q = ld64a(p);
  float2 r; r.x = __uint_as_float((unsigned)q); r.y = __uint_as_float((unsigned)(q >> 32));
  return r;
}
__device__ __forceinline__ s16x8 ldA(const unsigned short* p){
  union { u64 q[2]; s16x8 v; } u;
  u.q[0] = ld64a(p); u.q[1] = ld64a(p + 4);
  return u.v;
}
__device__ __forceinline__ u64 pk2f(float a, float b){
  return ((u64)__float_as_uint(b) << 32) | (u64)__float_as_uint(a);
}

// Split-phase one-shot tree grid barrier (R8-proven RMW mechanism).
// arrive(): waitcnt drains this wave's sc1 stores to the coherence point;
// syncthreads aligns all waves; tid0 does the tree RMW. Post-arrive
// block-local work may run before wait(). wait(): spin root, then sync.
__device__ __forceinline__ void gbar_arrive(unsigned* slots){
  __builtin_amdgcn_s_waitcnt(0);
  __syncthreads();
  if (threadIdx.x == 0){
    const unsigned g = blockIdx.x >> 4;
    unsigned prev = __hip_atomic_fetch_add(slots + g*16, 1u, __ATOMIC_RELAXED, __HIP_MEMORY_SCOPE_AGENT);
    if (prev == (unsigned)(GSZ-1))
      __hip_atomic_fetch_add(slots + NGRP*16, 1u, __ATOMIC_RELAXED, __HIP_MEMORY_SCOPE_AGENT);
  }
}
__device__ __forceinline__ void gbar_wait(unsigned* slots){
  if (threadIdx.x == 0){
    while (__hip_atomic_load(slots + NGRP*16, __ATOMIC_RELAXED, __HIP_MEMORY_SCOPE_AGENT) < (unsigned)NGRP)
      __builtin_amdgcn_s_sleep(1);
  }
  __syncthreads();
}

__device__ __forceinline__ float bsum(float v, float* red){
  #pragma unroll
  for (int o = 32; o; o >>= 1) v += __shfl_down(v, o);
  __syncthreads();
  if ((threadIdx.x & 63) == 0) red[threadIdx.x >> 6] = v;
  __syncthreads();
  float s = 0.f;
  #pragma unroll
  for (int w2 = 0; w2 < 8; ++w2) s += red[w2];
  return s;
}
__device__ __forceinline__ float bmax(float v, float* red){
  #pragma unroll
  for (int o = 32; o; o >>= 1) v = fmaxf(v, __shfl_down(v, o));
  __syncthreads();
  if ((threadIdx.x & 63) == 0) red[threadIdx.x >> 6] = v;
  __syncthreads();
  float s = -3.4e38f;
  #pragma unroll
  for (int w2 = 0; w2 < 8; ++w2) s = fmaxf(s, red[w2]);
  return s;
}

// out[32b x 16r] = X(bf16, fine-grained)[32 x 32*NCH] @ W(bf16 LDS)[16 x 32*NCH]^T
// Two-pass: batch-issue ALL A-frag loads (static reg arrays), then MFMA.
template<int NCH>
__device__ __forceinline__ void gemm_mfma(
    const unsigned short* __restrict__ Wl, const int wstr,
    const unsigned short* __restrict__ Xg, const int xstr,
    float* __restrict__ Gred, float* __restrict__ gout)
{
  const int tid = threadIdx.x;
  const int w = tid >> 6, lane = tid & 63;
  const int row = lane & 15, kg = lane >> 4;
  f32x4 acc0 = {0.f,0.f,0.f,0.f}, acc1 = {0.f,0.f,0.f,0.f};
  const unsigned short* xp0 = Xg + (size_t)row * xstr + (kg << 3);
  const unsigned short* xp1 = xp0 + (size_t)16 * xstr;
  const unsigned short* wp  = Wl + row * wstr + (kg << 3);
  constexpr int NI = (NCH + 7) >> 3;
  s16x8 a0[NI], a1[NI];
  #pragma unroll
  for (int i = 0; i < NI; ++i) {
    const int c = (i << 3) + w;
    if ((NCH & 7) == 0 || c < NCH) {
      a0[i] = ldA(xp0 + (c << 5));
      a1[i] = ldA(xp1 + (c << 5));
    }
  }
  #pragma unroll
  for (int i = 0; i < NI; ++i) {
    const int c = (i << 3) + w;
    if ((NCH & 7) == 0 || c < NCH) {
      s16x8 bw = *(const s16x8*)(wp + (c << 5));
      acc0 = __builtin_amdgcn_mfma_f32_16x16x32_bf16(a0[i], bw, acc0, 0, 0, 0);
      acc1 = __builtin_amdgcn_mfma_f32_16x16x32_bf16(a1[i], bw, acc1, 0, 0, 0);
    }
  }
  float* gw = Gred + (w << 9) + row;
  #pragma unroll
  for (int v = 0; v < 4; ++v) {
    gw[((kg << 2) + v) << 4]        = acc0[v];
    gw[((kg << 2) + v + 16) << 4]   = acc1[v];
  }
  __syncthreads();
  float s = 0.f;
  #pragma unroll
  for (int w8 = 0; w8 < 8; ++w8) s += Gred[(w8 << 9) + tid];
  gout[tid] = s;   // caller syncs before reading
}

__global__ void __launch_bounds__(NTHR, 2) decoder_kernel(
    const float* __restrict__ enc, const float* __restrict__ audio,
    const float* __restrict__ Wih0, const float* __restrict__ Whh0,
    const float* __restrict__ bih0, const float* __restrict__ bhh0,
    const float* __restrict__ Wih1, const float* __restrict__ Whh1,
    const float* __restrict__ bih1, const float* __restrict__ bhh1,
    const float* __restrict__ Wa, const float* __restrict__ ba,
    const float* __restrict__ Wfc, const float* __restrict__ bfc,
    float* __restrict__ out, float* __restrict__ ws)
{
  cg::grid_group grid = cg::this_grid();
  extern __shared__ char lds[];
  unsigned short* W0  = (unsigned short*)(lds + OFF_W0);
  unsigned short* W1I = (unsigned short*)(lds + OFF_W1I);
  unsigned short* W1H = (unsigned short*)(lds + OFF_W1H);
  float* Gred = (float*)(lds + OFF_GRED);
  float* Gsum = (float*)(lds + OFF_GSUM);
  float* Gs1p = (float*)(lds + OFF_GS1P);
  float* c0l  = (float*)(lds + OFF_C0);
  float* c1l  = (float*)(lds + OFF_C1);
  float* smw  = (float*)(lds + OFF_APOOL);
  float* red  = smw + 256;
  float* shC  = smw + 320;

  const int blk = blockIdx.x, tid = threadIdx.x;
  const int j = blk;                                // owns h-columns [4j, 4j+4)

  unsigned short* inp    = (unsigned short*)ws;     // 2 x [32][XSTR] bf16
  unsigned short* h1bufs = (unsigned short*)((char*)ws + WS_H1B); // 2 x [32][1024]
  float* h1f = (float*)((char*)ws + WS_H1F);
  float* esc = (float*)((char*)ws + WS_ESC);
  float* par = (float*)((char*)ws + WS_PAR);        // [32][256] score partials
  unsigned* bars = (unsigned*)((char*)ws + WS_BAR);

  const float waH0 = Wa[4*j], waH1 = Wa[4*j+1], waH2 = Wa[4*j+2], waH3 = Wa[4*j+3];

  // ---- prologue (plain stores; flushed by the one cg grid.sync) ----
  for (int i = tid; i < 16*XSTR; i += NTHR) {
    int r = i / XSTR, k = i - r*XSTR;
    int n = (r & 3)*HH + 4*j + (r >> 2);
    float v = 0.f;
    if (k < IN0) v = Wih0[(size_t)n*IN0 + k];
    else if (k < KT) v = Whh0[(size_t)n*HH + (k - IN0)];
    W0[i] = f2bf(v);
  }
  for (int i = tid; i < 16*W1STR; i += NTHR) {
    int r = i / W1STR, k = i - r*W1STR;
    int n = (r & 3)*HH + 4*j + (r >> 2);
    W1I[i] = (k < HH) ? f2bf(Wih1[(size_t)n*HH + k]) : (unsigned short)0;
    W1H[i] = (k < HH) ? f2bf(Whh1[(size_t)n*HH + k]) : (unsigned short)0;
  }
  if (tid < 128) { c0l[tid] = 0.f; c1l[tid] = 0.f; }
  for (int i = blk*NTHR + tid; i < 2*BBAT*XSTR; i += NBLK*NTHR) inp[i] = 0;
  for (int i = blk*NTHR + tid; i < 2*BBAT*HH; i += NBLK*NTHR) h1bufs[i] = 0;
  for (int i = blk*NTHR + tid; i < BBAT*HH; i += NBLK*NTHR) h1f[i] = 0.f;
  for (int i = blk*NTHR + tid; i < 3*TT*BSLOTS; i += NBLK*NTHR) bars[i] = 0u;
  for (int row = blk; row < BBAT*SE; row += NBLK) {
    float pp = tanhf(enc[(size_t)row*EE + tid]) * Wa[HH + tid];   // EE == NTHR
    pp = bsum(pp, red);
    if (tid == 0) esc[row] = pp;
  }
  grid.sync();   // single heavyweight sync (flushes prologue + barrier zeros)

  int cur = 0;
  for (int t = 0; t < TT; ++t) {
    unsigned short* inpA = inp + cur*BBAT*XSTR;
    unsigned short* inpN = inp + (cur^1)*BBAT*XSTR;
    unsigned short* h1bR = h1bufs + ((t&1)^1)*BBAT*HH;   // h1(t-1) bf16
    unsigned short* h1bW = h1bufs + (t&1)*BBAT*HH;       // h1(t)  bf16

    // ===== Phase A: attention -> ctx + audio pack | post-arrive: FC pred(t-1) =====
    {
      const int b = blk & 31, esl = blk >> 5;
      if (t > 0) {
        float pp = 0.f;
        if (tid < 128) {
          float2 pv = ld2f(par + b*256 + tid*2);
          pp = pv.x + pv.y;
        }
        float sdot = bsum(pp, red) + ba[0];
        float sc = (tid < SE) ? esc[b*SE + tid] + sdot : -3.4e38f;
        float mx = bmax(sc, red);
        float ex = (tid < SE) ? expf(sc - mx) : 0.f;
        float den = bsum(ex, red);
        if (tid < SE) smw[tid] = ex / den;
      } else {
        if (tid < SE) smw[tid] = 1.0f / (float)SE;
      }
      __syncthreads();
      const int sg = tid >> 6, el = tid & 63;
      const int e = esl*64 + el;
      float a = 0.f;
      for (int s2 = sg*25; s2 < sg*25 + 25; ++s2)
        a = fmaf(smw[s2], enc[((size_t)b*SE + s2)*EE + e], a);
      shC[sg*64 + el] = a;
      __syncthreads();
      if (tid < 64) {
        float r8 = 0.f;
        #pragma unroll
        for (int s3 = 0; s3 < 8; ++s3) r8 += shC[s3*64 + tid];
        red[tid] = r8;
      }
      __syncthreads();
      if (tid < 16) {
        u64 cp = 0;
        #pragma unroll
        for (int q = 0; q < 4; ++q) cp |= (u64)f2bf(red[4*tid + q]) << (16*q);
        st64a(inpA + (size_t)b*XSTR + MM + esl*64 + 4*tid, cp);
      }
      if (esl == 0 && tid < 20) {
        u64 xp = 0;
        #pragma unroll
        for (int q = 0; q < 4; ++q)
          xp |= (u64)f2bf(audio[((size_t)b*TT + t)*MM + 4*tid + q]) << (16*q);
        st64a(inpA + (size_t)b*XSTR + 4*tid, xp);
      }
    }
    gbar_arrive(bars + (3*t + 0)*BSLOTS);
    if (t > 0) {   // FC pred(t-1), hidden under barrier A (h1f stable: next write after barB)
      const int w = tid >> 6, lane = tid & 63;
      for (int u = w; u < 10; u += 8) {
        int idx = j*10 + u;
        int b = idx / MM, m = idx - b*MM;
        float pp = 0.f;
        #pragma unroll
        for (int cq = 0; cq < 4; ++cq) {
          float2 h0v = ld2f(h1f + (size_t)b*HH + cq*256 + lane*4);
          float2 h1v = ld2f(h1f + (size_t)b*HH + cq*256 + lane*4 + 2);
          float4 wv = *(const float4*)(Wfc + (size_t)m*HH + cq*256 + lane*4);
          pp = fmaf(h0v.x,wv.x, fmaf(h0v.y,wv.y, fmaf(h1v.x,wv.z, fmaf(h1v.y,wv.w, pp))));
        }
        #pragma unroll
        for (int o2 = 32; o2; o2 >>= 1) pp += __shfl_down(pp, o2);
        if (lane == 0) out[((size_t)b*TT + (t-1))*MM + m] = pp + bfc[m];
      }
    }
    gbar_wait(bars + (3*t + 0)*BSLOTS);

    // ===== Phase B: LSTM0 | post-arrive: Whh1@h1(t-1) partial =====
    gemm_mfma<51>(W0, XSTR, inpA, XSTR, Gred, Gsum);
    __syncthreads();
    if (tid < BBAT) {
      const int b = tid;
      u64 hp = 0;
      #pragma unroll
      for (int p = 0; p < 4; ++p) {
        f32x4 gv = *(const f32x4*)(Gsum + (b << 4) + (p << 2));
        const int nb = 4*j + p;
        float gi = gv[0] + bih0[nb]        + bhh0[nb];
        float gf = gv[1] + bih0[HH + nb]   + bhh0[HH + nb];
        float gg = gv[2] + bih0[2*HH + nb] + bhh0[2*HH + nb];
        float go = gv[3] + bih0[3*HH + nb] + bhh0[3*HH + nb];
        float cn = sigmf(gf) * c0l[p*32 + b] + sigmf(gi) * tanhf(gg);
        c0l[p*32 + b] = cn;
        hp |= (u64)f2bf(sigmf(go) * tanhf(cn)) << (16*p);
      }
      st64a(inpN + (size_t)b*XSTR + IN0 + 4*j, hp);
    }
    gbar_arrive(bars + (3*t + 1)*BSLOTS);
    // hidden under barrier B; reads h1bR (parity buffer t-1, no writer until C(t+1))
    gemm_mfma<32>(W1H, W1STR, h1bR, HH, Gred, Gs1p);
    gbar_wait(bars + (3*t + 1)*BSLOTS);

    // ===== Phase C: LSTM1 =====
    gemm_mfma<32>(W1I, W1STR, inpN + IN0, XSTR, Gred, Gsum);
    __syncthreads();
    if (tid < BBAT) {
      const int b = tid;
      u64 hp = 0;
      float hf[4];
      #pragma unroll
      for (int p = 0; p < 4; ++p) {
        f32x4 gv = *(const f32x4*)(Gsum + (b << 4) + (p << 2));
        f32x4 g1 = *(const f32x4*)(Gs1p + (b << 4) + (p << 2));
        const int nb = 4*j + p;
        float gi = gv[0] + g1[0] + bih1[nb]        + bhh1[nb];
        float gf = gv[1] + g1[1] + bih1[HH + nb]   + bhh1[HH + nb];
        float gg = gv[2] + g1[2] + bih1[2*HH + nb] + bhh1[2*HH + nb];
        float go = gv[3] + g1[3] + bih1[3*HH + nb] + bhh1[3*HH + nb];
        float cn = sigmf(gf) * c1l[p*32 + b] + sigmf(gi) * tanhf(gg);
        c1l[p*32 + b] = cn;
        float hn = sigmf(go) * tanhf(cn);
        hf[p] = hn;
        hp |= (u64)f2bf(hn) << (16*p);
      }
      st64a(h1bW + (size_t)b*HH + 4*j, hp);
      st64a(h1f + (size_t)b*HH + 4*j,     pk2f(hf[0], hf[1]));
      st64a(h1f + (size_t)b*HH + 4*j + 2, pk2f(hf[2], hf[3]));
      // distributed score partial: tanh(h1_local) . wa_h_local  (f32 h1, exact)
      float ps = tanhf(hf[0])*waH0 + tanhf(hf[1])*waH1 + tanhf(hf[2])*waH2 + tanhf(hf[3])*waH3;
      st32a(par + b*256 + j, ps);
    }
    gbar_arrive(bars + (3*t + 2)*BSLOTS);
    gbar_wait(bars + (3*t + 2)*BSLOTS);
    cur ^= 1;
  }

  // ---- epilogue: FC pred for t = TT-1 ----
  {
    const int w = tid >> 6, lane = tid & 63;
    for (int u = w; u < 10; u += 8) {
      int idx = j*10 + u;
      int b = idx / MM, m = idx - b*MM;
      float pp = 0.f;
      #pragma unroll
      for (int cq = 0; cq < 4; ++cq) {
        float2 h0v = ld2f(h1f + (size_t)b*HH + cq*256 + lane*4);
        float2 h1v = ld2f(h1f + (size_t)b*HH + cq*256 + lane*4 + 2);
        float4 wv = *(const float4*)(Wfc + (size_t)m*HH + cq*256 + lane*4);
        pp = fmaf(h0v.x,wv.x, fmaf(h0v.y,wv.y, fmaf(h1v.x,wv.z, fmaf(h1v.y,wv.w, pp))));
      }
      #pragma unroll
      for (int o2 = 32; o2; o2 >>= 1) pp += __shfl_down(pp, o2);
      if (lane == 0) out[((size_t)b*TT + (TT-1))*MM + m] = pp + bfc[m];
    }
  }
}

extern "C" void kernel_launch(void* const* d_in, const int* in_sizes, int n_in,
                              void* d_out, int out_size, void* d_ws, size_t ws_size,
                              hipStream_t stream) {
  const float* enc  = (const float*)d_in[0];
  const float* audio= (const float*)d_in[1];
  const float* Wih0 = (const float*)d_in[2];
  const float* Whh0 = (const float*)d_in[3];
  const float* bih0 = (const float*)d_in[4];
  const float* bhh0 = (const float*)d_in[5];
  const float* Wih1 = (const float*)d_in[6];
  const float* Whh1 = (const float*)d_in[7];
  const float* bih1 = (const float*)d_in[8];
  const float* bhh1 = (const float*)d_in[9];
  const float* Wa   = (const float*)d_in[10];
  const float* ba   = (const float*)d_in[11];
  const float* Wfc  = (const float*)d_in[12];
  const float* bfc  = (const float*)d_in[13];
  float* out = (float*)d_out;
  float* ws  = (float*)d_ws;

  (void)hipFuncSetAttribute((const void*)decoder_kernel,
                            hipFuncAttributeMaxDynamicSharedMemorySize, LDS_TOTAL);

  void* args[] = { &enc,&audio,&Wih0,&Whh0,&bih0,&bhh0,&Wih1,&Whh1,&bih1,&bhh1,
                   &Wa,&ba,&Wfc,&bfc,&out,&ws };
  hipLaunchCooperativeKernel((const void*)decoder_kernel, dim3(NBLK), dim3(NTHR),
                             args, LDS_TOTAL, stream);
}

// Round 10
// 7653.629 us; speedup vs baseline: 9.1641x; 1.3939x over previous
//
#include <hip/hip_runtime.h>
#include <hip/hip_cooperative_groups.h>

namespace cg = cooperative_groups;

#define BBAT 32
#define SE 200
#define TT 400
#define MM 80
#define EE 512
#define HH 1024
#define IN0 592
#define KT 1616
#define XSTR 1640      // inp row stride in bf16 elems (3280 B)
#define W1STR 1032
#define NBLK 256
#define NTHR 512

// barrier tree: 16 groups x 16 blocks, 17 padded slots (16 u32 each)
#define NGRP 16
#define GSZ  16
#define BSLOTS 272

typedef __attribute__((ext_vector_type(4))) float f32x4;
typedef __attribute__((ext_vector_type(8))) short s16x8;
typedef unsigned long long u64;

// LDS offsets (bytes)
#define OFF_W0    0          // 16*1640*2 = 52480
#define OFF_W1I   52480      // 33024
#define OFF_W1H   85504      // 33024
#define OFF_GRED  118528     // 16384
#define OFF_GSUM  134912     // 2048
#define OFF_GS1P  136960     // 2048
#define OFF_C0    139008     // 512
#define OFF_C1    139520     // 512
#define OFF_APOOL 140032     // smw 256 + red 64 f32
#define LDS_TOTAL 143360

// ws offsets (bytes)
#define WS_H1B  209920       // 2 x [32][1024] bf16 (t-parity)
#define WS_H1F  340992       // 2 x [32][1024] f32  (t-parity)
#define WS_ESC  603136       // [32][200] f32
#define WS_CTXS 628736       // [32][512] f32 (ctx_soft staging for t=0 overwrite)
#define WS_BAR  694272       // 800 x 272 u32

__device__ __forceinline__ float sigmf(float x){ return 1.0f/(1.0f+expf(-x)); }

__device__ __forceinline__ unsigned short f2bf(float v){
  unsigned int u = __float_as_uint(v);
  u += 0x7fffu + ((u >> 16) & 1u);
  return (unsigned short)(u >> 16);
}

// ---- agent-scope coherent accessors; RELAXED => no cache-maintenance ops ----
__device__ __forceinline__ void st64a(void* p, u64 v){
  __hip_atomic_store((u64*)p, v, __ATOMIC_RELAXED, __HIP_MEMORY_SCOPE_AGENT);
}
__device__ __forceinline__ u64 ld64a(const void* p){
  return __hip_atomic_load((const u64*)p, __ATOMIC_RELAXED, __HIP_MEMORY_SCOPE_AGENT);
}
__device__ __forceinline__ float2 ld2f(const float* p){
  u64 q = ld64a(p);
  float2 r; r.x = __uint_as_float((unsigned)q); r.y = __uint_as_float((unsigned)(q >> 32));
  return r;
}
__device__ __forceinline__ s16x8 ldA(const unsigned short* p){
  union { u64 q[2]; s16x8 v; } u;
  u.q[0] = ld64a(p); u.q[1] = ld64a(p + 4);
  return u.v;
}
__device__ __forceinline__ u64 pk2f(float a, float b){
  return ((u64)__float_as_uint(b) << 32) | (u64)__float_as_uint(a);
}

// Split-phase one-shot tree grid barrier (R8/R9-proven RMW mechanism).
__device__ __forceinline__ void gbar_arrive(unsigned* slots){
  __builtin_amdgcn_s_waitcnt(0);
  __syncthreads();
  if (threadIdx.x == 0){
    const unsigned g = blockIdx.x >> 4;
    unsigned prev = __hip_atomic_fetch_add(slots + g*16, 1u, __ATOMIC_RELAXED, __HIP_MEMORY_SCOPE_AGENT);
    if (prev == (unsigned)(GSZ-1))
      __hip_atomic_fetch_add(slots + NGRP*16, 1u, __ATOMIC_RELAXED, __HIP_MEMORY_SCOPE_AGENT);
  }
}
__device__ __forceinline__ void gbar_wait(unsigned* slots){
  if (threadIdx.x == 0){
    while (__hip_atomic_load(slots + NGRP*16, __ATOMIC_RELAXED, __HIP_MEMORY_SCOPE_AGENT) < (unsigned)NGRP)
      __builtin_amdgcn_s_sleep(1);
  }
  __syncthreads();
}

__device__ __forceinline__ float bsum(float v, float* red){
  #pragma unroll
  for (int o = 32; o; o >>= 1) v += __shfl_down(v, o);
  __syncthreads();
  if ((threadIdx.x & 63) == 0) red[threadIdx.x >> 6] = v;
  __syncthreads();
  float s = 0.f;
  #pragma unroll
  for (int w2 = 0; w2 < 8; ++w2) s += red[w2];
  return s;
}
__device__ __forceinline__ float bmax(float v, float* red){
  #pragma unroll
  for (int o = 32; o; o >>= 1) v = fmaxf(v, __shfl_down(v, o));
  __syncthreads();
  if ((threadIdx.x & 63) == 0) red[threadIdx.x >> 6] = v;
  __syncthreads();
  float s = -3.4e38f;
  #pragma unroll
  for (int w2 = 0; w2 < 8; ++w2) s = fmaxf(s, red[w2]);
  return s;
}

// LSTM0 pre-gemm: accumulate chunks {3..50} (static ctx + h0) into acc.
// Wave w: 6 chunks c = cstart + 8i, cstart = (w<3) ? w+8 : w.
__device__ __forceinline__ void gemm0_pre(
    const unsigned short* __restrict__ Wl,
    const unsigned short* __restrict__ Xg,
    f32x4& acc0, f32x4& acc1)
{
  const int tid = threadIdx.x;
  const int w = tid >> 6, lane = tid & 63;
  const int row = lane & 15, kg = lane >> 4;
  const unsigned short* xp0 = Xg + (size_t)row * XSTR + (kg << 3);
  const unsigned short* xp1 = xp0 + (size_t)16 * XSTR;
  const unsigned short* wp  = Wl + row * XSTR + (kg << 3);
  const int cstart = (w < 3) ? (w + 8) : w;
  s16x8 a0[6], a1[6];
  #pragma unroll
  for (int i = 0; i < 6; ++i) {
    const int c = cstart + (i << 3);
    a0[i] = ldA(xp0 + (c << 5));
    a1[i] = ldA(xp1 + (c << 5));
  }
  #pragma unroll
  for (int i = 0; i < 6; ++i) {
    const int c = cstart + (i << 3);
    s16x8 bw = *(const s16x8*)(wp + (c << 5));
    acc0 = __builtin_amdgcn_mfma_f32_16x16x32_bf16(a0[i], bw, acc0, 0, 0, 0);
    acc1 = __builtin_amdgcn_mfma_f32_16x16x32_bf16(a1[i], bw, acc1, 0, 0, 0);
  }
}

// LSTM0 post: chunks {0,1,2} (x_t + x/ctx boundary), then Gred reduce -> gout.
__device__ __forceinline__ void gemm0_post(
    const unsigned short* __restrict__ Wl,
    const unsigned short* __restrict__ Xg,
    f32x4 acc0, f32x4 acc1,
    float* __restrict__ Gred, float* __restrict__ gout)
{
  const int tid = threadIdx.x;
  const int w = tid >> 6, lane = tid & 63;
  const int row = lane & 15, kg = lane >> 4;
  if (w < 3) {
    const int c = w;
    const unsigned short* xp0 = Xg + (size_t)row * XSTR + (kg << 3) + (c << 5);
    s16x8 a0 = ldA(xp0);
    s16x8 a1 = ldA(xp0 + (size_t)16 * XSTR);
    s16x8 bw = *(const s16x8*)(Wl + row * XSTR + (kg << 3) + (c << 5));
    acc0 = __builtin_amdgcn_mfma_f32_16x16x32_bf16(a0, bw, acc0, 0, 0, 0);
    acc1 = __builtin_amdgcn_mfma_f32_16x16x32_bf16(a1, bw, acc1, 0, 0, 0);
  }
  float* gw = Gred + (w << 9) + row;
  #pragma unroll
  for (int v = 0; v < 4; ++v) {
    gw[((kg << 2) + v) << 4]      = acc0[v];
    gw[((kg << 2) + v + 16) << 4] = acc1[v];
  }
  __syncthreads();
  float s = 0.f;
  #pragma unroll
  for (int w8 = 0; w8 < 8; ++w8) s += Gred[(w8 << 9) + tid];
  gout[tid] = s;   // caller syncs before reading
}

// Generic 32-chunk gemm (Whh1, Wih1).
__device__ __forceinline__ void gemm32(
    const unsigned short* __restrict__ Wl, const int wstr,
    const unsigned short* __restrict__ Xg, const int xstr,
    float* __restrict__ Gred, float* __restrict__ gout)
{
  const int tid = threadIdx.x;
  const int w = tid >> 6, lane = tid & 63;
  const int row = lane & 15, kg = lane >> 4;
  f32x4 acc0 = {0.f,0.f,0.f,0.f}, acc1 = {0.f,0.f,0.f,0.f};
  const unsigned short* xp0 = Xg + (size_t)row * xstr + (kg << 3);
  const unsigned short* xp1 = xp0 + (size_t)16 * xstr;
  const unsigned short* wp  = Wl + row * wstr + (kg << 3);
  s16x8 a0[4], a1[4];
  #pragma unroll
  for (int i = 0; i < 4; ++i) {
    const int c = (i << 3) + w;
    a0[i] = ldA(xp0 + (c << 5));
    a1[i] = ldA(xp1 + (c << 5));
  }
  #pragma unroll
  for (int i = 0; i < 4; ++i) {
    const int c = (i << 3) + w;
    s16x8 bw = *(const s16x8*)(wp + (c << 5));
    acc0 = __builtin_amdgcn_mfma_f32_16x16x32_bf16(a0[i], bw, acc0, 0, 0, 0);
    acc1 = __builtin_amdgcn_mfma_f32_16x16x32_bf16(a1[i], bw, acc1, 0, 0, 0);
  }
  float* gw = Gred + (w << 9) + row;
  #pragma unroll
  for (int v = 0; v < 4; ++v) {
    gw[((kg << 2) + v) << 4]      = acc0[v];
    gw[((kg << 2) + v + 16) << 4] = acc1[v];
  }
  __syncthreads();
  float s = 0.f;
  #pragma unroll
  for (int w8 = 0; w8 < 8; ++w8) s += Gred[(w8 << 9) + tid];
  gout[tid] = s;
}

__global__ void __launch_bounds__(NTHR, 1) decoder_kernel(
    const float* __restrict__ enc, const float* __restrict__ audio,
    const float* __restrict__ Wih0, const float* __restrict__ Whh0,
    const float* __restrict__ bih0, const float* __restrict__ bhh0,
    const float* __restrict__ Wih1, const float* __restrict__ Whh1,
    const float* __restrict__ bih1, const float* __restrict__ bhh1,
    const float* __restrict__ Wa, const float* __restrict__ ba,
    const float* __restrict__ Wfc, const float* __restrict__ bfc,
    float* __restrict__ out, float* __restrict__ ws)
{
  cg::grid_group grid = cg::this_grid();
  extern __shared__ char lds[];
  unsigned short* W0  = (unsigned short*)(lds + OFF_W0);
  unsigned short* W1I = (unsigned short*)(lds + OFF_W1I);
  unsigned short* W1H = (unsigned short*)(lds + OFF_W1H);
  float* Gred = (float*)(lds + OFF_GRED);
  float* Gsum = (float*)(lds + OFF_GSUM);
  float* Gs1p = (float*)(lds + OFF_GS1P);
  float* c0l  = (float*)(lds + OFF_C0);
  float* c1l  = (float*)(lds + OFF_C1);
  float* smw  = (float*)(lds + OFF_APOOL);
  float* red  = smw + 256;

  const int blk = blockIdx.x, tid = threadIdx.x;
  const int j = blk;                                // owns h-columns [4j, 4j+4)

  unsigned short* inp    = (unsigned short*)ws;     // 2 x [32][XSTR] bf16
  unsigned short* h1bufs = (unsigned short*)((char*)ws + WS_H1B);
  float* h1f  = (float*)((char*)ws + WS_H1F);       // 2 x [32][1024] f32
  float* esc  = (float*)((char*)ws + WS_ESC);
  float* ctxs = (float*)((char*)ws + WS_CTXS);
  unsigned* bars = (unsigned*)((char*)ws + WS_BAR);

  // ---- prologue: weights -> LDS bf16; zero states; esc ----
  for (int i = tid; i < 16*XSTR; i += NTHR) {
    int r = i / XSTR, k = i - r*XSTR;
    int n = (r & 3)*HH + 4*j + (r >> 2);
    float v = 0.f;
    if (k < IN0) v = Wih0[(size_t)n*IN0 + k];
    else if (k < KT) v = Whh0[(size_t)n*HH + (k - IN0)];
    W0[i] = f2bf(v);
  }
  for (int i = tid; i < 16*W1STR; i += NTHR) {
    int r = i / W1STR, k = i - r*W1STR;
    int n = (r & 3)*HH + 4*j + (r >> 2);
    W1I[i] = (k < HH) ? f2bf(Wih1[(size_t)n*HH + k]) : (unsigned short)0;
    W1H[i] = (k < HH) ? f2bf(Whh1[(size_t)n*HH + k]) : (unsigned short)0;
  }
  if (tid < 128) { c0l[tid] = 0.f; c1l[tid] = 0.f; }
  for (int i = blk*NTHR + tid; i < 2*BBAT*XSTR; i += NBLK*NTHR) inp[i] = 0;
  for (int i = blk*NTHR + tid; i < 2*BBAT*HH; i += NBLK*NTHR) h1bufs[i] = 0;
  for (int i = blk*NTHR + tid; i < 2*BBAT*HH; i += NBLK*NTHR) h1f[i] = 0.f;
  for (int i = blk*NTHR + tid; i < 2*TT*BSLOTS; i += NBLK*NTHR) bars[i] = 0u;
  for (int row = blk; row < BBAT*SE; row += NBLK) {
    float pp = tanhf(enc[(size_t)row*EE + tid]) * Wa[HH + tid];   // EE == NTHR
    pp = bsum(pp, red);
    if (tid == 0) esc[row] = pp;
  }
  grid.sync();

  // ---- static softmax weights + static contexts (softmax is h1-invariant) ----
  if (blk < BBAT) {
    const int b = blk;
    float sc = (tid < SE) ? esc[b*SE + tid] : -3.4e38f;
    float mx = bmax(sc, red);
    float ex = (tid < SE) ? expf(sc - mx) : 0.f;
    float den = bsum(ex, red);
    if (tid < SE) smw[tid] = ex / den;
    __syncthreads();
    const int e = tid;                                // EE == NTHR
    float as = 0.f, am = 0.f;
    for (int s = 0; s < SE; ++s) {
      float v = enc[((size_t)b*SE + s)*EE + e];
      as = fmaf(smw[s], v, as);
      am += v;
    }
    am *= (1.0f/(float)SE);
    inp[(size_t)b*XSTR + MM + e]             = f2bf(am);   // buf0: ctx_mean (t=0)
    inp[BBAT*XSTR + (size_t)b*XSTR + MM + e] = f2bf(as);   // buf1: ctx_soft (odd t)
    ctxs[b*EE + e] = as;
    if (tid < MM)
      inp[(size_t)b*XSTR + tid] = f2bf(audio[((size_t)b*TT + 0)*MM + tid]);  // x_0
  }
  grid.sync();

  f32x4 z4 = {0.f,0.f,0.f,0.f};
  f32x4 acc0 = z4, acc1 = z4;
  gemm0_pre(W0, inp, acc0, acc1);    // t=0: ctx_mean + h0(-1)=0 chunks

  for (int t = 0; t < TT; ++t) {
    unsigned short* inpA = inp + (t&1)*BBAT*XSTR;
    unsigned short* inpN = inp + ((t&1)^1)*BBAT*XSTR;
    unsigned short* h1bR = h1bufs + ((t&1)^1)*BBAT*HH;
    unsigned short* h1bW = h1bufs + (t&1)*BBAT*HH;
    float* h1fR = h1f + ((t&1)^1)*BBAT*HH;
    float* h1fW = h1f + (t&1)*BBAT*HH;

    // ===== Phase B: finish LSTM0(t) =====
    gemm0_post(W0, inpA, acc0, acc1, Gred, Gsum);
    __syncthreads();
    if (tid < BBAT) {
      const int b = tid;
      u64 hp = 0;
      #pragma unroll
      for (int p = 0; p < 4; ++p) {
        f32x4 gv = *(const f32x4*)(Gsum + (b << 4) + (p << 2));
        const int nb = 4*j + p;
        float gi = gv[0] + bih0[nb]        + bhh0[nb];
        float gf = gv[1] + bih0[HH + nb]   + bhh0[HH + nb];
        float gg = gv[2] + bih0[2*HH + nb] + bhh0[2*HH + nb];
        float go = gv[3] + bih0[3*HH + nb] + bhh0[3*HH + nb];
        float cn = sigmf(gf) * c0l[p*32 + b] + sigmf(gi) * tanhf(gg);
        c0l[p*32 + b] = cn;
        hp |= (u64)f2bf(sigmf(go) * tanhf(cn)) << (16*p);
      }
      st64a(inpN + (size_t)b*XSTR + IN0 + 4*j, hp);
    }
    gbar_arrive(bars + (2*t + 0)*BSLOTS);
    // --- hidden under barrier B ---
    gemm32(W1H, W1STR, h1bR, HH, Gred, Gs1p);       // Whh1 @ h1(t-1) partial
    if (t + 1 < TT && blk < BBAT && tid < 20) {     // pack x_{t+1} into inpN
      const int b = blk;
      u64 xp = 0;
      #pragma unroll
      for (int q = 0; q < 4; ++q)
        xp |= (u64)f2bf(audio[((size_t)b*TT + (t+1))*MM + 4*tid + q]) << (16*q);
      st64a(inpN + (size_t)b*XSTR + 4*tid, xp);
    }
    if (t == 0 && blk < BBAT && tid < 128) {        // buf0 ctx: mean -> soft
      const int b = blk;
      u64 cp = 0;
      #pragma unroll
      for (int q = 0; q < 4; ++q) cp |= (u64)f2bf(ctxs[b*EE + 4*tid + q]) << (16*q);
      st64a(inp + (size_t)b*XSTR + MM + 4*tid, cp);
    }
    if (t > 0) {   // FC pred(t-1) from parity h1f (race-free: next writer behind barB(t+1))
      const int w = tid >> 6, lane = tid & 63;
      for (int u = w; u < 10; u += 8) {
        int idx = j*10 + u;
        int b = idx / MM, m = idx - b*MM;
        float pp = 0.f;
        #pragma unroll
        for (int cq = 0; cq < 4; ++cq) {
          float2 h0v = ld2f(h1fR + (size_t)b*HH + cq*256 + lane*4);
          float2 h1v = ld2f(h1fR + (size_t)b*HH + cq*256 + lane*4 + 2);
          float4 wv = *(const float4*)(Wfc + (size_t)m*HH + cq*256 + lane*4);
          pp = fmaf(h0v.x,wv.x, fmaf(h0v.y,wv.y, fmaf(h1v.x,wv.z, fmaf(h1v.y,wv.w, pp))));
        }
        #pragma unroll
        for (int o2 = 32; o2; o2 >>= 1) pp += __shfl_down(pp, o2);
        if (lane == 0) out[((size_t)b*TT + (t-1))*MM + m] = pp + bfc[m];
      }
    }
    gbar_wait(bars + (2*t + 0)*BSLOTS);

    // ===== Phase C: LSTM1(t) =====
    gemm32(W1I, W1STR, inpN + IN0, XSTR, Gred, Gsum);
    __syncthreads();
    if (tid < BBAT) {
      const int b = tid;
      u64 hp = 0;
      float hf[4];
      #pragma unroll
      for (int p = 0; p < 4; ++p) {
        f32x4 gv = *(const f32x4*)(Gsum + (b << 4) + (p << 2));
        f32x4 g1 = *(const f32x4*)(Gs1p + (b << 4) + (p << 2));
        const int nb = 4*j + p;
        float gi = gv[0] + g1[0] + bih1[nb]        + bhh1[nb];
        float gf = gv[1] + g1[1] + bih1[HH + nb]   + bhh1[HH + nb];
        float gg = gv[2] + g1[2] + bih1[2*HH + nb] + bhh1[2*HH + nb];
        float go = gv[3] + g1[3] + bih1[3*HH + nb] + bhh1[3*HH + nb];
        float cn = sigmf(gf) * c1l[p*32 + b] + sigmf(gi) * tanhf(gg);
        c1l[p*32 + b] = cn;
        float hn = sigmf(go) * tanhf(cn);
        hf[p] = hn;
        hp |= (u64)f2bf(hn) << (16*p);
      }
      st64a(h1bW + (size_t)b*HH + 4*j, hp);
      st64a(h1fW + (size_t)b*HH + 4*j,     pk2f(hf[0], hf[1]));
      st64a(h1fW + (size_t)b*HH + 4*j + 2, pk2f(hf[2], hf[3]));
    }
    gbar_arrive(bars + (2*t + 1)*BSLOTS);
    // --- hidden under barrier C: pre-gemm LSTM0(t+1) (static ctx + h0(t)) ---
    acc0 = z4; acc1 = z4;
    if (t + 1 < TT) gemm0_pre(W0, inpN, acc0, acc1);
    gbar_wait(bars + (2*t + 1)*BSLOTS);
  }

  // ---- epilogue: FC pred for t = TT-1 ----
  {
    const float* h1fL = h1f + ((TT-1)&1)*BBAT*HH;
    const int w = tid >> 6, lane = tid & 63;
    for (int u = w; u < 10; u += 8) {
      int idx = j*10 + u;
      int b = idx / MM, m = idx - b*MM;
      float pp = 0.f;
      #pragma unroll
      for (int cq = 0; cq < 4; ++cq) {
        float2 h0v = ld2f(h1fL + (size_t)b*HH + cq*256 + lane*4);
        float2 h1v = ld2f(h1fL + (size_t)b*HH + cq*256 + lane*4 + 2);
        float4 wv = *(const float4*)(Wfc + (size_t)m*HH + cq*256 + lane*4);
        pp = fmaf(h0v.x,wv.x, fmaf(h0v.y,wv.y, fmaf(h1v.x,wv.z, fmaf(h1v.y,wv.w, pp))));
      }
      #pragma unroll
      for (int o2 = 32; o2; o2 >>= 1) pp += __shfl_down(pp, o2);
      if (lane == 0) out[((size_t)b*TT + (TT-1))*MM + m] = pp + bfc[m];
    }
  }
}

extern "C" void kernel_launch(void* const* d_in, const int* in_sizes, int n_in,
                              void* d_out, int out_size, void* d_ws, size_t ws_size,
                              hipStream_t stream) {
  const float* enc  = (const float*)d_in[0];
  const float* audio= (const float*)d_in[1];
  const float* Wih0 = (const float*)d_in[2];
  const float* Whh0 = (const float*)d_in[3];
  const float* bih0 = (const float*)d_in[4];
  const float* bhh0 = (const float*)d_in[5];
  const float* Wih1 = (const float*)d_in[6];
  const float* Whh1 = (const float*)d_in[7];
  const float* bih1 = (const float*)d_in[8];
  const float* bhh1 = (const float*)d_in[9];
  const float* Wa   = (const float*)d_in[10];
  const float* ba   = (const float*)d_in[11];
  const float* Wfc  = (const float*)d_in[12];
  const float* bfc  = (const float*)d_in[13];
  float* out = (float*)d_out;
  float* ws  = (float*)d_ws;

  (void)hipFuncSetAttribute((const void*)decoder_kernel,
                            hipFuncAttributeMaxDynamicSharedMemorySize, LDS_TOTAL);

  void* args[] = { &enc,&audio,&Wih0,&Whh0,&bih0,&bhh0,&Wih1,&Whh1,&bih1,&bhh1,
                   &Wa,&ba,&Wfc,&bfc,&out,&ws };
  hipLaunchCooperativeKernel((const void*)decoder_kernel, dim3(NBLK), dim3(NTHR),
                             args, LDS_TOTAL, stream);
}

// Round 11
// 5701.649 us; speedup vs baseline: 12.3015x; 1.3424x over previous
//
#include <hip/hip_runtime.h>
#include <hip/hip_cooperative_groups.h>

namespace cg = cooperative_groups;

#define BBAT 32
#define SE 200
#define TT 400
#define MM 80
#define EE 512
#define HH 1024
#define IN0 592
#define KS 608         // static panel row: x(80) + ctx(512) + zero pad(16)
#define NSC 19         // static chunks (KS/32)
#define XH 1032        // h0/h1 bf16 row stride
#define W0S 1640       // W0 LDS row stride (1632 + pad)
#define W1STR 1032
#define NBLK 256
#define NTHR 512

// barrier tree: 16 groups x 16 blocks, 17 padded slots (16 u32 each)
#define NGRP 16
#define GSZ  16
#define BSLOTS 272

typedef __attribute__((ext_vector_type(4))) float f32x4;
typedef __attribute__((ext_vector_type(8))) short s16x8;
typedef unsigned long long u64;

// LDS offsets (bytes)
#define OFF_W0    0          // 16*1640*2 = 52480
#define OFF_W1I   52480      // 33024
#define OFF_W1H   85504      // 33024
#define OFF_GRED  118528     // 16384
#define OFF_GSUM  134912     // 2048
#define OFF_C0    136960     // 512
#define OFF_C1    137472     // 512
#define OFF_APOOL 137984     // smw 256 + red 64 f32 = 1280
#define LDS_TOTAL 139264

// ws offsets (bytes)
#define WS_XSTAT 0                 // 400*32*608*2 = 15,564,800
#define WS_H0B   15564800          // 2*32*1032*2 = 132,096
#define WS_H1B   15696896          // 132,096
#define WS_H1F   15828992          // 2*32*1024*4 = 262,144
#define WS_ESC   16091136          // 25,600
#define WS_CST   16116736          // 2*32*512*4 = 131,072 (cm | cs)
#define WS_BAR   16247808          // 401*272*4 = 436,288

__device__ __forceinline__ float sigmf(float x){ return 1.0f/(1.0f+expf(-x)); }

__device__ __forceinline__ unsigned short f2bf(float v){
  unsigned int u = __float_as_uint(v);
  u += 0x7fffu + ((u >> 16) & 1u);
  return (unsigned short)(u >> 16);
}

// ---- agent-scope coherent accessors; RELAXED => no cache-maintenance ops ----
__device__ __forceinline__ void st64a(void* p, u64 v){
  __hip_atomic_store((u64*)p, v, __ATOMIC_RELAXED, __HIP_MEMORY_SCOPE_AGENT);
}
__device__ __forceinline__ u64 ld64a(const void* p){
  return __hip_atomic_load((const u64*)p, __ATOMIC_RELAXED, __HIP_MEMORY_SCOPE_AGENT);
}
__device__ __forceinline__ float2 ld2f(const float* p){
  u64 q = ld64a(p);
  float2 r; r.x = __uint_as_float((unsigned)q); r.y = __uint_as_float((unsigned)(q >> 32));
  return r;
}
__device__ __forceinline__ s16x8 ldA(const unsigned short* p){
  union { u64 q[2]; s16x8 v; } u;
  u.q[0] = ld64a(p); u.q[1] = ld64a(p + 4);
  return u.v;
}
__device__ __forceinline__ u64 pk2f(float a, float b){
  return ((u64)__float_as_uint(b) << 32) | (u64)__float_as_uint(a);
}

// Split-phase one-shot tree grid barrier (R8/R9/R10-proven RMW mechanism).
__device__ __forceinline__ void gbar_arrive(unsigned* slots){
  __builtin_amdgcn_s_waitcnt(0);
  __syncthreads();
  if (threadIdx.x == 0){
    const unsigned g = blockIdx.x >> 4;
    unsigned prev = __hip_atomic_fetch_add(slots + g*16, 1u, __ATOMIC_RELAXED, __HIP_MEMORY_SCOPE_AGENT);
    if (prev == (unsigned)(GSZ-1))
      __hip_atomic_fetch_add(slots + NGRP*16, 1u, __ATOMIC_RELAXED, __HIP_MEMORY_SCOPE_AGENT);
  }
}
__device__ __forceinline__ void gbar_wait(unsigned* slots){
  if (threadIdx.x == 0){
    while (__hip_atomic_load(slots + NGRP*16, __ATOMIC_RELAXED, __HIP_MEMORY_SCOPE_AGENT) < (unsigned)NGRP)
      __builtin_amdgcn_s_sleep(1);
  }
  __syncthreads();
}

__device__ __forceinline__ float bsum(float v, float* red){
  #pragma unroll
  for (int o = 32; o; o >>= 1) v += __shfl_down(v, o);
  __syncthreads();
  if ((threadIdx.x & 63) == 0) red[threadIdx.x >> 6] = v;
  __syncthreads();
  float s = 0.f;
  #pragma unroll
  for (int w2 = 0; w2 < 8; ++w2) s += red[w2];
  return s;
}
__device__ __forceinline__ float bmax(float v, float* red){
  #pragma unroll
  for (int o = 32; o; o >>= 1) v = fmaxf(v, __shfl_down(v, o));
  __syncthreads();
  if ((threadIdx.x & 63) == 0) red[threadIdx.x >> 6] = v;
  __syncthreads();
  float s = -3.4e38f;
  #pragma unroll
  for (int w2 = 0; w2 < 8; ++w2) s = fmaxf(s, red[w2]);
  return s;
}

// Cross-wave reduce of per-wave MFMA partials: Gred[8][512] -> gout[512].
// Caller must __syncthreads() after (before reading gout).
__device__ __forceinline__ void gred_reduce(f32x4 acc0, f32x4 acc1,
    float* __restrict__ Gred, float* __restrict__ gout)
{
  const int tid = threadIdx.x;
  const int w = tid >> 6, lane = tid & 63;
  const int row = lane & 15, kg = lane >> 4;
  float* gw = Gred + (w << 9) + row;
  #pragma unroll
  for (int v = 0; v < 4; ++v) {
    gw[((kg << 2) + v) << 4]      = acc0[v];
    gw[((kg << 2) + v + 16) << 4] = acc1[v];
  }
  __syncthreads();
  float s = 0.f;
  #pragma unroll
  for (int w8 = 0; w8 < 8; ++w8) s += Gred[(w8 << 9) + tid];
  gout[tid] = s;
}

__global__ void __launch_bounds__(NTHR, 1) decoder_kernel(
    const float* __restrict__ enc, const float* __restrict__ audio,
    const float* __restrict__ Wih0, const float* __restrict__ Whh0,
    const float* __restrict__ bih0, const float* __restrict__ bhh0,
    const float* __restrict__ Wih1, const float* __restrict__ Whh1,
    const float* __restrict__ bih1, const float* __restrict__ bhh1,
    const float* __restrict__ Wa, const float* __restrict__ ba,
    const float* __restrict__ Wfc, const float* __restrict__ bfc,
    float* __restrict__ out, float* __restrict__ ws)
{
  cg::grid_group grid = cg::this_grid();
  extern __shared__ char lds[];
  unsigned short* W0  = (unsigned short*)(lds + OFF_W0);
  unsigned short* W1I = (unsigned short*)(lds + OFF_W1I);
  unsigned short* W1H = (unsigned short*)(lds + OFF_W1H);
  float* Gred = (float*)(lds + OFF_GRED);
  float* Gsum = (float*)(lds + OFF_GSUM);
  float* c0l  = (float*)(lds + OFF_C0);
  float* c1l  = (float*)(lds + OFF_C1);
  float* smw  = (float*)(lds + OFF_APOOL);
  float* red  = smw + 256;

  const int blk = blockIdx.x, tid = threadIdx.x;
  const int j = blk;                                // owns h-columns [4j, 4j+4)
  const int w = tid >> 6, lane = tid & 63;
  const int row = lane & 15, kg = lane >> 4;

  unsigned short* xstat = (unsigned short*)((char*)ws + WS_XSTAT);
  unsigned short* h0b   = (unsigned short*)((char*)ws + WS_H0B);
  unsigned short* h1b   = (unsigned short*)((char*)ws + WS_H1B);
  float* h1f  = (float*)((char*)ws + WS_H1F);
  float* esc  = (float*)((char*)ws + WS_ESC);
  float* cm   = (float*)((char*)ws + WS_CST);       // ctx_mean
  float* cs   = cm + BBAT*EE;                       // ctx_soft
  unsigned* bars = (unsigned*)((char*)ws + WS_BAR);

  // ---- prologue: weights -> LDS bf16 ----
  for (int i = tid; i < 16*W0S; i += NTHR) {
    int r = i / W0S, k = i - r*W0S;
    int n = (r & 3)*HH + 4*j + (r >> 2);
    float v = 0.f;
    if (k < IN0) v = Wih0[(size_t)n*IN0 + k];
    else if (k >= KS && k < KS + HH) v = Whh0[(size_t)n*HH + (k - KS)];
    W0[i] = f2bf(v);
  }
  for (int i = tid; i < 16*W1STR; i += NTHR) {
    int r = i / W1STR, k = i - r*W1STR;
    int n = (r & 3)*HH + 4*j + (r >> 2);
    W1I[i] = (k < HH) ? f2bf(Wih1[(size_t)n*HH + k]) : (unsigned short)0;
    W1H[i] = (k < HH) ? f2bf(Whh1[(size_t)n*HH + k]) : (unsigned short)0;
  }
  if (tid < 128) { c0l[tid] = 0.f; c1l[tid] = 0.f; }
  for (int i = blk*NTHR + tid; i < 2*BBAT*XH; i += NBLK*NTHR) { h0b[i] = 0; h1b[i] = 0; }
  for (int i = blk*NTHR + tid; i < 2*BBAT*HH; i += NBLK*NTHR) h1f[i] = 0.f;
  for (int i = blk*NTHR + tid; i < (TT+1)*BSLOTS; i += NBLK*NTHR) bars[i] = 0u;
  for (int r2 = blk; r2 < BBAT*SE; r2 += NBLK) {
    float pp = tanhf(enc[(size_t)r2*EE + tid]) * Wa[HH + tid];   // EE == NTHR
    pp = bsum(pp, red);
    if (tid == 0) esc[r2] = pp;
  }
  grid.sync();

  // ---- static softmax + contexts (softmax is h1-invariant; R10-validated) ----
  if (blk < BBAT) {
    const int b = blk;
    float sc = (tid < SE) ? esc[b*SE + tid] : -3.4e38f;
    float mx = bmax(sc, red);
    float ex = (tid < SE) ? expf(sc - mx) : 0.f;
    float den = bsum(ex, red);
    if (tid < SE) smw[tid] = ex / den;
    __syncthreads();
    const int e = tid;                                // EE == NTHR
    float as = 0.f, am = 0.f;
    for (int s = 0; s < SE; ++s) {
      float v = enc[((size_t)b*SE + s)*EE + e];
      as = fmaf(smw[s], v, as);
      am += v;
    }
    cm[b*EE + e] = am * (1.0f/(float)SE);
    cs[b*EE + e] = as;
  }
  grid.sync();

  // ---- fill static panel xstat[t][b][608] = [x_t | ctx | 0] bf16 ----
  for (int t2 = blk; t2 < TT; t2 += NBLK) {
    const float* cx = (t2 == 0) ? cm : cs;
    for (int b = 0; b < BBAT; ++b) {
      for (int k = tid; k < KS; k += NTHR) {
        float v;
        if (k < MM)        v = audio[((size_t)b*TT + t2)*MM + k];
        else if (k < IN0)  v = cx[b*EE + (k - MM)];
        else               v = 0.f;
        xstat[((size_t)t2*BBAT + b)*KS + k] = f2bf(v);
      }
    }
  }
  grid.sync();

  const f32x4 z4 = {0.f,0.f,0.f,0.f};
  f32x4 accP0 = z4, accP1 = z4;
  { // initial LSTM0(0) static part (h0(-1)=0 contributes nothing)
    const unsigned short* xs = xstat;
    for (int c = w; c < NSC; c += 8) {
      const int off = (c << 5) + (kg << 3);
      s16x8 a0 = *(const s16x8*)(xs + (size_t)row*KS + off);
      s16x8 a1 = *(const s16x8*)(xs + (size_t)(row+16)*KS + off);
      s16x8 bw = *(const s16x8*)(W0 + row*W0S + off);
      accP0 = __builtin_amdgcn_mfma_f32_16x16x32_bf16(a0, bw, accP0, 0, 0, 0);
      accP1 = __builtin_amdgcn_mfma_f32_16x16x32_bf16(a1, bw, accP1, 0, 0, 0);
    }
  }

  for (int t = 0; t < TT; ++t) {
    unsigned short* h0W = h0b + (t&1)*BBAT*XH;
    const unsigned short* h0R = h0W;
    const unsigned short* h1R = h1b + ((t&1)^1)*BBAT*XH;
    unsigned short* h1W = h1b + (t&1)*BBAT*XH;
    const float* h1fR = h1f + ((t&1)^1)*BBAT*HH;
    float* h1fW = h1f + (t&1)*BBAT*HH;

    // ===== finish LSTM0(t): reduce accP, gates, publish h0(t) =====
    gred_reduce(accP0, accP1, Gred, Gsum);
    __syncthreads();
    if (tid < BBAT) {
      const int b = tid;
      u64 hp = 0;
      #pragma unroll
      for (int p = 0; p < 4; ++p) {
        f32x4 gv = *(const f32x4*)(Gsum + (b << 4) + (p << 2));
        const int nb = 4*j + p;
        float gi = gv[0] + bih0[nb]        + bhh0[nb];
        float gf = gv[1] + bih0[HH + nb]   + bhh0[HH + nb];
        float gg = gv[2] + bih0[2*HH + nb] + bhh0[2*HH + nb];
        float go = gv[3] + bih0[3*HH + nb] + bhh0[3*HH + nb];
        float cn = sigmf(gf) * c0l[p*32 + b] + sigmf(gi) * tanhf(gg);
        c0l[p*32 + b] = cn;
        hp |= (u64)f2bf(sigmf(go) * tanhf(cn)) << (16*p);
      }
      st64a(h0W + (size_t)b*XH + 4*j, hp);
    }
    gbar_arrive(bars + t*BSLOTS);
    // --- barrier window: static chunks of LSTM0(t+1) (cached, race-free) ---
    accP0 = z4; accP1 = z4;
    if (t + 1 < TT) {
      const unsigned short* xs = xstat + (size_t)(t+1)*BBAT*KS;
      for (int c = w; c < NSC; c += 8) {
        const int off = (c << 5) + (kg << 3);
        s16x8 a0 = *(const s16x8*)(xs + (size_t)row*KS + off);
        s16x8 a1 = *(const s16x8*)(xs + (size_t)(row+16)*KS + off);
        s16x8 bw = *(const s16x8*)(W0 + row*W0S + off);
        accP0 = __builtin_amdgcn_mfma_f32_16x16x32_bf16(a0, bw, accP0, 0, 0, 0);
        accP1 = __builtin_amdgcn_mfma_f32_16x16x32_bf16(a1, bw, accP1, 0, 0, 0);
      }
    }
    gbar_wait(bars + t*BSLOTS);

    // ===== exposed: LSTM1(t) gemms + h0-part of LSTM0(t+1), shared A-frags =====
    s16x8 A0h[4], A1h[4], A0g[4], A1g[4];
    #pragma unroll
    for (int i = 0; i < 4; ++i) {
      const int c = w + (i << 3);
      const int off = (c << 5) + (kg << 3);
      A0h[i] = ldA(h0R + (size_t)row*XH + off);
      A1h[i] = ldA(h0R + (size_t)(row+16)*XH + off);
      A0g[i] = ldA(h1R + (size_t)row*XH + off);
      A1g[i] = ldA(h1R + (size_t)(row+16)*XH + off);
    }
    if (t > 0) {   // FC pred(t-1) overlapped under the fine-grained load latency
      for (int u = w; u < 10; u += 8) {
        int idx = j*10 + u;
        int b = idx / MM, m = idx - b*MM;
        float pp = 0.f;
        #pragma unroll
        for (int cq = 0; cq < 4; ++cq) {
          float2 h0v = ld2f(h1fR + (size_t)b*HH + cq*256 + lane*4);
          float2 h1v = ld2f(h1fR + (size_t)b*HH + cq*256 + lane*4 + 2);
          float4 wv = *(const float4*)(Wfc + (size_t)m*HH + cq*256 + lane*4);
          pp = fmaf(h0v.x,wv.x, fmaf(h0v.y,wv.y, fmaf(h1v.x,wv.z, fmaf(h1v.y,wv.w, pp))));
        }
        #pragma unroll
        for (int o2 = 32; o2; o2 >>= 1) pp += __shfl_down(pp, o2);
        if (lane == 0) out[((size_t)b*TT + (t-1))*MM + m] = pp + bfc[m];
      }
    }
    f32x4 q0 = z4, q1 = z4;
    #pragma unroll
    for (int i = 0; i < 4; ++i) {
      const int c = w + (i << 3);
      const int off = (c << 5) + (kg << 3);
      s16x8 b1 = *(const s16x8*)(W1I + row*W1STR + off);
      q0 = __builtin_amdgcn_mfma_f32_16x16x32_bf16(A0h[i], b1, q0, 0, 0, 0);
      q1 = __builtin_amdgcn_mfma_f32_16x16x32_bf16(A1h[i], b1, q1, 0, 0, 0);
      s16x8 b0 = *(const s16x8*)(W0 + row*W0S + KS + off);
      accP0 = __builtin_amdgcn_mfma_f32_16x16x32_bf16(A0h[i], b0, accP0, 0, 0, 0);
      accP1 = __builtin_amdgcn_mfma_f32_16x16x32_bf16(A1h[i], b0, accP1, 0, 0, 0);
      s16x8 b2 = *(const s16x8*)(W1H + row*W1STR + off);
      q0 = __builtin_amdgcn_mfma_f32_16x16x32_bf16(A0g[i], b2, q0, 0, 0, 0);
      q1 = __builtin_amdgcn_mfma_f32_16x16x32_bf16(A1g[i], b2, q1, 0, 0, 0);
    }
    gred_reduce(q0, q1, Gred, Gsum);
    __syncthreads();
    if (tid < BBAT) {
      const int b = tid;
      u64 hp = 0;
      float hf[4];
      #pragma unroll
      for (int p = 0; p < 4; ++p) {
        f32x4 gv = *(const f32x4*)(Gsum + (b << 4) + (p << 2));
        const int nb = 4*j + p;
        float gi = gv[0] + bih1[nb]        + bhh1[nb];
        float gf = gv[1] + bih1[HH + nb]   + bhh1[HH + nb];
        float gg = gv[2] + bih1[2*HH + nb] + bhh1[2*HH + nb];
        float go = gv[3] + bih1[3*HH + nb] + bhh1[3*HH + nb];
        float cn = sigmf(gf) * c1l[p*32 + b] + sigmf(gi) * tanhf(gg);
        c1l[p*32 + b] = cn;
        float hn = sigmf(go) * tanhf(cn);
        hf[p] = hn;
        hp |= (u64)f2bf(hn) << (16*p);
      }
      st64a(h1W + (size_t)b*XH + 4*j, hp);
      st64a(h1fW + (size_t)b*HH + 4*j,     pk2f(hf[0], hf[1]));
      st64a(h1fW + (size_t)b*HH + 4*j + 2, pk2f(hf[2], hf[3]));
    }
  }

  // ---- final barrier + FC pred(TT-1) ----
  gbar_arrive(bars + TT*BSLOTS);
  gbar_wait(bars + TT*BSLOTS);
  {
    const float* h1fL = h1f + ((TT-1)&1)*BBAT*HH;
    for (int u = w; u < 10; u += 8) {
      int idx = j*10 + u;
      int b = idx / MM, m = idx - b*MM;
      float pp = 0.f;
      #pragma unroll
      for (int cq = 0; cq < 4; ++cq) {
        float2 h0v = ld2f(h1fL + (size_t)b*HH + cq*256 + lane*4);
        float2 h1v = ld2f(h1fL + (size_t)b*HH + cq*256 + lane*4 + 2);
        float4 wv = *(const float4*)(Wfc + (size_t)m*HH + cq*256 + lane*4);
        pp = fmaf(h0v.x,wv.x, fmaf(h0v.y,wv.y, fmaf(h1v.x,wv.z, fmaf(h1v.y,wv.w, pp))));
      }
      #pragma unroll
      for (int o2 = 32; o2; o2 >>= 1) pp += __shfl_down(pp, o2);
      if (lane == 0) out[((size_t)b*TT + (TT-1))*MM + m] = pp + bfc[m];
    }
  }
}

extern "C" void kernel_launch(void* const* d_in, const int* in_sizes, int n_in,
                              void* d_out, int out_size, void* d_ws, size_t ws_size,
                              hipStream_t stream) {
  const float* enc  = (const float*)d_in[0];
  const float* audio= (const float*)d_in[1];
  const float* Wih0 = (const float*)d_in[2];
  const float* Whh0 = (const float*)d_in[3];
  const float* bih0 = (const float*)d_in[4];
  const float* bhh0 = (const float*)d_in[5];
  const float* Wih1 = (const float*)d_in[6];
  const float* Whh1 = (const float*)d_in[7];
  const float* bih1 = (const float*)d_in[8];
  const float* bhh1 = (const float*)d_in[9];
  const float* Wa   = (const float*)d_in[10];
  const float* ba   = (const float*)d_in[11];
  const float* Wfc  = (const float*)d_in[12];
  const float* bfc  = (const float*)d_in[13];
  float* out = (float*)d_out;
  float* ws  = (float*)d_ws;

  (void)hipFuncSetAttribute((const void*)decoder_kernel,
                            hipFuncAttributeMaxDynamicSharedMemorySize, LDS_TOTAL);

  void* args[] = { &enc,&audio,&Wih0,&Whh0,&bih0,&bhh0,&Wih1,&Whh1,&bih1,&bhh1,
                   &Wa,&ba,&Wfc,&bfc,&out,&ws };
  hipLaunchCooperativeKernel((const void*)decoder_kernel, dim3(NBLK), dim3(NTHR),
                             args, LDS_TOTAL, stream);
}

// Round 12
// 4828.181 us; speedup vs baseline: 14.5269x; 1.1809x over previous
//
#include <hip/hip_runtime.h>
#include <hip/hip_cooperative_groups.h>

namespace cg = cooperative_groups;

#define BBAT 32
#define SE 200
#define TT 400
#define MM 80
#define EE 512
#define HH 1024
#define IN0 592
#define KS 608         // static panel row: x(80) + ctx(512) + zero pad(16)
#define NSC 19         // static chunks (KS/32)
#define XH 1032        // h0/h1 bf16 row stride
#define W0S 1640       // W0 LDS row stride (608 static + 1024 hh + 8 pad)
#define W1STR 1032
#define NBLK 256
#define NTHR 512

// barrier tree: 16 groups x 16 blocks, 17 padded slots (16 u32 each)
#define NGRP 16
#define GSZ  16
#define BSLOTS 272

typedef __attribute__((ext_vector_type(4))) float f32x4;
typedef __attribute__((ext_vector_type(8))) short s16x8;
typedef unsigned long long u64;

// LDS offsets (bytes)
#define OFF_W0    0          // 16*1640*2 = 52480
#define OFF_W1I   52480      // 33024
#define OFF_W1H   85504      // 33024
#define OFF_GRED  118528     // 8 waves x 1024 f32 = 32768 (2 planes)
#define OFF_GSUM  151296     // 1024 f32 = 4096 (plane0: LSTM0, plane1: LSTM1)
#define OFF_C0    155392     // 512
#define OFF_C1    155904     // 512
#define LDS_TOTAL 156416
// prologue-only smw/red alias the GRED region (no temporal overlap)

// ws offsets (bytes)
#define WS_XSTAT 0                 // 400*32*608*2 = 15,564,800
#define WS_H0B   15564800          // 2*32*1032*2 = 132,096
#define WS_H1B   15696896          // 132,096
#define WS_H1F   15828992          // 3*32*1024*4 = 393,216 (triple buffer)
#define WS_ESC   16222208          // 25,600
#define WS_CST   16247808          // 131,072 (cm | cs)
#define WS_BAR   16378880          // 402*272*4 = 437,376

__device__ __forceinline__ float sigmf(float x){ return 1.0f/(1.0f+expf(-x)); }

__device__ __forceinline__ unsigned short f2bf(float v){
  unsigned int u = __float_as_uint(v);
  u += 0x7fffu + ((u >> 16) & 1u);
  return (unsigned short)(u >> 16);
}

// ---- agent-scope coherent accessors; RELAXED => no cache-maintenance ops ----
__device__ __forceinline__ void st64a(void* p, u64 v){
  __hip_atomic_store((u64*)p, v, __ATOMIC_RELAXED, __HIP_MEMORY_SCOPE_AGENT);
}
__device__ __forceinline__ u64 ld64a(const void* p){
  return __hip_atomic_load((const u64*)p, __ATOMIC_RELAXED, __HIP_MEMORY_SCOPE_AGENT);
}
__device__ __forceinline__ float2 ld2f(const float* p){
  u64 q = ld64a(p);
  float2 r; r.x = __uint_as_float((unsigned)q); r.y = __uint_as_float((unsigned)(q >> 32));
  return r;
}
__device__ __forceinline__ s16x8 ldA(const unsigned short* p){
  union { u64 q[2]; s16x8 v; } u;
  u.q[0] = ld64a(p); u.q[1] = ld64a(p + 4);
  return u.v;
}
__device__ __forceinline__ u64 pk2f(float a, float b){
  return ((u64)__float_as_uint(b) << 32) | (u64)__float_as_uint(a);
}

// Split-phase one-shot tree grid barrier (R8-R11 proven RMW mechanism).
__device__ __forceinline__ void gbar_arrive(unsigned* slots){
  __builtin_amdgcn_s_waitcnt(0);
  __syncthreads();
  if (threadIdx.x == 0){
    const unsigned g = blockIdx.x >> 4;
    unsigned prev = __hip_atomic_fetch_add(slots + g*16, 1u, __ATOMIC_RELAXED, __HIP_MEMORY_SCOPE_AGENT);
    if (prev == (unsigned)(GSZ-1))
      __hip_atomic_fetch_add(slots + NGRP*16, 1u, __ATOMIC_RELAXED, __HIP_MEMORY_SCOPE_AGENT);
  }
}
__device__ __forceinline__ void gbar_wait(unsigned* slots){
  if (threadIdx.x == 0){
    while (__hip_atomic_load(slots + NGRP*16, __ATOMIC_RELAXED, __HIP_MEMORY_SCOPE_AGENT) < (unsigned)NGRP)
      __builtin_amdgcn_s_sleep(1);
  }
  __syncthreads();
}

__device__ __forceinline__ float bsum(float v, float* red){
  #pragma unroll
  for (int o = 32; o; o >>= 1) v += __shfl_down(v, o);
  __syncthreads();
  if ((threadIdx.x & 63) == 0) red[threadIdx.x >> 6] = v;
  __syncthreads();
  float s = 0.f;
  #pragma unroll
  for (int w2 = 0; w2 < 8; ++w2) s += red[w2];
  return s;
}
__device__ __forceinline__ float bmax(float v, float* red){
  #pragma unroll
  for (int o = 32; o; o >>= 1) v = fmaxf(v, __shfl_down(v, o));
  __syncthreads();
  if ((threadIdx.x & 63) == 0) red[threadIdx.x >> 6] = v;
  __syncthreads();
  float s = -3.4e38f;
  #pragma unroll
  for (int w2 = 0; w2 < 8; ++w2) s = fmaxf(s, red[w2]);
  return s;
}

#define MFMA16(a,b,c) __builtin_amdgcn_mfma_f32_16x16x32_bf16((a),(b),(c),0,0,0)

// static-panel MFMAs for LSTM0 time tau (cached loads; xstat stable after prologue)
__device__ __forceinline__ void mfma_static(const unsigned short* __restrict__ xs,
    const unsigned short* __restrict__ W0, int w, int row, int kg,
    f32x4& acc0, f32x4& acc1)
{
  for (int c = w; c < NSC; c += 8) {
    const int off = (c << 5) + (kg << 3);
    s16x8 a0 = *(const s16x8*)(xs + (size_t)row*KS + off);
    s16x8 a1 = *(const s16x8*)(xs + (size_t)(row+16)*KS + off);
    s16x8 bw = *(const s16x8*)(W0 + row*W0S + off);
    acc0 = MFMA16(a0, bw, acc0);
    acc1 = MFMA16(a1, bw, acc1);
  }
}

__global__ void __launch_bounds__(NTHR, 1) decoder_kernel(
    const float* __restrict__ enc, const float* __restrict__ audio,
    const float* __restrict__ Wih0, const float* __restrict__ Whh0,
    const float* __restrict__ bih0, const float* __restrict__ bhh0,
    const float* __restrict__ Wih1, const float* __restrict__ Whh1,
    const float* __restrict__ bih1, const float* __restrict__ bhh1,
    const float* __restrict__ Wa, const float* __restrict__ ba,
    const float* __restrict__ Wfc, const float* __restrict__ bfc,
    float* __restrict__ out, float* __restrict__ ws)
{
  cg::grid_group grid = cg::this_grid();
  extern __shared__ char lds[];
  unsigned short* W0  = (unsigned short*)(lds + OFF_W0);
  unsigned short* W1I = (unsigned short*)(lds + OFF_W1I);
  unsigned short* W1H = (unsigned short*)(lds + OFF_W1H);
  float* Gred = (float*)(lds + OFF_GRED);
  float* Gsum = (float*)(lds + OFF_GSUM);    // [0,512) LSTM0, [512,1024) LSTM1
  float* c0l  = (float*)(lds + OFF_C0);
  float* c1l  = (float*)(lds + OFF_C1);
  float* smw  = Gred;                        // prologue-only aliases
  float* red  = Gred + 256;

  const int blk = blockIdx.x, tid = threadIdx.x;
  const int j = blk;                                // owns h-columns [4j, 4j+4)
  const int w = tid >> 6, lane = tid & 63;
  const int row = lane & 15, kg = lane >> 4;

  unsigned short* xstat = (unsigned short*)((char*)ws + WS_XSTAT);
  unsigned short* h0b   = (unsigned short*)((char*)ws + WS_H0B);
  unsigned short* h1b   = (unsigned short*)((char*)ws + WS_H1B);
  float* h1f  = (float*)((char*)ws + WS_H1F);       // 3 parity buffers
  float* esc  = (float*)((char*)ws + WS_ESC);
  float* cm   = (float*)((char*)ws + WS_CST);
  float* cs   = cm + BBAT*EE;
  unsigned* bars = (unsigned*)((char*)ws + WS_BAR);

  // ---- prologue: weights -> LDS bf16 ----
  for (int i = tid; i < 16*W0S; i += NTHR) {
    int r = i / W0S, k = i - r*W0S;
    int n = (r & 3)*HH + 4*j + (r >> 2);
    float v = 0.f;
    if (k < IN0) v = Wih0[(size_t)n*IN0 + k];
    else if (k >= KS && k < KS + HH) v = Whh0[(size_t)n*HH + (k - KS)];
    W0[i] = f2bf(v);
  }
  for (int i = tid; i < 16*W1STR; i += NTHR) {
    int r = i / W1STR, k = i - r*W1STR;
    int n = (r & 3)*HH + 4*j + (r >> 2);
    W1I[i] = (k < HH) ? f2bf(Wih1[(size_t)n*HH + k]) : (unsigned short)0;
    W1H[i] = (k < HH) ? f2bf(Whh1[(size_t)n*HH + k]) : (unsigned short)0;
  }
  if (tid < 128) { c0l[tid] = 0.f; c1l[tid] = 0.f; }
  for (int i = blk*NTHR + tid; i < 2*BBAT*XH; i += NBLK*NTHR) { h0b[i] = 0; h1b[i] = 0; }
  for (int i = blk*NTHR + tid; i < 3*BBAT*HH; i += NBLK*NTHR) h1f[i] = 0.f;
  for (int i = blk*NTHR + tid; i < (TT+2)*BSLOTS; i += NBLK*NTHR) bars[i] = 0u;
  for (int r2 = blk; r2 < BBAT*SE; r2 += NBLK) {
    float pp = tanhf(enc[(size_t)r2*EE + tid]) * Wa[HH + tid];   // EE == NTHR
    pp = bsum(pp, red);
    if (tid == 0) esc[r2] = pp;
  }
  grid.sync();

  // ---- static softmax + contexts (softmax is h1-invariant; R10/R11-validated) ----
  if (blk < BBAT) {
    const int b = blk;
    float sc = (tid < SE) ? esc[b*SE + tid] : -3.4e38f;
    float mx = bmax(sc, red);
    float ex = (tid < SE) ? expf(sc - mx) : 0.f;
    float den = bsum(ex, red);
    if (tid < SE) smw[tid] = ex / den;
    __syncthreads();
    const int e = tid;                                // EE == NTHR
    float as = 0.f, am = 0.f;
    for (int s = 0; s < SE; ++s) {
      float v = enc[((size_t)b*SE + s)*EE + e];
      as = fmaf(smw[s], v, as);
      am += v;
    }
    cm[b*EE + e] = am * (1.0f/(float)SE);
    cs[b*EE + e] = as;
  }
  grid.sync();

  // ---- fill static panel xstat[t][b][608] = [x_t | ctx | 0] bf16 ----
  for (int t2 = blk; t2 < TT; t2 += NBLK) {
    const float* cx = (t2 == 0) ? cm : cs;
    for (int b = 0; b < BBAT; ++b) {
      for (int k = tid; k < KS; k += NTHR) {
        float v;
        if (k < MM)        v = audio[((size_t)b*TT + t2)*MM + k];
        else if (k < IN0)  v = cx[b*EE + (k - MM)];
        else               v = 0.f;
        xstat[((size_t)t2*BBAT + b)*KS + k] = f2bf(v);
      }
    }
  }
  grid.sync();

  const f32x4 z4 = {0.f,0.f,0.f,0.f};
  f32x4 accP0 = z4, accP1 = z4;

  // ---- pre-loop: LSTM0(0) = static(0) (h0(-1)=0); publish h0(0); B(0) ----
  mfma_static(xstat, W0, w, row, kg, accP0, accP1);
  {
    float* gw = Gred + (w << 10) + row;
    #pragma unroll
    for (int v = 0; v < 4; ++v) {
      gw[(((kg<<2)+v)    << 4)] = accP0[v];
      gw[(((kg<<2)+v+16) << 4)] = accP1[v];
    }
    __syncthreads();
    float s0 = 0.f;
    #pragma unroll
    for (int w8 = 0; w8 < 8; ++w8) s0 += Gred[(w8 << 10) + tid];
    Gsum[tid] = s0;
    __syncthreads();
    if (tid >= 64 && tid < 64 + BBAT) {
      const int b = tid - 64;
      u64 hp = 0;
      #pragma unroll
      for (int p = 0; p < 4; ++p) {
        f32x4 gv = *(const f32x4*)(Gsum + (b << 4) + (p << 2));
        const int nb = 4*j + p;
        float gi = gv[0] + bih0[nb]        + bhh0[nb];
        float gf = gv[1] + bih0[HH + nb]   + bhh0[HH + nb];
        float gg = gv[2] + bih0[2*HH + nb] + bhh0[2*HH + nb];
        float go = gv[3] + bih0[3*HH + nb] + bhh0[3*HH + nb];
        float cn = sigmf(gf) * 0.f + sigmf(gi) * tanhf(gg);
        c0l[p*32 + b] = cn;
        hp |= (u64)f2bf(sigmf(go) * tanhf(cn)) << (16*p);
      }
      st64a(h0b + (size_t)b*XH + 4*j, hp);   // h0(0) -> buf 0
    }
  }
  gbar_arrive(bars);
  accP0 = z4; accP1 = z4;
  mfma_static(xstat + (size_t)BBAT*KS, W0, w, row, kg, accP0, accP1);  // static(1)
  gbar_wait(bars);

  for (int t = 0; t < TT; ++t) {
    const unsigned short* h0R = h0b + (t&1)*BBAT*XH;           // h0(t)
    const unsigned short* h1R = h1b + ((t&1)^1)*BBAT*XH;       // h1(t-1)
    unsigned short* h1W = h1b + (t&1)*BBAT*XH;                 // h1(t)
    unsigned short* h0Wn = h0b + ((t+1)&1)*BBAT*XH;            // h0(t+1)
    float* h1fW = h1f + (size_t)(t % 3)*BBAT*HH;

    // ===== exposed: batch fine-grained loads, 40 MFMA, merged reduce, dual epi =====
    s16x8 A0h[4], A1h[4], A0g[4], A1g[4];
    #pragma unroll
    for (int i = 0; i < 4; ++i) {
      const int off = ((w + (i << 3)) << 5) + (kg << 3);
      A0h[i] = ldA(h0R + (size_t)row*XH + off);
      A1h[i] = ldA(h0R + (size_t)(row+16)*XH + off);
      A0g[i] = ldA(h1R + (size_t)row*XH + off);
      A1g[i] = ldA(h1R + (size_t)(row+16)*XH + off);
    }
    f32x4 q0 = z4, q1 = z4;
    #pragma unroll
    for (int i = 0; i < 4; ++i) {
      const int off = ((w + (i << 3)) << 5) + (kg << 3);
      s16x8 b1 = *(const s16x8*)(W1I + row*W1STR + off);
      q0 = MFMA16(A0h[i], b1, q0);
      q1 = MFMA16(A1h[i], b1, q1);
      s16x8 b0 = *(const s16x8*)(W0 + row*W0S + KS + off);
      accP0 = MFMA16(A0h[i], b0, accP0);
      accP1 = MFMA16(A1h[i], b0, accP1);
      s16x8 b2 = *(const s16x8*)(W1H + row*W1STR + off);
      q0 = MFMA16(A0g[i], b2, q0);
      q1 = MFMA16(A1g[i], b2, q1);
    }
    { // merged two-plane reduce
      float* gw = Gred + (w << 10) + row;
      #pragma unroll
      for (int v = 0; v < 4; ++v) {
        gw[(((kg<<2)+v)    << 4)]       = accP0[v];
        gw[(((kg<<2)+v+16) << 4)]       = accP1[v];
        gw[512 + (((kg<<2)+v)    << 4)] = q0[v];
        gw[512 + (((kg<<2)+v+16) << 4)] = q1[v];
      }
      __syncthreads();
      float s0 = 0.f, s1 = 0.f;
      #pragma unroll
      for (int w8 = 0; w8 < 8; ++w8) {
        s0 += Gred[(w8 << 10) + tid];
        s1 += Gred[(w8 << 10) + 512 + tid];
      }
      Gsum[tid] = s0;
      Gsum[512 + tid] = s1;
      __syncthreads();
    }
    if (tid < BBAT) {                       // wave0: LSTM1(t) -> h1(t)
      const int b = tid;
      u64 hp = 0; float hf[4];
      #pragma unroll
      for (int p = 0; p < 4; ++p) {
        f32x4 gv = *(const f32x4*)(Gsum + 512 + (b << 4) + (p << 2));
        const int nb = 4*j + p;
        float gi = gv[0] + bih1[nb]        + bhh1[nb];
        float gf = gv[1] + bih1[HH + nb]   + bhh1[HH + nb];
        float gg = gv[2] + bih1[2*HH + nb] + bhh1[2*HH + nb];
        float go = gv[3] + bih1[3*HH + nb] + bhh1[3*HH + nb];
        float cn = sigmf(gf) * c1l[p*32 + b] + sigmf(gi) * tanhf(gg);
        c1l[p*32 + b] = cn;
        float hn = sigmf(go) * tanhf(cn);
        hf[p] = hn;
        hp |= (u64)f2bf(hn) << (16*p);
      }
      st64a(h1W + (size_t)b*XH + 4*j, hp);
      st64a(h1fW + (size_t)b*HH + 4*j,     pk2f(hf[0], hf[1]));
      st64a(h1fW + (size_t)b*HH + 4*j + 2, pk2f(hf[2], hf[3]));
    } else if (tid >= 64 && tid < 64 + BBAT) {   // wave1: LSTM0(t+1) -> h0(t+1)
      const int b = tid - 64;
      u64 hp = 0;
      #pragma unroll
      for (int p = 0; p < 4; ++p) {
        f32x4 gv = *(const f32x4*)(Gsum + (b << 4) + (p << 2));
        const int nb = 4*j + p;
        float gi = gv[0] + bih0[nb]        + bhh0[nb];
        float gf = gv[1] + bih0[HH + nb]   + bhh0[HH + nb];
        float gg = gv[2] + bih0[2*HH + nb] + bhh0[2*HH + nb];
        float go = gv[3] + bih0[3*HH + nb] + bhh0[3*HH + nb];
        float cn = sigmf(gf) * c0l[p*32 + b] + sigmf(gi) * tanhf(gg);
        c0l[p*32 + b] = cn;
        hp |= (u64)f2bf(sigmf(go) * tanhf(cn)) << (16*p);
      }
      st64a(h0Wn + (size_t)b*XH + 4*j, hp);
    }
    gbar_arrive(bars + (size_t)(t+1)*BSLOTS);

    // ===== barrier window: static(t+2) MFMAs + FC pred(t-1) =====
    accP0 = z4; accP1 = z4;
    if (t + 2 < TT)
      mfma_static(xstat + (size_t)(t+2)*BBAT*KS, W0, w, row, kg, accP0, accP1);
    if (t >= 1) {   // FC(t-1): h1f(t-1) globally published since wait B(t)
      const float* h1fF = h1f + (size_t)((t-1) % 3)*BBAT*HH;
      for (int u = w; u < 10; u += 8) {
        int idx = j*10 + u;
        int b = idx / MM, m = idx - b*MM;
        float pp = 0.f;
        #pragma unroll
        for (int cq = 0; cq < 4; ++cq) {
          float2 h0v = ld2f(h1fF + (size_t)b*HH + cq*256 + lane*4);
          float2 h1v = ld2f(h1fF + (size_t)b*HH + cq*256 + lane*4 + 2);
          float4 wv = *(const float4*)(Wfc + (size_t)m*HH + cq*256 + lane*4);
          pp = fmaf(h0v.x,wv.x, fmaf(h0v.y,wv.y, fmaf(h1v.x,wv.z, fmaf(h1v.y,wv.w, pp))));
        }
        #pragma unroll
        for (int o2 = 32; o2; o2 >>= 1) pp += __shfl_down(pp, o2);
        if (lane == 0) out[((size_t)b*TT + (t-1))*MM + m] = pp + bfc[m];
      }
    }
    gbar_wait(bars + (size_t)(t+1)*BSLOTS);
  }

  // ---- epilogue: FC pred(TT-1) ----
  {
    const float* h1fL = h1f + (size_t)((TT-1) % 3)*BBAT*HH;
    for (int u = w; u < 10; u += 8) {
      int idx = j*10 + u;
      int b = idx / MM, m = idx - b*MM;
      float pp = 0.f;
      #pragma unroll
      for (int cq = 0; cq < 4; ++cq) {
        float2 h0v = ld2f(h1fL + (size_t)b*HH + cq*256 + lane*4);
        float2 h1v = ld2f(h1fL + (size_t)b*HH + cq*256 + lane*4 + 2);
        float4 wv = *(const float4*)(Wfc + (size_t)m*HH + cq*256 + lane*4);
        pp = fmaf(h0v.x,wv.x, fmaf(h0v.y,wv.y, fmaf(h1v.x,wv.z, fmaf(h1v.y,wv.w, pp))));
      }
      #pragma unroll
      for (int o2 = 32; o2; o2 >>= 1) pp += __shfl_down(pp, o2);
      if (lane == 0) out[((size_t)b*TT + (TT-1))*MM + m] = pp + bfc[m];
    }
  }
}

extern "C" void kernel_launch(void* const* d_in, const int* in_sizes, int n_in,
                              void* d_out, int out_size, void* d_ws, size_t ws_size,
                              hipStream_t stream) {
  const float* enc  = (const float*)d_in[0];
  const float* audio= (const float*)d_in[1];
  const float* Wih0 = (const float*)d_in[2];
  const float* Whh0 = (const float*)d_in[3];
  const float* bih0 = (const float*)d_in[4];
  const float* bhh0 = (const float*)d_in[5];
  const float* Wih1 = (const float*)d_in[6];
  const float* Whh1 = (const float*)d_in[7];
  const float* bih1 = (const float*)d_in[8];
  const float* bhh1 = (const float*)d_in[9];
  const float* Wa   = (const float*)d_in[10];
  const float* ba   = (const float*)d_in[11];
  const float* Wfc  = (const float*)d_in[12];
  const float* bfc  = (const float*)d_in[13];
  float* out = (float*)d_out;
  float* ws  = (float*)d_ws;

  (void)hipFuncSetAttribute((const void*)decoder_kernel,
                            hipFuncAttributeMaxDynamicSharedMemorySize, LDS_TOTAL);

  void* args[] = { &enc,&audio,&Wih0,&Whh0,&bih0,&bhh0,&Wih1,&Whh1,&bih1,&bhh1,
                   &Wa,&ba,&Wfc,&bfc,&out,&ws };
  hipLaunchCooperativeKernel((const void*)decoder_kernel, dim3(NBLK), dim3(NTHR),
                             args, LDS_TOTAL, stream);
}

// Round 13
// 3916.917 us; speedup vs baseline: 17.9066x; 1.2326x over previous
//
#include <hip/hip_runtime.h>
#include <hip/hip_cooperative_groups.h>

namespace cg = cooperative_groups;

#define BBAT 32
#define SE 200
#define TT 400
#define MM 80
#define EE 512
#define HH 1024
#define IN0 592
#define KS 608         // static panel row: x(80) + ctx(512) + zero pad(16)
#define NSC 19         // static chunks (KS/32)
#define XH 1032        // h0/h1 bf16 row stride (2064 B, 16B-aligned)
#define W0S 1640       // W0 LDS row stride (608 static + 1024 hh + 8 pad)
#define W1STR 1032
#define NBLK 256
#define NTHR 512

// barrier tree: 16 groups x 16 blocks, 17 padded slots (16 u32 each)
#define NGRP 16
#define GSZ  16
#define BSLOTS 272

typedef __attribute__((ext_vector_type(4))) float f32x4;
typedef __attribute__((ext_vector_type(8))) short s16x8;
typedef unsigned long long u64;

// LDS offsets (bytes)
#define OFF_W0    0          // 16*1640*2 = 52480
#define OFF_W1I   52480      // 33024
#define OFF_W1H   85504      // 33024
#define OFF_GRED  118528     // 8 waves x 1024 f32 = 32768 (2 planes)
#define OFF_GSUM  151296     // 1024 f32 = 4096 (plane0: LSTM0, plane1: LSTM1)
#define OFF_C0    155392     // 512
#define OFF_C1    155904     // 512
#define LDS_TOTAL 156416
// prologue-only smw/red alias the GRED region (no temporal overlap)

// ws offsets (bytes)
#define WS_XSTAT 0                 // 400*32*608*2 = 15,564,800
#define WS_H0B   15564800          // 2*32*1032*2 = 132,096
#define WS_H1B   15696896          // 132,096
#define WS_H1F   15828992          // 3*32*1024*4 = 393,216 (triple buffer)
#define WS_ESC   16222208          // 25,600
#define WS_CST   16247808          // 131,072 (cm | cs)
#define WS_BAR   16378880          // 402*272*4 = 437,376

__device__ __forceinline__ float sigmf(float x){ return 1.0f/(1.0f+expf(-x)); }

__device__ __forceinline__ unsigned short f2bf(float v){
  unsigned int u = __float_as_uint(v);
  u += 0x7fffu + ((u >> 16) & 1u);
  return (unsigned short)(u >> 16);
}

// ---- agent-scope coherent accessors; RELAXED => no cache-maintenance ops ----
__device__ __forceinline__ void st64a(void* p, u64 v){
  __hip_atomic_store((u64*)p, v, __ATOMIC_RELAXED, __HIP_MEMORY_SCOPE_AGENT);
}
__device__ __forceinline__ u64 ld64a(const void* p){
  return __hip_atomic_load((const u64*)p, __ATOMIC_RELAXED, __HIP_MEMORY_SCOPE_AGENT);
}
__device__ __forceinline__ float2 ld2f(const float* p){
  u64 q = ld64a(p);
  float2 r; r.x = __uint_as_float((unsigned)q); r.y = __uint_as_float((unsigned)(q >> 32));
  return r;
}
__device__ __forceinline__ u64 pk2f(float a, float b){
  return ((u64)__float_as_uint(b) << 32) | (u64)__float_as_uint(a);
}

// 4x 16B coherent loads (bypass L1/L2 via sc0 sc1 -> reads coherence point).
// Early-clobber outputs: async returns must not alias later load addresses.
#define LD4C(d0,d1,d2,d3,p0,p1,p2,p3) \
  asm volatile("global_load_dwordx4 %0, %4, off sc0 sc1\n\t" \
               "global_load_dwordx4 %1, %5, off sc0 sc1\n\t" \
               "global_load_dwordx4 %2, %6, off sc0 sc1\n\t" \
               "global_load_dwordx4 %3, %7, off sc0 sc1" \
               : "=&v"(d0), "=&v"(d1), "=&v"(d2), "=&v"(d3) \
               : "v"(p0), "v"(p1), "v"(p2), "v"(p3))

// Single waitcnt tying all 16 fragments as in-outs: every later use has a
// data-dependence on this asm's redefinition -> cannot be hoisted above it.
#define WAIT16(a0,a1,a2,a3,b0,b1,b2,b3,c0,c1,c2,c3,d0,d1,d2,d3) \
  asm volatile("s_waitcnt vmcnt(0)" \
    : "+v"(a0),"+v"(a1),"+v"(a2),"+v"(a3), \
      "+v"(b0),"+v"(b1),"+v"(b2),"+v"(b3), \
      "+v"(c0),"+v"(c1),"+v"(c2),"+v"(c3), \
      "+v"(d0),"+v"(d1),"+v"(d2),"+v"(d3))

// Split-phase one-shot tree grid barrier (R8-R12 proven RMW mechanism).
__device__ __forceinline__ void gbar_arrive(unsigned* slots){
  __builtin_amdgcn_s_waitcnt(0);
  __syncthreads();
  if (threadIdx.x == 0){
    const unsigned g = blockIdx.x >> 4;
    unsigned prev = __hip_atomic_fetch_add(slots + g*16, 1u, __ATOMIC_RELAXED, __HIP_MEMORY_SCOPE_AGENT);
    if (prev == (unsigned)(GSZ-1))
      __hip_atomic_fetch_add(slots + NGRP*16, 1u, __ATOMIC_RELAXED, __HIP_MEMORY_SCOPE_AGENT);
  }
}
__device__ __forceinline__ void gbar_wait(unsigned* slots){
  if (threadIdx.x == 0){
    while (__hip_atomic_load(slots + NGRP*16, __ATOMIC_RELAXED, __HIP_MEMORY_SCOPE_AGENT) < (unsigned)NGRP)
      __builtin_amdgcn_s_sleep(1);
  }
  __syncthreads();
}

__device__ __forceinline__ float bsum(float v, float* red){
  #pragma unroll
  for (int o = 32; o; o >>= 1) v += __shfl_down(v, o);
  __syncthreads();
  if ((threadIdx.x & 63) == 0) red[threadIdx.x >> 6] = v;
  __syncthreads();
  float s = 0.f;
  #pragma unroll
  for (int w2 = 0; w2 < 8; ++w2) s += red[w2];
  return s;
}
__device__ __forceinline__ float bmax(float v, float* red){
  #pragma unroll
  for (int o = 32; o; o >>= 1) v = fmaxf(v, __shfl_down(v, o));
  __syncthreads();
  if ((threadIdx.x & 63) == 0) red[threadIdx.x >> 6] = v;
  __syncthreads();
  float s = -3.4e38f;
  #pragma unroll
  for (int w2 = 0; w2 < 8; ++w2) s = fmaxf(s, red[w2]);
  return s;
}

#define MFMA16(a,b,c) __builtin_amdgcn_mfma_f32_16x16x32_bf16((a),(b),(c),0,0,0)

// static-panel MFMAs for LSTM0 time tau (cached loads; xstat stable after prologue)
__device__ __forceinline__ void mfma_static(const unsigned short* __restrict__ xs,
    const unsigned short* __restrict__ W0, int w, int row, int kg,
    f32x4& acc0, f32x4& acc1)
{
  for (int c = w; c < NSC; c += 8) {
    const int off = (c << 5) + (kg << 3);
    s16x8 a0 = *(const s16x8*)(xs + (size_t)row*KS + off);
    s16x8 a1 = *(const s16x8*)(xs + (size_t)(row+16)*KS + off);
    s16x8 bw = *(const s16x8*)(W0 + row*W0S + off);
    acc0 = MFMA16(a0, bw, acc0);
    acc1 = MFMA16(a1, bw, acc1);
  }
}

__global__ void __launch_bounds__(NTHR, 1) decoder_kernel(
    const float* __restrict__ enc, const float* __restrict__ audio,
    const float* __restrict__ Wih0, const float* __restrict__ Whh0,
    const float* __restrict__ bih0, const float* __restrict__ bhh0,
    const float* __restrict__ Wih1, const float* __restrict__ Whh1,
    const float* __restrict__ bih1, const float* __restrict__ bhh1,
    const float* __restrict__ Wa, const float* __restrict__ ba,
    const float* __restrict__ Wfc, const float* __restrict__ bfc,
    float* __restrict__ out, float* __restrict__ ws)
{
  cg::grid_group grid = cg::this_grid();
  extern __shared__ char lds[];
  unsigned short* W0  = (unsigned short*)(lds + OFF_W0);
  unsigned short* W1I = (unsigned short*)(lds + OFF_W1I);
  unsigned short* W1H = (unsigned short*)(lds + OFF_W1H);
  float* Gred = (float*)(lds + OFF_GRED);
  float* Gsum = (float*)(lds + OFF_GSUM);    // [0,512) LSTM0, [512,1024) LSTM1
  float* c0l  = (float*)(lds + OFF_C0);
  float* c1l  = (float*)(lds + OFF_C1);
  float* smw  = Gred;                        // prologue-only aliases
  float* red  = Gred + 256;

  const int blk = blockIdx.x, tid = threadIdx.x;
  const int j = blk;                                // owns h-columns [4j, 4j+4)
  const int w = tid >> 6, lane = tid & 63;
  const int row = lane & 15, kg = lane >> 4;

  unsigned short* xstat = (unsigned short*)((char*)ws + WS_XSTAT);
  unsigned short* h0b   = (unsigned short*)((char*)ws + WS_H0B);
  unsigned short* h1b   = (unsigned short*)((char*)ws + WS_H1B);
  float* h1f  = (float*)((char*)ws + WS_H1F);       // 3 parity buffers
  float* esc  = (float*)((char*)ws + WS_ESC);
  float* cm   = (float*)((char*)ws + WS_CST);
  float* cs   = cm + BBAT*EE;
  unsigned* bars = (unsigned*)((char*)ws + WS_BAR);

  // ---- prologue: weights -> LDS bf16 ----
  for (int i = tid; i < 16*W0S; i += NTHR) {
    int r = i / W0S, k = i - r*W0S;
    int n = (r & 3)*HH + 4*j + (r >> 2);
    float v = 0.f;
    if (k < IN0) v = Wih0[(size_t)n*IN0 + k];
    else if (k >= KS && k < KS + HH) v = Whh0[(size_t)n*HH + (k - KS)];
    W0[i] = f2bf(v);
  }
  for (int i = tid; i < 16*W1STR; i += NTHR) {
    int r = i / W1STR, k = i - r*W1STR;
    int n = (r & 3)*HH + 4*j + (r >> 2);
    W1I[i] = (k < HH) ? f2bf(Wih1[(size_t)n*HH + k]) : (unsigned short)0;
    W1H[i] = (k < HH) ? f2bf(Whh1[(size_t)n*HH + k]) : (unsigned short)0;
  }
  if (tid < 128) { c0l[tid] = 0.f; c1l[tid] = 0.f; }
  for (int i = blk*NTHR + tid; i < 2*BBAT*XH; i += NBLK*NTHR) { h0b[i] = 0; h1b[i] = 0; }
  for (int i = blk*NTHR + tid; i < 3*BBAT*HH; i += NBLK*NTHR) h1f[i] = 0.f;
  for (int i = blk*NTHR + tid; i < (TT+2)*BSLOTS; i += NBLK*NTHR) bars[i] = 0u;
  for (int r2 = blk; r2 < BBAT*SE; r2 += NBLK) {
    float pp = tanhf(enc[(size_t)r2*EE + tid]) * Wa[HH + tid];   // EE == NTHR
    pp = bsum(pp, red);
    if (tid == 0) esc[r2] = pp;
  }
  grid.sync();

  // ---- static softmax + contexts (softmax is h1-invariant; R10-R12 validated) ----
  if (blk < BBAT) {
    const int b = blk;
    float sc = (tid < SE) ? esc[b*SE + tid] : -3.4e38f;
    float mx = bmax(sc, red);
    float ex = (tid < SE) ? expf(sc - mx) : 0.f;
    float den = bsum(ex, red);
    if (tid < SE) smw[tid] = ex / den;
    __syncthreads();
    const int e = tid;                                // EE == NTHR
    float as = 0.f, am = 0.f;
    for (int s = 0; s < SE; ++s) {
      float v = enc[((size_t)b*SE + s)*EE + e];
      as = fmaf(smw[s], v, as);
      am += v;
    }
    cm[b*EE + e] = am * (1.0f/(float)SE);
    cs[b*EE + e] = as;
  }
  grid.sync();

  // ---- fill static panel xstat[t][b][608] = [x_t | ctx | 0] bf16 ----
  for (int t2 = blk; t2 < TT; t2 += NBLK) {
    const float* cx = (t2 == 0) ? cm : cs;
    for (int b = 0; b < BBAT; ++b) {
      for (int k = tid; k < KS; k += NTHR) {
        float v;
        if (k < MM)        v = audio[((size_t)b*TT + t2)*MM + k];
        else if (k < IN0)  v = cx[b*EE + (k - MM)];
        else               v = 0.f;
        xstat[((size_t)t2*BBAT + b)*KS + k] = f2bf(v);
      }
    }
  }
  grid.sync();

  const f32x4 z4 = {0.f,0.f,0.f,0.f};
  f32x4 accP0 = z4, accP1 = z4;

  // ---- pre-loop: LSTM0(0) = static(0) (h0(-1)=0); publish h0(0); B(0) ----
  mfma_static(xstat, W0, w, row, kg, accP0, accP1);
  {
    float* gw = Gred + (w << 10) + row;
    #pragma unroll
    for (int v = 0; v < 4; ++v) {
      gw[(((kg<<2)+v)    << 4)] = accP0[v];
      gw[(((kg<<2)+v+16) << 4)] = accP1[v];
    }
    __syncthreads();
    float s0 = 0.f;
    #pragma unroll
    for (int w8 = 0; w8 < 8; ++w8) s0 += Gred[(w8 << 10) + tid];
    Gsum[tid] = s0;
    __syncthreads();
    if (tid >= 64 && tid < 64 + BBAT) {
      const int b = tid - 64;
      u64 hp = 0;
      #pragma unroll
      for (int p = 0; p < 4; ++p) {
        f32x4 gv = *(const f32x4*)(Gsum + (b << 4) + (p << 2));
        const int nb = 4*j + p;
        float gi = gv[0] + bih0[nb]        + bhh0[nb];
        float gf = gv[1] + bih0[HH + nb]   + bhh0[HH + nb];
        float gg = gv[2] + bih0[2*HH + nb] + bhh0[2*HH + nb];
        float go = gv[3] + bih0[3*HH + nb] + bhh0[3*HH + nb];
        float cn = sigmf(gf) * 0.f + sigmf(gi) * tanhf(gg);
        c0l[p*32 + b] = cn;
        hp |= (u64)f2bf(sigmf(go) * tanhf(cn)) << (16*p);
      }
      st64a(h0b + (size_t)b*XH + 4*j, hp);   // h0(0) -> buf 0
    }
  }
  gbar_arrive(bars);
  accP0 = z4; accP1 = z4;
  mfma_static(xstat + (size_t)BBAT*KS, W0, w, row, kg, accP0, accP1);  // static(1)
  gbar_wait(bars);

  for (int t = 0; t < TT; ++t) {
    const unsigned short* h0R = h0b + (t&1)*BBAT*XH;           // h0(t)
    const unsigned short* h1R = h1b + ((t&1)^1)*BBAT*XH;       // h1(t-1)
    unsigned short* h1W = h1b + (t&1)*BBAT*XH;                 // h1(t)
    unsigned short* h0Wn = h0b + ((t+1)&1)*BBAT*XH;            // h0(t+1)
    float* h1fW = h1f + (size_t)(t % 3)*BBAT*HH;

    // ===== exposed: batched 16B coherent loads, 40 MFMA, merged reduce, dual epi =====
    s16x8 A0h[4], A1h[4], A0g[4], A1g[4];
    {
      const unsigned short* ph0a = h0R + (size_t)row*XH + (kg << 3);
      const unsigned short* ph0b_ = h0R + (size_t)(row+16)*XH + (kg << 3);
      const unsigned short* ph1a = h1R + (size_t)row*XH + (kg << 3);
      const unsigned short* ph1b_ = h1R + (size_t)(row+16)*XH + (kg << 3);
      const int o0 = (w << 5), o1 = ((w+8) << 5), o2_ = ((w+16) << 5), o3 = ((w+24) << 5);
      LD4C(A0h[0],A0h[1],A0h[2],A0h[3], ph0a+o0, ph0a+o1, ph0a+o2_, ph0a+o3);
      LD4C(A1h[0],A1h[1],A1h[2],A1h[3], ph0b_+o0, ph0b_+o1, ph0b_+o2_, ph0b_+o3);
      LD4C(A0g[0],A0g[1],A0g[2],A0g[3], ph1a+o0, ph1a+o1, ph1a+o2_, ph1a+o3);
      LD4C(A1g[0],A1g[1],A1g[2],A1g[3], ph1b_+o0, ph1b_+o1, ph1b_+o2_, ph1b_+o3);
      WAIT16(A0h[0],A0h[1],A0h[2],A0h[3], A1h[0],A1h[1],A1h[2],A1h[3],
             A0g[0],A0g[1],A0g[2],A0g[3], A1g[0],A1g[1],A1g[2],A1g[3]);
    }
    f32x4 q0 = z4, q1 = z4;
    #pragma unroll
    for (int i = 0; i < 4; ++i) {
      const int off = ((w + (i << 3)) << 5) + (kg << 3);
      s16x8 b1 = *(const s16x8*)(W1I + row*W1STR + off);
      q0 = MFMA16(A0h[i], b1, q0);
      q1 = MFMA16(A1h[i], b1, q1);
      s16x8 b0 = *(const s16x8*)(W0 + row*W0S + KS + off);
      accP0 = MFMA16(A0h[i], b0, accP0);
      accP1 = MFMA16(A1h[i], b0, accP1);
      s16x8 b2 = *(const s16x8*)(W1H + row*W1STR + off);
      q0 = MFMA16(A0g[i], b2, q0);
      q1 = MFMA16(A1g[i], b2, q1);
    }
    { // merged two-plane reduce
      float* gw = Gred + (w << 10) + row;
      #pragma unroll
      for (int v = 0; v < 4; ++v) {
        gw[(((kg<<2)+v)    << 4)]       = accP0[v];
        gw[(((kg<<2)+v+16) << 4)]       = accP1[v];
        gw[512 + (((kg<<2)+v)    << 4)] = q0[v];
        gw[512 + (((kg<<2)+v+16) << 4)] = q1[v];
      }
      __syncthreads();
      float s0 = 0.f, s1 = 0.f;
      #pragma unroll
      for (int w8 = 0; w8 < 8; ++w8) {
        s0 += Gred[(w8 << 10) + tid];
        s1 += Gred[(w8 << 10) + 512 + tid];
      }
      Gsum[tid] = s0;
      Gsum[512 + tid] = s1;
      __syncthreads();
    }
    if (tid < BBAT) {                       // wave0: LSTM1(t) -> h1(t)
      const int b = tid;
      u64 hp = 0; float hf[4];
      #pragma unroll
      for (int p = 0; p < 4; ++p) {
        f32x4 gv = *(const f32x4*)(Gsum + 512 + (b << 4) + (p << 2));
        const int nb = 4*j + p;
        float gi = gv[0] + bih1[nb]        + bhh1[nb];
        float gf = gv[1] + bih1[HH + nb]   + bhh1[HH + nb];
        float gg = gv[2] + bih1[2*HH + nb] + bhh1[2*HH + nb];
        float go = gv[3] + bih1[3*HH + nb] + bhh1[3*HH + nb];
        float cn = sigmf(gf) * c1l[p*32 + b] + sigmf(gi) * tanhf(gg);
        c1l[p*32 + b] = cn;
        float hn = sigmf(go) * tanhf(cn);
        hf[p] = hn;
        hp |= (u64)f2bf(hn) << (16*p);
      }
      st64a(h1W + (size_t)b*XH + 4*j, hp);
      st64a(h1fW + (size_t)b*HH + 4*j,     pk2f(hf[0], hf[1]));
      st64a(h1fW + (size_t)b*HH + 4*j + 2, pk2f(hf[2], hf[3]));
    } else if (tid >= 64 && tid < 64 + BBAT) {   // wave1: LSTM0(t+1) -> h0(t+1)
      const int b = tid - 64;
      u64 hp = 0;
      #pragma unroll
      for (int p = 0; p < 4; ++p) {
        f32x4 gv = *(const f32x4*)(Gsum + (b << 4) + (p << 2));
        const int nb = 4*j + p;
        float gi = gv[0] + bih0[nb]        + bhh0[nb];
        float gf = gv[1] + bih0[HH + nb]   + bhh0[HH + nb];
        float gg = gv[2] + bih0[2*HH + nb] + bhh0[2*HH + nb];
        float go = gv[3] + bih0[3*HH + nb] + bhh0[3*HH + nb];
        float cn = sigmf(gf) * c0l[p*32 + b] + sigmf(gi) * tanhf(gg);
        c0l[p*32 + b] = cn;
        hp |= (u64)f2bf(sigmf(go) * tanhf(cn)) << (16*p);
      }
      st64a(h0Wn + (size_t)b*XH + 4*j, hp);
    }
    gbar_arrive(bars + (size_t)(t+1)*BSLOTS);

    // ===== barrier window: FC pred(t-1) first (coherent loads issue early), then static(t+2) =====
    if (t >= 1) {   // FC(t-1): h1f(t-1) globally published since wait B(t)
      const float* h1fF = h1f + (size_t)((t-1) % 3)*BBAT*HH;
      for (int u = w; u < 10; u += 8) {
        int idx = j*10 + u;
        int b = idx / MM, m = idx - b*MM;
        float pp = 0.f;
        #pragma unroll
        for (int cq = 0; cq < 4; ++cq) {
          float2 h0v = ld2f(h1fF + (size_t)b*HH + cq*256 + lane*4);
          float2 h1v = ld2f(h1fF + (size_t)b*HH + cq*256 + lane*4 + 2);
          float4 wv = *(const float4*)(Wfc + (size_t)m*HH + cq*256 + lane*4);
          pp = fmaf(h0v.x,wv.x, fmaf(h0v.y,wv.y, fmaf(h1v.x,wv.z, fmaf(h1v.y,wv.w, pp))));
        }
        #pragma unroll
        for (int o2 = 32; o2; o2 >>= 1) pp += __shfl_down(pp, o2);
        if (lane == 0) out[((size_t)b*TT + (t-1))*MM + m] = pp + bfc[m];
      }
    }
    accP0 = z4; accP1 = z4;
    if (t + 2 < TT)
      mfma_static(xstat + (size_t)(t+2)*BBAT*KS, W0, w, row, kg, accP0, accP1);
    gbar_wait(bars + (size_t)(t+1)*BSLOTS);
  }

  // ---- epilogue: FC pred(TT-1) ----
  {
    const float* h1fL = h1f + (size_t)((TT-1) % 3)*BBAT*HH;
    for (int u = w; u < 10; u += 8) {
      int idx = j*10 + u;
      int b = idx / MM, m = idx - b*MM;
      float pp = 0.f;
      #pragma unroll
      for (int cq = 0; cq < 4; ++cq) {
        float2 h0v = ld2f(h1fL + (size_t)b*HH + cq*256 + lane*4);
        float2 h1v = ld2f(h1fL + (size_t)b*HH + cq*256 + lane*4 + 2);
        float4 wv = *(const float4*)(Wfc + (size_t)m*HH + cq*256 + lane*4);
        pp = fmaf(h0v.x,wv.x, fmaf(h0v.y,wv.y, fmaf(h1v.x,wv.z, fmaf(h1v.y,wv.w, pp))));
      }
      #pragma unroll
      for (int o2 = 32; o2; o2 >>= 1) pp += __shfl_down(pp, o2);
      if (lane == 0) out[((size_t)b*TT + (TT-1))*MM + m] = pp + bfc[m];
    }
  }
}

extern "C" void kernel_launch(void* const* d_in, const int* in_sizes, int n_in,
                              void* d_out, int out_size, void* d_ws, size_t ws_size,
                              hipStream_t stream) {
  const float* enc  = (const float*)d_in[0];
  const float* audio= (const float*)d_in[1];
  const float* Wih0 = (const float*)d_in[2];
  const float* Whh0 = (const float*)d_in[3];
  const float* bih0 = (const float*)d_in[4];
  const float* bhh0 = (const float*)d_in[5];
  const float* Wih1 = (const float*)d_in[6];
  const float* Whh1 = (const float*)d_in[7];
  const float* bih1 = (const float*)d_in[8];
  const float* bhh1 = (const float*)d_in[9];
  const float* Wa   = (const float*)d_in[10];
  const float* ba   = (const float*)d_in[11];
  const float* Wfc  = (const float*)d_in[12];
  const float* bfc  = (const float*)d_in[13];
  float* out = (float*)d_out;
  float* ws  = (float*)d_ws;

  (void)hipFuncSetAttribute((const void*)decoder_kernel,
                            hipFuncAttributeMaxDynamicSharedMemorySize, LDS_TOTAL);

  void* args[] = { &enc,&audio,&Wih0,&Whh0,&bih0,&bhh0,&Wih1,&Whh1,&bih1,&bhh1,
                   &Wa,&ba,&Wfc,&bfc,&out,&ws };
  hipLaunchCooperativeKernel((const void*)decoder_kernel, dim3(NBLK), dim3(NTHR),
                             args, LDS_TOTAL, stream);
}

// Round 14
// 3306.130 us; speedup vs baseline: 21.2147x; 1.1847x over previous
//
#include <hip/hip_runtime.h>
#include <hip/hip_cooperative_groups.h>

namespace cg = cooperative_groups;

#define BBAT 32
#define SE 200
#define TT 400
#define MM 80
#define EE 512
#define HH 1024
#define IN0 592
#define KS 608         // static panel row: x(80) + ctx(512) + zero pad(16)
#define NSC 19         // static chunks (KS/32)
#define W0S 1640       // W0 LDS row stride (608 static + 1024 hh + 8 pad)
#define W1STR 1032
#define NBLK 256
#define NTHR 512

// barrier tree: 16 groups x 16 blocks, 17 padded slots (16 u32 each)
#define NGRP 16
#define GSZ  16
#define BSLOTS 272

typedef __attribute__((ext_vector_type(4))) float f32x4;
typedef __attribute__((ext_vector_type(8))) short s16x8;
typedef unsigned long long u64;

// LDS offsets (bytes)
#define OFF_W0    0          // 16*1640*2 = 52480
#define OFF_W1I   52480      // 33024
#define OFF_W1H   85504      // 33024
#define OFF_GRED  118528     // 8 waves x 1024 f32 = 32768 (2 planes)
#define OFF_GSUM  151296     // 1024 f32 = 4096 (plane0: LSTM0, plane1: LSTM1)
#define OFF_C0    155392     // 512
#define OFF_C1    155904     // 512
#define LDS_TOTAL 156416
// prologue-only smw/red alias the GRED region (no temporal overlap)

// ws offsets (bytes)
// h0b/h1b are CHUNK-MAJOR: [2 parity][32 chunk][32 batch][32 elem] bf16
#define WS_XSTAT 0                 // 400*32*608*2 = 15,564,800
#define WS_H0B   15564800          // 2*32768*2 = 131,072
#define WS_H1B   15696896          // 131,072
#define WS_H1F   15828992          // 3*32*1024*4 = 393,216 (triple buffer, [b][k] f32)
#define WS_ESC   16222208          // 25,600
#define WS_CST   16247808          // 131,072 (cm | cs)
#define WS_BAR   16378880          // 402*272*4 = 437,376

__device__ __forceinline__ float sigmf(float x){ return 1.0f/(1.0f+expf(-x)); }

__device__ __forceinline__ unsigned short f2bf(float v){
  unsigned int u = __float_as_uint(v);
  u += 0x7fffu + ((u >> 16) & 1u);
  return (unsigned short)(u >> 16);
}

// ---- agent-scope coherent accessors; RELAXED => no cache-maintenance ops ----
__device__ __forceinline__ void st64a(void* p, u64 v){
  __hip_atomic_store((u64*)p, v, __ATOMIC_RELAXED, __HIP_MEMORY_SCOPE_AGENT);
}
__device__ __forceinline__ u64 ld64a(const void* p){
  return __hip_atomic_load((const u64*)p, __ATOMIC_RELAXED, __HIP_MEMORY_SCOPE_AGENT);
}
__device__ __forceinline__ float2 ld2f(const float* p){
  u64 q = ld64a(p);
  float2 r; r.x = __uint_as_float((unsigned)q); r.y = __uint_as_float((unsigned)(q >> 32));
  return r;
}
__device__ __forceinline__ u64 pk2f(float a, float b){
  return ((u64)__float_as_uint(b) << 32) | (u64)__float_as_uint(a);
}

// 4x 16B coherent loads (sc0 sc1 -> read at coherence point). In chunk-major
// layout each wave's 64 lanes span 1KB CONTIGUOUS per instruction (8x128B
// lines) instead of 64 scattered 16B requests.
#define LD4C(d0,d1,d2,d3,p0,p1,p2,p3) \
  asm volatile("global_load_dwordx4 %0, %4, off sc0 sc1\n\t" \
               "global_load_dwordx4 %1, %5, off sc0 sc1\n\t" \
               "global_load_dwordx4 %2, %6, off sc0 sc1\n\t" \
               "global_load_dwordx4 %3, %7, off sc0 sc1" \
               : "=&v"(d0), "=&v"(d1), "=&v"(d2), "=&v"(d3) \
               : "v"(p0), "v"(p1), "v"(p2), "v"(p3))

// Single waitcnt tying all 16 fragments as in-outs (anti-hoist: rule #18).
#define WAIT16(a0,a1,a2,a3,b0,b1,b2,b3,c0,c1,c2,c3,d0,d1,d2,d3) \
  asm volatile("s_waitcnt vmcnt(0)" \
    : "+v"(a0),"+v"(a1),"+v"(a2),"+v"(a3), \
      "+v"(b0),"+v"(b1),"+v"(b2),"+v"(b3), \
      "+v"(c0),"+v"(c1),"+v"(c2),"+v"(c3), \
      "+v"(d0),"+v"(d1),"+v"(d2),"+v"(d3))

// Split-phase one-shot tree grid barrier (R8-R13 proven RMW mechanism).
__device__ __forceinline__ void gbar_arrive(unsigned* slots){
  __builtin_amdgcn_s_waitcnt(0);
  __syncthreads();
  if (threadIdx.x == 0){
    const unsigned g = blockIdx.x >> 4;
    unsigned prev = __hip_atomic_fetch_add(slots + g*16, 1u, __ATOMIC_RELAXED, __HIP_MEMORY_SCOPE_AGENT);
    if (prev == (unsigned)(GSZ-1))
      __hip_atomic_fetch_add(slots + NGRP*16, 1u, __ATOMIC_RELAXED, __HIP_MEMORY_SCOPE_AGENT);
  }
}
__device__ __forceinline__ void gbar_wait(unsigned* slots){
  if (threadIdx.x == 0){
    while (__hip_atomic_load(slots + NGRP*16, __ATOMIC_RELAXED, __HIP_MEMORY_SCOPE_AGENT) < (unsigned)NGRP)
      __builtin_amdgcn_s_sleep(1);
  }
  __syncthreads();
}

__device__ __forceinline__ float bsum(float v, float* red){
  #pragma unroll
  for (int o = 32; o; o >>= 1) v += __shfl_down(v, o);
  __syncthreads();
  if ((threadIdx.x & 63) == 0) red[threadIdx.x >> 6] = v;
  __syncthreads();
  float s = 0.f;
  #pragma unroll
  for (int w2 = 0; w2 < 8; ++w2) s += red[w2];
  return s;
}
__device__ __forceinline__ float bmax(float v, float* red){
  #pragma unroll
  for (int o = 32; o; o >>= 1) v = fmaxf(v, __shfl_down(v, o));
  __syncthreads();
  if ((threadIdx.x & 63) == 0) red[threadIdx.x >> 6] = v;
  __syncthreads();
  float s = -3.4e38f;
  #pragma unroll
  for (int w2 = 0; w2 < 8; ++w2) s = fmaxf(s, red[w2]);
  return s;
}

#define MFMA16(a,b,c) __builtin_amdgcn_mfma_f32_16x16x32_bf16((a),(b),(c),0,0,0)

// static-panel MFMAs for LSTM0 time tau (cached loads; xstat stable after prologue)
__device__ __forceinline__ void mfma_static(const unsigned short* __restrict__ xs,
    const unsigned short* __restrict__ W0, int w, int row, int kg,
    f32x4& acc0, f32x4& acc1)
{
  for (int c = w; c < NSC; c += 8) {
    const int off = (c << 5) + (kg << 3);
    s16x8 a0 = *(const s16x8*)(xs + (size_t)row*KS + off);
    s16x8 a1 = *(const s16x8*)(xs + (size_t)(row+16)*KS + off);
    s16x8 bw = *(const s16x8*)(W0 + row*W0S + off);
    acc0 = MFMA16(a0, bw, acc0);
    acc1 = MFMA16(a1, bw, acc1);
  }
}

__global__ void __launch_bounds__(NTHR, 1) decoder_kernel(
    const float* __restrict__ enc, const float* __restrict__ audio,
    const float* __restrict__ Wih0, const float* __restrict__ Whh0,
    const float* __restrict__ bih0, const float* __restrict__ bhh0,
    const float* __restrict__ Wih1, const float* __restrict__ Whh1,
    const float* __restrict__ bih1, const float* __restrict__ bhh1,
    const float* __restrict__ Wa, const float* __restrict__ ba,
    const float* __restrict__ Wfc, const float* __restrict__ bfc,
    float* __restrict__ out, float* __restrict__ ws)
{
  cg::grid_group grid = cg::this_grid();
  extern __shared__ char lds[];
  unsigned short* W0  = (unsigned short*)(lds + OFF_W0);
  unsigned short* W1I = (unsigned short*)(lds + OFF_W1I);
  unsigned short* W1H = (unsigned short*)(lds + OFF_W1H);
  float* Gred = (float*)(lds + OFF_GRED);
  float* Gsum = (float*)(lds + OFF_GSUM);    // [0,512) LSTM0, [512,1024) LSTM1
  float* c0l  = (float*)(lds + OFF_C0);
  float* c1l  = (float*)(lds + OFF_C1);
  float* smw  = Gred;                        // prologue-only aliases
  float* red  = Gred + 256;

  const int blk = blockIdx.x, tid = threadIdx.x;
  const int j = blk;                                // owns h-columns [4j, 4j+4)
  const int w = tid >> 6, lane = tid & 63;
  const int row = lane & 15, kg = lane >> 4;
  const int cblk = j >> 3;                          // chunk holding this block's cols
  const int colw = (j & 7) << 2;                    // col offset within chunk

  unsigned short* xstat = (unsigned short*)((char*)ws + WS_XSTAT);
  unsigned short* h0b   = (unsigned short*)((char*)ws + WS_H0B);   // chunk-major
  unsigned short* h1b   = (unsigned short*)((char*)ws + WS_H1B);   // chunk-major
  float* h1f  = (float*)((char*)ws + WS_H1F);       // 3 parity buffers, [b][k]
  float* esc  = (float*)((char*)ws + WS_ESC);
  float* cm   = (float*)((char*)ws + WS_CST);
  float* cs   = cm + BBAT*EE;
  unsigned* bars = (unsigned*)((char*)ws + WS_BAR);

  // ---- prologue: weights -> LDS bf16 ----
  for (int i = tid; i < 16*W0S; i += NTHR) {
    int r = i / W0S, k = i - r*W0S;
    int n = (r & 3)*HH + 4*j + (r >> 2);
    float v = 0.f;
    if (k < IN0) v = Wih0[(size_t)n*IN0 + k];
    else if (k >= KS && k < KS + HH) v = Whh0[(size_t)n*HH + (k - KS)];
    W0[i] = f2bf(v);
  }
  for (int i = tid; i < 16*W1STR; i += NTHR) {
    int r = i / W1STR, k = i - r*W1STR;
    int n = (r & 3)*HH + 4*j + (r >> 2);
    W1I[i] = (k < HH) ? f2bf(Wih1[(size_t)n*HH + k]) : (unsigned short)0;
    W1H[i] = (k < HH) ? f2bf(Whh1[(size_t)n*HH + k]) : (unsigned short)0;
  }
  if (tid < 128) { c0l[tid] = 0.f; c1l[tid] = 0.f; }
  for (int i = blk*NTHR + tid; i < 2*BBAT*HH; i += NBLK*NTHR) { h0b[i] = 0; h1b[i] = 0; }
  for (int i = blk*NTHR + tid; i < 3*BBAT*HH; i += NBLK*NTHR) h1f[i] = 0.f;
  for (int i = blk*NTHR + tid; i < (TT+2)*BSLOTS; i += NBLK*NTHR) bars[i] = 0u;
  for (int r2 = blk; r2 < BBAT*SE; r2 += NBLK) {
    float pp = tanhf(enc[(size_t)r2*EE + tid]) * Wa[HH + tid];   // EE == NTHR
    pp = bsum(pp, red);
    if (tid == 0) esc[r2] = pp;
  }
  grid.sync();

  // ---- static softmax + contexts (softmax is h1-invariant; R10-R13 validated) ----
  if (blk < BBAT) {
    const int b = blk;
    float sc = (tid < SE) ? esc[b*SE + tid] : -3.4e38f;
    float mx = bmax(sc, red);
    float ex = (tid < SE) ? expf(sc - mx) : 0.f;
    float den = bsum(ex, red);
    if (tid < SE) smw[tid] = ex / den;
    __syncthreads();
    const int e = tid;                                // EE == NTHR
    float as = 0.f, am = 0.f;
    for (int s = 0; s < SE; ++s) {
      float v = enc[((size_t)b*SE + s)*EE + e];
      as = fmaf(smw[s], v, as);
      am += v;
    }
    cm[b*EE + e] = am * (1.0f/(float)SE);
    cs[b*EE + e] = as;
  }
  grid.sync();

  // ---- fill static panel xstat[t][b][608] = [x_t | ctx | 0] bf16 ----
  for (int t2 = blk; t2 < TT; t2 += NBLK) {
    const float* cx = (t2 == 0) ? cm : cs;
    for (int b = 0; b < BBAT; ++b) {
      for (int k = tid; k < KS; k += NTHR) {
        float v;
        if (k < MM)        v = audio[((size_t)b*TT + t2)*MM + k];
        else if (k < IN0)  v = cx[b*EE + (k - MM)];
        else               v = 0.f;
        xstat[((size_t)t2*BBAT + b)*KS + k] = f2bf(v);
      }
    }
  }
  grid.sync();

  const f32x4 z4 = {0.f,0.f,0.f,0.f};
  f32x4 accP0 = z4, accP1 = z4;

  // ---- pre-loop: LSTM0(0) = static(0) (h0(-1)=0); publish h0(0); B(0) ----
  mfma_static(xstat, W0, w, row, kg, accP0, accP1);
  {
    float* gw = Gred + (w << 10) + row;
    #pragma unroll
    for (int v = 0; v < 4; ++v) {
      gw[(((kg<<2)+v)    << 4)] = accP0[v];
      gw[(((kg<<2)+v+16) << 4)] = accP1[v];
    }
    __syncthreads();
    float s0 = 0.f;
    #pragma unroll
    for (int w8 = 0; w8 < 8; ++w8) s0 += Gred[(w8 << 10) + tid];
    Gsum[tid] = s0;
    __syncthreads();
    if (tid >= 64 && tid < 64 + BBAT) {
      const int b = tid - 64;
      u64 hp = 0;
      #pragma unroll
      for (int p = 0; p < 4; ++p) {
        f32x4 gv = *(const f32x4*)(Gsum + (b << 4) + (p << 2));
        const int nb = 4*j + p;
        float gi = gv[0] + bih0[nb]        + bhh0[nb];
        float gf = gv[1] + bih0[HH + nb]   + bhh0[HH + nb];
        float gg = gv[2] + bih0[2*HH + nb] + bhh0[2*HH + nb];
        float go = gv[3] + bih0[3*HH + nb] + bhh0[3*HH + nb];
        float cn = sigmf(gf) * 0.f + sigmf(gi) * tanhf(gg);
        c0l[p*32 + b] = cn;
        hp |= (u64)f2bf(sigmf(go) * tanhf(cn)) << (16*p);
      }
      st64a(h0b + (cblk << 10) + (b << 5) + colw, hp);   // h0(0) -> parity buf 0
    }
  }
  gbar_arrive(bars);
  accP0 = z4; accP1 = z4;
  mfma_static(xstat + (size_t)BBAT*KS, W0, w, row, kg, accP0, accP1);  // static(1)
  gbar_wait(bars);

  for (int t = 0; t < TT; ++t) {
    const unsigned short* h0R = h0b + (t&1)*BBAT*HH;           // h0(t), chunk-major
    const unsigned short* h1R = h1b + ((t&1)^1)*BBAT*HH;       // h1(t-1)
    unsigned short* h1W = h1b + (t&1)*BBAT*HH;                 // h1(t)
    unsigned short* h0Wn = h0b + ((t+1)&1)*BBAT*HH;            // h0(t+1)
    float* h1fW = h1f + (size_t)(t % 3)*BBAT*HH;

    // ===== exposed: coalesced coherent loads, 40 MFMA, merged reduce, dual epi =====
    s16x8 A0h[4], A1h[4], A0g[4], A1g[4];
    {
      // chunk-major: lane addr = c*1024 + row*32 + kg*8 (elems); wave spans 1KB contig
      const unsigned short* ph0a  = h0R + (row << 5) + (kg << 3);
      const unsigned short* ph0b_ = h0R + ((row+16) << 5) + (kg << 3);
      const unsigned short* ph1a  = h1R + (row << 5) + (kg << 3);
      const unsigned short* ph1b_ = h1R + ((row+16) << 5) + (kg << 3);
      const int o0 = (w << 10), o1 = ((w+8) << 10), o2_ = ((w+16) << 10), o3 = ((w+24) << 10);
      LD4C(A0h[0],A0h[1],A0h[2],A0h[3], ph0a+o0, ph0a+o1, ph0a+o2_, ph0a+o3);
      LD4C(A1h[0],A1h[1],A1h[2],A1h[3], ph0b_+o0, ph0b_+o1, ph0b_+o2_, ph0b_+o3);
      LD4C(A0g[0],A0g[1],A0g[2],A0g[3], ph1a+o0, ph1a+o1, ph1a+o2_, ph1a+o3);
      LD4C(A1g[0],A1g[1],A1g[2],A1g[3], ph1b_+o0, ph1b_+o1, ph1b_+o2_, ph1b_+o3);
      WAIT16(A0h[0],A0h[1],A0h[2],A0h[3], A1h[0],A1h[1],A1h[2],A1h[3],
             A0g[0],A0g[1],A0g[2],A0g[3], A1g[0],A1g[1],A1g[2],A1g[3]);
    }
    f32x4 q0 = z4, q1 = z4;
    #pragma unroll
    for (int i = 0; i < 4; ++i) {
      const int off = ((w + (i << 3)) << 5) + (kg << 3);
      s16x8 b1 = *(const s16x8*)(W1I + row*W1STR + off);
      q0 = MFMA16(A0h[i], b1, q0);
      q1 = MFMA16(A1h[i], b1, q1);
      s16x8 b0 = *(const s16x8*)(W0 + row*W0S + KS + off);
      accP0 = MFMA16(A0h[i], b0, accP0);
      accP1 = MFMA16(A1h[i], b0, accP1);
      s16x8 b2 = *(const s16x8*)(W1H + row*W1STR + off);
      q0 = MFMA16(A0g[i], b2, q0);
      q1 = MFMA16(A1g[i], b2, q1);
    }
    { // merged two-plane reduce
      float* gw = Gred + (w << 10) + row;
      #pragma unroll
      for (int v = 0; v < 4; ++v) {
        gw[(((kg<<2)+v)    << 4)]       = accP0[v];
        gw[(((kg<<2)+v+16) << 4)]       = accP1[v];
        gw[512 + (((kg<<2)+v)    << 4)] = q0[v];
        gw[512 + (((kg<<2)+v+16) << 4)] = q1[v];
      }
      __syncthreads();
      float s0 = 0.f, s1 = 0.f;
      #pragma unroll
      for (int w8 = 0; w8 < 8; ++w8) {
        s0 += Gred[(w8 << 10) + tid];
        s1 += Gred[(w8 << 10) + 512 + tid];
      }
      Gsum[tid] = s0;
      Gsum[512 + tid] = s1;
      __syncthreads();
    }
    if (tid < BBAT) {                       // wave0: LSTM1(t) -> h1(t)
      const int b = tid;
      u64 hp = 0; float hf[4];
      #pragma unroll
      for (int p = 0; p < 4; ++p) {
        f32x4 gv = *(const f32x4*)(Gsum + 512 + (b << 4) + (p << 2));
        const int nb = 4*j + p;
        float gi = gv[0] + bih1[nb]        + bhh1[nb];
        float gf = gv[1] + bih1[HH + nb]   + bhh1[HH + nb];
        float gg = gv[2] + bih1[2*HH + nb] + bhh1[2*HH + nb];
        float go = gv[3] + bih1[3*HH + nb] + bhh1[3*HH + nb];
        float cn = sigmf(gf) * c1l[p*32 + b] + sigmf(gi) * tanhf(gg);
        c1l[p*32 + b] = cn;
        float hn = sigmf(go) * tanhf(cn);
        hf[p] = hn;
        hp |= (u64)f2bf(hn) << (16*p);
      }
      st64a(h1W + (cblk << 10) + (b << 5) + colw, hp);
      st64a(h1fW + (size_t)b*HH + 4*j,     pk2f(hf[0], hf[1]));
      st64a(h1fW + (size_t)b*HH + 4*j + 2, pk2f(hf[2], hf[3]));
    } else if (tid >= 64 && tid < 64 + BBAT) {   // wave1: LSTM0(t+1) -> h0(t+1)
      const int b = tid - 64;
      u64 hp = 0;
      #pragma unroll
      for (int p = 0; p < 4; ++p) {
        f32x4 gv = *(const f32x4*)(Gsum + (b << 4) + (p << 2));
        const int nb = 4*j + p;
        float gi = gv[0] + bih0[nb]        + bhh0[nb];
        float gf = gv[1] + bih0[HH + nb]   + bhh0[HH + nb];
        float gg = gv[2] + bih0[2*HH + nb] + bhh0[2*HH + nb];
        float go = gv[3] + bih0[3*HH + nb] + bhh0[3*HH + nb];
        float cn = sigmf(gf) * c0l[p*32 + b] + sigmf(gi) * tanhf(gg);
        c0l[p*32 + b] = cn;
        hp |= (u64)f2bf(sigmf(go) * tanhf(cn)) << (16*p);
      }
      st64a(h0Wn + (cblk << 10) + (b << 5) + colw, hp);
    }
    gbar_arrive(bars + (size_t)(t+1)*BSLOTS);

    // ===== barrier window: FC pred(t-1) first, then static(t+2) =====
    if (t >= 1) {   // FC(t-1): h1f(t-1) globally published since wait B(t)
      const float* h1fF = h1f + (size_t)((t-1) % 3)*BBAT*HH;
      for (int u = w; u < 10; u += 8) {
        int idx = j*10 + u;
        int b = idx / MM, m = idx - b*MM;
        float pp = 0.f;
        #pragma unroll
        for (int cq = 0; cq < 4; ++cq) {
          float2 h0v = ld2f(h1fF + (size_t)b*HH + cq*256 + lane*4);
          float2 h1v = ld2f(h1fF + (size_t)b*HH + cq*256 + lane*4 + 2);
          float4 wv = *(const float4*)(Wfc + (size_t)m*HH + cq*256 + lane*4);
          pp = fmaf(h0v.x,wv.x, fmaf(h0v.y,wv.y, fmaf(h1v.x,wv.z, fmaf(h1v.y,wv.w, pp))));
        }
        #pragma unroll
        for (int o2 = 32; o2; o2 >>= 1) pp += __shfl_down(pp, o2);
        if (lane == 0) out[((size_t)b*TT + (t-1))*MM + m] = pp + bfc[m];
      }
    }
    accP0 = z4; accP1 = z4;
    if (t + 2 < TT)
      mfma_static(xstat + (size_t)(t+2)*BBAT*KS, W0, w, row, kg, accP0, accP1);
    gbar_wait(bars + (size_t)(t+1)*BSLOTS);
  }

  // ---- epilogue: FC pred(TT-1) ----
  {
    const float* h1fL = h1f + (size_t)((TT-1) % 3)*BBAT*HH;
    for (int u = w; u < 10; u += 8) {
      int idx = j*10 + u;
      int b = idx / MM, m = idx - b*MM;
      float pp = 0.f;
      #pragma unroll
      for (int cq = 0; cq < 4; ++cq) {
        float2 h0v = ld2f(h1fL + (size_t)b*HH + cq*256 + lane*4);
        float2 h1v = ld2f(h1fL + (size_t)b*HH + cq*256 + lane*4 + 2);
        float4 wv = *(const float4*)(Wfc + (size_t)m*HH + cq*256 + lane*4);
        pp = fmaf(h0v.x,wv.x, fmaf(h0v.y,wv.y, fmaf(h1v.x,wv.z, fmaf(h1v.y,wv.w, pp))));
      }
      #pragma unroll
      for (int o2 = 32; o2; o2 >>= 1) pp += __shfl_down(pp, o2);
      if (lane == 0) out[((size_t)b*TT + (TT-1))*MM + m] = pp + bfc[m];
    }
  }
}

extern "C" void kernel_launch(void* const* d_in, const int* in_sizes, int n_in,
                              void* d_out, int out_size, void* d_ws, size_t ws_size,
                              hipStream_t stream) {
  const float* enc  = (const float*)d_in[0];
  const float* audio= (const float*)d_in[1];
  const float* Wih0 = (const float*)d_in[2];
  const float* Whh0 = (const float*)d_in[3];
  const float* bih0 = (const float*)d_in[4];
  const float* bhh0 = (const float*)d_in[5];
  const float* Wih1 = (const float*)d_in[6];
  const float* Whh1 = (const float*)d_in[7];
  const float* bih1 = (const float*)d_in[8];
  const float* bhh1 = (const float*)d_in[9];
  const float* Wa   = (const float*)d_in[10];
  const float* ba   = (const float*)d_in[11];
  const float* Wfc  = (const float*)d_in[12];
  const float* bfc  = (const float*)d_in[13];
  float* out = (float*)d_out;
  float* ws  = (float*)d_ws;

  (void)hipFuncSetAttribute((const void*)decoder_kernel,
                            hipFuncAttributeMaxDynamicSharedMemorySize, LDS_TOTAL);

  void* args[] = { &enc,&audio,&Wih0,&Whh0,&bih0,&bhh0,&Wih1,&Whh1,&bih1,&bhh1,
                   &Wa,&ba,&Wfc,&bfc,&out,&ws };
  hipLaunchCooperativeKernel((const void*)decoder_kernel, dim3(NBLK), dim3(NTHR),
                             args, LDS_TOTAL, stream);
}

// Round 15
// 3096.068 us; speedup vs baseline: 22.6541x; 1.0678x over previous
//
#include <hip/hip_runtime.h>
#include <hip/hip_cooperative_groups.h>

namespace cg = cooperative_groups;

#define BBAT 32
#define SE 200
#define TT 400
#define MM 80
#define EE 512
#define HH 1024
#define IN0 592
#define KS 608         // static panel row: x(80) + ctx(512) + zero pad(16)
#define NSC 19         // static chunks (KS/32)
#define W0S 1640       // W0 LDS row stride (608 static + 1024 hh + 8 pad)
#define W1STR 1032
#define NBLK 256
#define NTHR 512

// barrier tree: 16 groups x 16 blocks, 17 padded slots (16 u32 each)
#define NGRP 16
#define GSZ  16
#define BSLOTS 272

typedef __attribute__((ext_vector_type(4))) float f32x4;
typedef __attribute__((ext_vector_type(8))) short s16x8;
typedef unsigned long long u64;

// LDS offsets (bytes)
#define OFF_W0    0          // 16*1640*2 = 52480
#define OFF_W1I   52480      // 33024
#define OFF_W1H   85504      // 33024
#define OFF_GRED  118528     // 8 waves x 1024 f32 = 32768 (2 planes)
#define OFF_C0    151296     // 512
#define OFF_C1    151808     // 512
#define OFF_BS    152320     // b0s[16] + b1s[16] f32 = 128
#define LDS_TOTAL 152448
// prologue-only smw/red alias the GRED region (no temporal overlap)

// ws offsets (bytes)
// h0b/h1b are CHUNK-MAJOR: [2 parity][32 chunk][32 batch][32 elem] bf16
#define WS_XSTAT 0                 // 400*32*608*2 = 15,564,800
#define WS_H0B   15564800          // 131,072
#define WS_H1B   15696896          // 131,072
#define WS_H1F   15828992          // 3*32*1024*4 = 393,216 (triple buffer, [b][k] f32)
#define WS_ESC   16222208          // 25,600
#define WS_CST   16247808          // 131,072 (cm | cs)
#define WS_BAR   16378880          // 402*272*4 = 437,376

__device__ __forceinline__ float sigmf(float x){ return 1.0f/(1.0f+expf(-x)); }

__device__ __forceinline__ unsigned short f2bf(float v){
  unsigned int u = __float_as_uint(v);
  u += 0x7fffu + ((u >> 16) & 1u);
  return (unsigned short)(u >> 16);
}

// ---- agent-scope coherent accessors; RELAXED => no cache-maintenance ops ----
__device__ __forceinline__ void st64a(void* p, u64 v){
  __hip_atomic_store((u64*)p, v, __ATOMIC_RELAXED, __HIP_MEMORY_SCOPE_AGENT);
}
__device__ __forceinline__ u64 ld64a(const void* p){
  return __hip_atomic_load((const u64*)p, __ATOMIC_RELAXED, __HIP_MEMORY_SCOPE_AGENT);
}
__device__ __forceinline__ float2 ld2f(const float* p){
  u64 q = ld64a(p);
  float2 r; r.x = __uint_as_float((unsigned)q); r.y = __uint_as_float((unsigned)(q >> 32));
  return r;
}
__device__ __forceinline__ u64 pk2f(float a, float b){
  return ((u64)__float_as_uint(b) << 32) | (u64)__float_as_uint(a);
}

// 4x 16B coherent loads (sc0 sc1 -> coherence point). Chunk-major: each wave
// spans 1KB contiguous per instruction (8x128B lines).
#define LD4C(d0,d1,d2,d3,p0,p1,p2,p3) \
  asm volatile("global_load_dwordx4 %0, %4, off sc0 sc1\n\t" \
               "global_load_dwordx4 %1, %5, off sc0 sc1\n\t" \
               "global_load_dwordx4 %2, %6, off sc0 sc1\n\t" \
               "global_load_dwordx4 %3, %7, off sc0 sc1" \
               : "=&v"(d0), "=&v"(d1), "=&v"(d2), "=&v"(d3) \
               : "v"(p0), "v"(p1), "v"(p2), "v"(p3))

// Single waitcnt tying all 16 fragments as in-outs (anti-hoist: rule #18).
#define WAIT16(a0,a1,a2,a3,b0,b1,b2,b3,c0,c1,c2,c3,d0,d1,d2,d3) \
  asm volatile("s_waitcnt vmcnt(0)" \
    : "+v"(a0),"+v"(a1),"+v"(a2),"+v"(a3), \
      "+v"(b0),"+v"(b1),"+v"(b2),"+v"(b3), \
      "+v"(c0),"+v"(c1),"+v"(c2),"+v"(c3), \
      "+v"(d0),"+v"(d1),"+v"(d2),"+v"(d3))

// Split-phase one-shot tree grid barrier (R8-R14 proven RMW mechanism).
__device__ __forceinline__ void gbar_arrive(unsigned* slots){
  __builtin_amdgcn_s_waitcnt(0);
  __syncthreads();
  if (threadIdx.x == 0){
    const unsigned g = blockIdx.x >> 4;
    unsigned prev = __hip_atomic_fetch_add(slots + g*16, 1u, __ATOMIC_RELAXED, __HIP_MEMORY_SCOPE_AGENT);
    if (prev == (unsigned)(GSZ-1))
      __hip_atomic_fetch_add(slots + NGRP*16, 1u, __ATOMIC_RELAXED, __HIP_MEMORY_SCOPE_AGENT);
  }
}
__device__ __forceinline__ void gbar_wait(unsigned* slots){
  if (threadIdx.x == 0){
    while (__hip_atomic_load(slots + NGRP*16, __ATOMIC_RELAXED, __HIP_MEMORY_SCOPE_AGENT) < (unsigned)NGRP)
      __builtin_amdgcn_s_sleep(1);
  }
  __syncthreads();
}

__device__ __forceinline__ float bsum(float v, float* red){
  #pragma unroll
  for (int o = 32; o; o >>= 1) v += __shfl_down(v, o);
  __syncthreads();
  if ((threadIdx.x & 63) == 0) red[threadIdx.x >> 6] = v;
  __syncthreads();
  float s = 0.f;
  #pragma unroll
  for (int w2 = 0; w2 < 8; ++w2) s += red[w2];
  return s;
}
__device__ __forceinline__ float bmax(float v, float* red){
  #pragma unroll
  for (int o = 32; o; o >>= 1) v = fmaxf(v, __shfl_down(v, o));
  __syncthreads();
  if ((threadIdx.x & 63) == 0) red[threadIdx.x >> 6] = v;
  __syncthreads();
  float s = -3.4e38f;
  #pragma unroll
  for (int w2 = 0; w2 < 8; ++w2) s = fmaxf(s, red[w2]);
  return s;
}

#define MFMA16(a,b,c) __builtin_amdgcn_mfma_f32_16x16x32_bf16((a),(b),(c),0,0,0)

// static-panel MFMAs for LSTM0 time tau (cached loads; xstat stable after prologue)
__device__ __forceinline__ void mfma_static(const unsigned short* __restrict__ xs,
    const unsigned short* __restrict__ W0, int w, int row, int kg,
    f32x4& acc0, f32x4& acc1)
{
  for (int c = w; c < NSC; c += 8) {
    const int off = (c << 5) + (kg << 3);
    s16x8 a0 = *(const s16x8*)(xs + (size_t)row*KS + off);
    s16x8 a1 = *(const s16x8*)(xs + (size_t)(row+16)*KS + off);
    s16x8 bw = *(const s16x8*)(W0 + row*W0S + off);
    acc0 = MFMA16(a0, bw, acc0);
    acc1 = MFMA16(a1, bw, acc1);
  }
}

__global__ void __launch_bounds__(NTHR, 1) decoder_kernel(
    const float* __restrict__ enc, const float* __restrict__ audio,
    const float* __restrict__ Wih0, const float* __restrict__ Whh0,
    const float* __restrict__ bih0, const float* __restrict__ bhh0,
    const float* __restrict__ Wih1, const float* __restrict__ Whh1,
    const float* __restrict__ bih1, const float* __restrict__ bhh1,
    const float* __restrict__ Wa, const float* __restrict__ ba,
    const float* __restrict__ Wfc, const float* __restrict__ bfc,
    float* __restrict__ out, float* __restrict__ ws)
{
  cg::grid_group grid = cg::this_grid();
  extern __shared__ char lds[];
  unsigned short* W0  = (unsigned short*)(lds + OFF_W0);
  unsigned short* W1I = (unsigned short*)(lds + OFF_W1I);
  unsigned short* W1H = (unsigned short*)(lds + OFF_W1H);
  float* Gred = (float*)(lds + OFF_GRED);
  float* c0l  = (float*)(lds + OFF_C0);
  float* c1l  = (float*)(lds + OFF_C1);
  float* b0s  = (float*)(lds + OFF_BS);      // combined LSTM0 biases [p*4+g]
  float* b1s  = b0s + 16;                    // combined LSTM1 biases
  float* smw  = Gred;                        // prologue-only aliases
  float* red  = Gred + 256;

  const int blk = blockIdx.x, tid = threadIdx.x;
  const int j = blk;                                // owns h-columns [4j, 4j+4)
  const int w = tid >> 6, lane = tid & 63;
  const int row = lane & 15, kg = lane >> 4;
  const int cblk = j >> 3;                          // chunk holding this block's cols
  const int colw = (j & 7) << 2;                    // col offset within chunk
  // epilogue decomposition of tid: gate g = tid&3, p = (tid>>2)&3, b = tid>>4
  const int eg = tid & 3, ep = (tid >> 2) & 3, eb = tid >> 4;

  unsigned short* xstat = (unsigned short*)((char*)ws + WS_XSTAT);
  unsigned short* h0b   = (unsigned short*)((char*)ws + WS_H0B);   // chunk-major
  unsigned short* h1b   = (unsigned short*)((char*)ws + WS_H1B);   // chunk-major
  float* h1f  = (float*)((char*)ws + WS_H1F);       // 3 parity buffers, [b][k]
  float* esc  = (float*)((char*)ws + WS_ESC);
  float* cm   = (float*)((char*)ws + WS_CST);
  float* cs   = cm + BBAT*EE;
  unsigned* bars = (unsigned*)((char*)ws + WS_BAR);

  // ---- prologue: weights -> LDS bf16; combined biases ----
  for (int i = tid; i < 16*W0S; i += NTHR) {
    int r = i / W0S, k = i - r*W0S;
    int n = (r & 3)*HH + 4*j + (r >> 2);
    float v = 0.f;
    if (k < IN0) v = Wih0[(size_t)n*IN0 + k];
    else if (k >= KS && k < KS + HH) v = Whh0[(size_t)n*HH + (k - KS)];
    W0[i] = f2bf(v);
  }
  for (int i = tid; i < 16*W1STR; i += NTHR) {
    int r = i / W1STR, k = i - r*W1STR;
    int n = (r & 3)*HH + 4*j + (r >> 2);
    W1I[i] = (k < HH) ? f2bf(Wih1[(size_t)n*HH + k]) : (unsigned short)0;
    W1H[i] = (k < HH) ? f2bf(Whh1[(size_t)n*HH + k]) : (unsigned short)0;
  }
  if (tid < 16) {
    int p = tid >> 2, g = tid & 3, n = g*HH + 4*j + p;
    b0s[tid] = bih0[n] + bhh0[n];
    b1s[tid] = bih1[n] + bhh1[n];
  }
  if (tid < 128) { c0l[tid] = 0.f; c1l[tid] = 0.f; }
  for (int i = blk*NTHR + tid; i < 2*BBAT*HH; i += NBLK*NTHR) { h0b[i] = 0; h1b[i] = 0; }
  for (int i = blk*NTHR + tid; i < 3*BBAT*HH; i += NBLK*NTHR) h1f[i] = 0.f;
  for (int i = blk*NTHR + tid; i < (TT+2)*BSLOTS; i += NBLK*NTHR) bars[i] = 0u;
  for (int r2 = blk; r2 < BBAT*SE; r2 += NBLK) {
    float pp = tanhf(enc[(size_t)r2*EE + tid]) * Wa[HH + tid];   // EE == NTHR
    pp = bsum(pp, red);
    if (tid == 0) esc[r2] = pp;
  }
  grid.sync();

  // ---- static softmax + contexts (softmax is h1-invariant; R10-R14 validated) ----
  if (blk < BBAT) {
    const int b = blk;
    float sc = (tid < SE) ? esc[b*SE + tid] : -3.4e38f;
    float mx = bmax(sc, red);
    float ex = (tid < SE) ? expf(sc - mx) : 0.f;
    float den = bsum(ex, red);
    if (tid < SE) smw[tid] = ex / den;
    __syncthreads();
    const int e = tid;                                // EE == NTHR
    float as = 0.f, am = 0.f;
    for (int s = 0; s < SE; ++s) {
      float v = enc[((size_t)b*SE + s)*EE + e];
      as = fmaf(smw[s], v, as);
      am += v;
    }
    cm[b*EE + e] = am * (1.0f/(float)SE);
    cs[b*EE + e] = as;
  }
  grid.sync();

  // ---- fill static panel xstat[t][b][608] = [x_t | ctx | 0] bf16 ----
  for (int t2 = blk; t2 < TT; t2 += NBLK) {
    const float* cx = (t2 == 0) ? cm : cs;
    for (int b = 0; b < BBAT; ++b) {
      for (int k = tid; k < KS; k += NTHR) {
        float v;
        if (k < MM)        v = audio[((size_t)b*TT + t2)*MM + k];
        else if (k < IN0)  v = cx[b*EE + (k - MM)];
        else               v = 0.f;
        xstat[((size_t)t2*BBAT + b)*KS + k] = f2bf(v);
      }
    }
  }
  grid.sync();

  const f32x4 z4 = {0.f,0.f,0.f,0.f};
  f32x4 accP0 = z4, accP1 = z4;

  // ---- pre-loop: LSTM0(0) = static(0) (h0(-1)=0); publish h0(0); B(0) ----
  mfma_static(xstat, W0, w, row, kg, accP0, accP1);
  {
    float* gw = Gred + (w << 10) + row;
    #pragma unroll
    for (int v = 0; v < 4; ++v) {
      gw[(((kg<<2)+v)    << 4)] = accP0[v];
      gw[(((kg<<2)+v+16) << 4)] = accP1[v];
    }
    __syncthreads();
    float s0 = 0.f;
    #pragma unroll
    for (int w8 = 0; w8 < 8; ++w8) s0 += Gred[(w8 << 10) + tid];
    // quad shfl-gather + leader epilogue (plane0 only)
    float ga = s0;
    float gb = __shfl_xor(s0, 1);
    float gc = __shfl_xor(s0, 2);
    float gd = __shfl_xor(gb, 2);
    if (eg == 0) {
      f32x4 bi = *(const f32x4*)(b0s + (ep << 2));
      float gi = ga + bi[0], gf = gb + bi[1], gg = gc + bi[2], go = gd + bi[3];
      float cn = sigmf(gi) * tanhf(gg);   // c_old = 0
      c0l[ep*32 + eb] = cn;
      float hn = sigmf(go) * tanhf(cn);
      float hB = __shfl_xor(hn, 4);
      float hC = __shfl_xor(hn, 8);
      float hD = __shfl_xor(hB, 8);
      if ((tid & 15) == 0) {
        u64 hp = (u64)f2bf(hn) | ((u64)f2bf(hB) << 16) | ((u64)f2bf(hC) << 32) | ((u64)f2bf(hD) << 48);
        st64a(h0b + (cblk << 10) + (eb << 5) + colw, hp);   // h0(0) -> parity buf 0
      }
    }
  }
  gbar_arrive(bars);
  accP0 = z4; accP1 = z4;
  mfma_static(xstat + (size_t)BBAT*KS, W0, w, row, kg, accP0, accP1);  // static(1)
  gbar_wait(bars);

  for (int t = 0; t < TT; ++t) {
    const unsigned short* h0R = h0b + (t&1)*BBAT*HH;           // h0(t), chunk-major
    const unsigned short* h1R = h1b + ((t&1)^1)*BBAT*HH;       // h1(t-1)
    unsigned short* h1W = h1b + (t&1)*BBAT*HH;                 // h1(t)
    unsigned short* h0Wn = h0b + ((t+1)&1)*BBAT*HH;            // h0(t+1)
    float* h1fW = h1f + (size_t)(t % 3)*BBAT*HH;

    // ===== exposed: coalesced coherent loads, 40 MFMA, reduce, shfl epilogues =====
    s16x8 A0h[4], A1h[4], A0g[4], A1g[4];
    {
      const unsigned short* ph0a  = h0R + (row << 5) + (kg << 3);
      const unsigned short* ph0b_ = h0R + ((row+16) << 5) + (kg << 3);
      const unsigned short* ph1a  = h1R + (row << 5) + (kg << 3);
      const unsigned short* ph1b_ = h1R + ((row+16) << 5) + (kg << 3);
      const int o0 = (w << 10), o1 = ((w+8) << 10), o2_ = ((w+16) << 10), o3 = ((w+24) << 10);
      LD4C(A0h[0],A0h[1],A0h[2],A0h[3], ph0a+o0, ph0a+o1, ph0a+o2_, ph0a+o3);
      LD4C(A1h[0],A1h[1],A1h[2],A1h[3], ph0b_+o0, ph0b_+o1, ph0b_+o2_, ph0b_+o3);
      LD4C(A0g[0],A0g[1],A0g[2],A0g[3], ph1a+o0, ph1a+o1, ph1a+o2_, ph1a+o3);
      LD4C(A1g[0],A1g[1],A1g[2],A1g[3], ph1b_+o0, ph1b_+o1, ph1b_+o2_, ph1b_+o3);
      WAIT16(A0h[0],A0h[1],A0h[2],A0h[3], A1h[0],A1h[1],A1h[2],A1h[3],
             A0g[0],A0g[1],A0g[2],A0g[3], A1g[0],A1g[1],A1g[2],A1g[3]);
    }
    f32x4 q0 = z4, q1 = z4;
    #pragma unroll
    for (int i = 0; i < 4; ++i) {
      const int off = ((w + (i << 3)) << 5) + (kg << 3);
      s16x8 b1 = *(const s16x8*)(W1I + row*W1STR + off);
      q0 = MFMA16(A0h[i], b1, q0);
      q1 = MFMA16(A1h[i], b1, q1);
      s16x8 b0 = *(const s16x8*)(W0 + row*W0S + KS + off);
      accP0 = MFMA16(A0h[i], b0, accP0);
      accP1 = MFMA16(A1h[i], b0, accP1);
      s16x8 b2 = *(const s16x8*)(W1H + row*W1STR + off);
      q0 = MFMA16(A0g[i], b2, q0);
      q1 = MFMA16(A1g[i], b2, q1);
    }
    { // two-plane partial write + single sync + per-thread sums
      float* gw = Gred + (w << 10) + row;
      #pragma unroll
      for (int v = 0; v < 4; ++v) {
        gw[(((kg<<2)+v)    << 4)]       = accP0[v];
        gw[(((kg<<2)+v+16) << 4)]       = accP1[v];
        gw[512 + (((kg<<2)+v)    << 4)] = q0[v];
        gw[512 + (((kg<<2)+v+16) << 4)] = q1[v];
      }
      __syncthreads();
      float s0 = 0.f, s1 = 0.f;
      #pragma unroll
      for (int w8 = 0; w8 < 8; ++w8) {
        s0 += Gred[(w8 << 10) + tid];
        s1 += Gred[(w8 << 10) + 512 + tid];
      }
      // quad shfl-gather: gates g0..g3 of (b,p) into the quad leader
      float a0g_ = s0;
      float b0g_ = __shfl_xor(s0, 1);
      float c0g_ = __shfl_xor(s0, 2);
      float d0g_ = __shfl_xor(b0g_, 2);
      float a1g_ = s1;
      float b1g_ = __shfl_xor(s1, 1);
      float c1g_ = __shfl_xor(s1, 2);
      float d1g_ = __shfl_xor(b1g_, 2);
      if (eg == 0) {
        // ---- LSTM1(t) epilogue -> h1(t), h1f ----
        f32x4 bi1 = *(const f32x4*)(b1s + (ep << 2));
        float gi = a1g_ + bi1[0], gf = b1g_ + bi1[1], gg = c1g_ + bi1[2], go = d1g_ + bi1[3];
        float cn1 = sigmf(gf) * c1l[ep*32 + eb] + sigmf(gi) * tanhf(gg);
        c1l[ep*32 + eb] = cn1;
        float hn1 = sigmf(go) * tanhf(cn1);
        // ---- LSTM0(t+1) epilogue -> h0(t+1) ----
        f32x4 bi0 = *(const f32x4*)(b0s + (ep << 2));
        float fi = a0g_ + bi0[0], ff = b0g_ + bi0[1], fg = c0g_ + bi0[2], fo = d0g_ + bi0[3];
        float cn0 = sigmf(ff) * c0l[ep*32 + eb] + sigmf(fi) * tanhf(fg);
        c0l[ep*32 + eb] = cn0;
        float hn0 = sigmf(fo) * tanhf(cn0);
        // cross-quad gather (p = 0..3 of this b) and publish
        float h1B = __shfl_xor(hn1, 4);
        float h1C = __shfl_xor(hn1, 8);
        float h1D = __shfl_xor(h1B, 8);
        float h0B = __shfl_xor(hn0, 4);
        float h0C = __shfl_xor(hn0, 8);
        float h0D = __shfl_xor(h0B, 8);
        if ((tid & 15) == 0) {
          u64 hp1 = (u64)f2bf(hn1) | ((u64)f2bf(h1B) << 16) | ((u64)f2bf(h1C) << 32) | ((u64)f2bf(h1D) << 48);
          st64a(h1W + (cblk << 10) + (eb << 5) + colw, hp1);
          st64a(h1fW + (size_t)eb*HH + 4*j,     pk2f(hn1, h1B));
          st64a(h1fW + (size_t)eb*HH + 4*j + 2, pk2f(h1C, h1D));
          u64 hp0 = (u64)f2bf(hn0) | ((u64)f2bf(h0B) << 16) | ((u64)f2bf(h0C) << 32) | ((u64)f2bf(h0D) << 48);
          st64a(h0Wn + (cblk << 10) + (eb << 5) + colw, hp0);
        }
      }
    }
    gbar_arrive(bars + (size_t)(t+1)*BSLOTS);

    // ===== barrier window: FC pred(t-1) first, then static(t+2) =====
    if (t >= 1) {   // FC(t-1): h1f(t-1) globally published since wait B(t)
      const float* h1fF = h1f + (size_t)((t-1) % 3)*BBAT*HH;
      for (int u = w; u < 10; u += 8) {
        int idx = j*10 + u;
        int b = idx / MM, m = idx - b*MM;
        float pp = 0.f;
        #pragma unroll
        for (int cq = 0; cq < 4; ++cq) {
          float2 h0v = ld2f(h1fF + (size_t)b*HH + cq*256 + lane*4);
          float2 h1v = ld2f(h1fF + (size_t)b*HH + cq*256 + lane*4 + 2);
          float4 wv = *(const float4*)(Wfc + (size_t)m*HH + cq*256 + lane*4);
          pp = fmaf(h0v.x,wv.x, fmaf(h0v.y,wv.y, fmaf(h1v.x,wv.z, fmaf(h1v.y,wv.w, pp))));
        }
        #pragma unroll
        for (int o2 = 32; o2; o2 >>= 1) pp += __shfl_down(pp, o2);
        if (lane == 0) out[((size_t)b*TT + (t-1))*MM + m] = pp + bfc[m];
      }
    }
    accP0 = z4; accP1 = z4;
    if (t + 2 < TT)
      mfma_static(xstat + (size_t)(t+2)*BBAT*KS, W0, w, row, kg, accP0, accP1);
    gbar_wait(bars + (size_t)(t+1)*BSLOTS);
  }

  // ---- epilogue: FC pred(TT-1) ----
  {
    const float* h1fL = h1f + (size_t)((TT-1) % 3)*BBAT*HH;
    for (int u = w; u < 10; u += 8) {
      int idx = j*10 + u;
      int b = idx / MM, m = idx - b*MM;
      float pp = 0.f;
      #pragma unroll
      for (int cq = 0; cq < 4; ++cq) {
        float2 h0v = ld2f(h1fL + (size_t)b*HH + cq*256 + lane*4);
        float2 h1v = ld2f(h1fL + (size_t)b*HH + cq*256 + lane*4 + 2);
        float4 wv = *(const float4*)(Wfc + (size_t)m*HH + cq*256 + lane*4);
        pp = fmaf(h0v.x,wv.x, fmaf(h0v.y,wv.y, fmaf(h1v.x,wv.z, fmaf(h1v.y,wv.w, pp))));
      }
      #pragma unroll
      for (int o2 = 32; o2; o2 >>= 1) pp += __shfl_down(pp, o2);
      if (lane == 0) out[((size_t)b*TT + (TT-1))*MM + m] = pp + bfc[m];
    }
  }
}

extern "C" void kernel_launch(void* const* d_in, const int* in_sizes, int n_in,
                              void* d_out, int out_size, void* d_ws, size_t ws_size,
                              hipStream_t stream) {
  const float* enc  = (const float*)d_in[0];
  const float* audio= (const float*)d_in[1];
  const float* Wih0 = (const float*)d_in[2];
  const float* Whh0 = (const float*)d_in[3];
  const float* bih0 = (const float*)d_in[4];
  const float* bhh0 = (const float*)d_in[5];
  const float* Wih1 = (const float*)d_in[6];
  const float* Whh1 = (const float*)d_in[7];
  const float* bih1 = (const float*)d_in[8];
  const float* bhh1 = (const float*)d_in[9];
  const float* Wa   = (const float*)d_in[10];
  const float* ba   = (const float*)d_in[11];
  const float* Wfc  = (const float*)d_in[12];
  const float* bfc  = (const float*)d_in[13];
  float* out = (float*)d_out;
  float* ws  = (float*)d_ws;

  (void)hipFuncSetAttribute((const void*)decoder_kernel,
                            hipFuncAttributeMaxDynamicSharedMemorySize, LDS_TOTAL);

  void* args[] = { &enc,&audio,&Wih0,&Whh0,&bih0,&bhh0,&Wih1,&Whh1,&bih1,&bhh1,
                   &Wa,&ba,&Wfc,&bfc,&out,&ws };
  hipLaunchCooperativeKernel((const void*)decoder_kernel, dim3(NBLK), dim3(NTHR),
                             args, LDS_TOTAL, stream);
}

// Round 16
// 2846.617 us; speedup vs baseline: 24.6393x; 1.0876x over previous
//
#include <hip/hip_runtime.h>
#include <hip/hip_cooperative_groups.h>

namespace cg = cooperative_groups;

#define BBAT 32
#define SE 200
#define TT 400
#define MM 80
#define EE 512
#define HH 1024
#define IN0 592
#define KS 608         // static panel row: x(80) + ctx(512) + zero pad(16)
#define NSC 19         // static chunks (KS/32)
#define W0S 1640       // W0 LDS row stride (608 static + 1024 hh + 8 pad)
#define W1STR 1032
#define NBLK 256
#define NTHR 512

typedef __attribute__((ext_vector_type(4))) float f32x4;
typedef __attribute__((ext_vector_type(8))) short s16x8;
typedef unsigned long long u64;

// LDS offsets (bytes)
#define OFF_W0    0          // 16*1640*2 = 52480
#define OFF_W1I   52480      // 33024
#define OFF_W1H   85504      // 33024
#define OFF_GRED  118528     // 8 waves x 1024 f32 = 32768 (2 planes)
#define OFF_C0    151296     // 512
#define OFF_C1    151808     // 512
#define OFF_BS    152320     // b0s[16] + b1s[16] f32 = 128
#define LDS_TOTAL 152448
// prologue-only smw/red alias the GRED region (no temporal overlap)

// ws offsets (bytes)
// h0b/h1b are CHUNK-MAJOR: [2 parity][32 chunk][32 batch][32 elem] bf16
#define WS_XSTAT 0                 // 400*32*608*2 = 15,564,800
#define WS_H0B   15564800          // 131,072
#define WS_H1B   15696896          // 131,072
#define WS_H1F   15828992          // 3*32*1024*4 = 393,216 (triple buffer, [b][k] f32)
#define WS_ESC   16222208          // 25,600
#define WS_CST   16247808          // 131,072 (cm | cs)
#define WS_FLG   16378880          // dataflow flags: 2*(TT+1)*32 x 16B = 410,624
// flag layout (u32 units): h0 epoch t chunk c -> flg[(t*32+c)*4]
//                          h1 epoch t chunk c -> flg[H1OFFU + (t*32+c)*4]
#define H1OFFU   ((TT+1)*32*4)
#define FLGN     (2*(TT+1)*32*4)

__device__ __forceinline__ float sigmf(float x){ return 1.0f/(1.0f+expf(-x)); }

__device__ __forceinline__ unsigned short f2bf(float v){
  unsigned int u = __float_as_uint(v);
  u += 0x7fffu + ((u >> 16) & 1u);
  return (unsigned short)(u >> 16);
}

// ---- agent-scope coherent accessors; RELAXED => no cache-maintenance ops ----
__device__ __forceinline__ void st64a(void* p, u64 v){
  __hip_atomic_store((u64*)p, v, __ATOMIC_RELAXED, __HIP_MEMORY_SCOPE_AGENT);
}
__device__ __forceinline__ u64 ld64a(const void* p){
  return __hip_atomic_load((const u64*)p, __ATOMIC_RELAXED, __HIP_MEMORY_SCOPE_AGENT);
}
__device__ __forceinline__ float2 ld2f(const float* p){
  u64 q = ld64a(p);
  float2 r; r.x = __uint_as_float((unsigned)q); r.y = __uint_as_float((unsigned)(q >> 32));
  return r;
}
__device__ __forceinline__ u64 pk2f(float a, float b){
  return ((u64)__float_as_uint(b) << 32) | (u64)__float_as_uint(a);
}

// 4x 16B coherent loads (sc0 sc1 -> coherence point). Chunk-major: each wave
// spans 1KB contiguous per instruction (8x128B lines).
#define LD4C(d0,d1,d2,d3,p0,p1,p2,p3) \
  asm volatile("global_load_dwordx4 %0, %4, off sc0 sc1\n\t" \
               "global_load_dwordx4 %1, %5, off sc0 sc1\n\t" \
               "global_load_dwordx4 %2, %6, off sc0 sc1\n\t" \
               "global_load_dwordx4 %3, %7, off sc0 sc1" \
               : "=&v"(d0), "=&v"(d1), "=&v"(d2), "=&v"(d3) \
               : "v"(p0), "v"(p1), "v"(p2), "v"(p3))

// Single waitcnt tying all 16 fragments as in-outs (anti-hoist: rule #18).
#define WAIT16(a0,a1,a2,a3,b0,b1,b2,b3,c0,c1,c2,c3,d0,d1,d2,d3) \
  asm volatile("s_waitcnt vmcnt(0)" \
    : "+v"(a0),"+v"(a1),"+v"(a2),"+v"(a3), \
      "+v"(b0),"+v"(b1),"+v"(b2),"+v"(b3), \
      "+v"(c0),"+v"(c1),"+v"(c2),"+v"(c3), \
      "+v"(d0),"+v"(d1),"+v"(d2),"+v"(d3))

__device__ __forceinline__ float bsum(float v, float* red){
  #pragma unroll
  for (int o = 32; o; o >>= 1) v += __shfl_down(v, o);
  __syncthreads();
  if ((threadIdx.x & 63) == 0) red[threadIdx.x >> 6] = v;
  __syncthreads();
  float s = 0.f;
  #pragma unroll
  for (int w2 = 0; w2 < 8; ++w2) s += red[w2];
  return s;
}
__device__ __forceinline__ float bmax(float v, float* red){
  #pragma unroll
  for (int o = 32; o; o >>= 1) v = fmaxf(v, __shfl_down(v, o));
  __syncthreads();
  if ((threadIdx.x & 63) == 0) red[threadIdx.x >> 6] = v;
  __syncthreads();
  float s = -3.4e38f;
  #pragma unroll
  for (int w2 = 0; w2 < 8; ++w2) s = fmaxf(s, red[w2]);
  return s;
}

#define MFMA16(a,b,c) __builtin_amdgcn_mfma_f32_16x16x32_bf16((a),(b),(c),0,0,0)

// static-panel MFMAs for LSTM0 time tau (cached loads; xstat stable after prologue)
__device__ __forceinline__ void mfma_static(const unsigned short* __restrict__ xs,
    const unsigned short* __restrict__ W0, int w, int row, int kg,
    f32x4& acc0, f32x4& acc1)
{
  for (int c = w; c < NSC; c += 8) {
    const int off = (c << 5) + (kg << 3);
    s16x8 a0 = *(const s16x8*)(xs + (size_t)row*KS + off);
    s16x8 a1 = *(const s16x8*)(xs + (size_t)(row+16)*KS + off);
    s16x8 bw = *(const s16x8*)(W0 + row*W0S + off);
    acc0 = MFMA16(a0, bw, acc0);
    acc1 = MFMA16(a1, bw, acc1);
  }
}

__global__ void __launch_bounds__(NTHR, 1) decoder_kernel(
    const float* __restrict__ enc, const float* __restrict__ audio,
    const float* __restrict__ Wih0, const float* __restrict__ Whh0,
    const float* __restrict__ bih0, const float* __restrict__ bhh0,
    const float* __restrict__ Wih1, const float* __restrict__ Whh1,
    const float* __restrict__ bih1, const float* __restrict__ bhh1,
    const float* __restrict__ Wa, const float* __restrict__ ba,
    const float* __restrict__ Wfc, const float* __restrict__ bfc,
    float* __restrict__ out, float* __restrict__ ws)
{
  cg::grid_group grid = cg::this_grid();
  extern __shared__ char lds[];
  unsigned short* W0  = (unsigned short*)(lds + OFF_W0);
  unsigned short* W1I = (unsigned short*)(lds + OFF_W1I);
  unsigned short* W1H = (unsigned short*)(lds + OFF_W1H);
  float* Gred = (float*)(lds + OFF_GRED);
  float* c0l  = (float*)(lds + OFF_C0);
  float* c1l  = (float*)(lds + OFF_C1);
  float* b0s  = (float*)(lds + OFF_BS);      // combined LSTM0 biases [p*4+g]
  float* b1s  = b0s + 16;                    // combined LSTM1 biases
  float* smw  = Gred;                        // prologue-only aliases
  float* red  = Gred + 256;

  const int blk = blockIdx.x, tid = threadIdx.x;
  const int j = blk;                                // owns h-columns [4j, 4j+4)
  const int w = tid >> 6, lane = tid & 63;
  const int row = lane & 15, kg = lane >> 4;
  const int cblk = j >> 3;                          // chunk holding this block's cols
  const int colw = (j & 7) << 2;                    // col offset within chunk
  const int eg = tid & 3, ep = (tid >> 2) & 3, eb = tid >> 4;

  unsigned short* xstat = (unsigned short*)((char*)ws + WS_XSTAT);
  unsigned short* h0b   = (unsigned short*)((char*)ws + WS_H0B);   // chunk-major
  unsigned short* h1b   = (unsigned short*)((char*)ws + WS_H1B);   // chunk-major
  float* h1f  = (float*)((char*)ws + WS_H1F);       // 3 parity buffers, [b][k]
  float* esc  = (float*)((char*)ws + WS_ESC);
  float* cm   = (float*)((char*)ws + WS_CST);
  float* cs   = cm + BBAT*EE;
  unsigned* flg = (unsigned*)((char*)ws + WS_FLG);  // dataflow flags

  // ---- prologue: weights -> LDS bf16; combined biases ----
  for (int i = tid; i < 16*W0S; i += NTHR) {
    int r = i / W0S, k = i - r*W0S;
    int n = (r & 3)*HH + 4*j + (r >> 2);
    float v = 0.f;
    if (k < IN0) v = Wih0[(size_t)n*IN0 + k];
    else if (k >= KS && k < KS + HH) v = Whh0[(size_t)n*HH + (k - KS)];
    W0[i] = f2bf(v);
  }
  for (int i = tid; i < 16*W1STR; i += NTHR) {
    int r = i / W1STR, k = i - r*W1STR;
    int n = (r & 3)*HH + 4*j + (r >> 2);
    W1I[i] = (k < HH) ? f2bf(Wih1[(size_t)n*HH + k]) : (unsigned short)0;
    W1H[i] = (k < HH) ? f2bf(Whh1[(size_t)n*HH + k]) : (unsigned short)0;
  }
  if (tid < 16) {
    int p = tid >> 2, g = tid & 3, n = g*HH + 4*j + p;
    b0s[tid] = bih0[n] + bhh0[n];
    b1s[tid] = bih1[n] + bhh1[n];
  }
  if (tid < 128) { c0l[tid] = 0.f; c1l[tid] = 0.f; }
  for (int i = blk*NTHR + tid; i < 2*BBAT*HH; i += NBLK*NTHR) { h0b[i] = 0; h1b[i] = 0; }
  for (int i = blk*NTHR + tid; i < 3*BBAT*HH; i += NBLK*NTHR) h1f[i] = 0.f;
  for (int i = blk*NTHR + tid; i < FLGN; i += NBLK*NTHR) flg[i] = 0u;
  for (int r2 = blk; r2 < BBAT*SE; r2 += NBLK) {
    float pp = tanhf(enc[(size_t)r2*EE + tid]) * Wa[HH + tid];   // EE == NTHR
    pp = bsum(pp, red);
    if (tid == 0) esc[r2] = pp;
  }
  grid.sync();

  // ---- static softmax + contexts (softmax is h1-invariant; R10-R15 validated) ----
  if (blk < BBAT) {
    const int b = blk;
    float sc = (tid < SE) ? esc[b*SE + tid] : -3.4e38f;
    float mx = bmax(sc, red);
    float ex = (tid < SE) ? expf(sc - mx) : 0.f;
    float den = bsum(ex, red);
    if (tid < SE) smw[tid] = ex / den;
    __syncthreads();
    const int e = tid;                                // EE == NTHR
    float as = 0.f, am = 0.f;
    for (int s = 0; s < SE; ++s) {
      float v = enc[((size_t)b*SE + s)*EE + e];
      as = fmaf(smw[s], v, as);
      am += v;
    }
    cm[b*EE + e] = am * (1.0f/(float)SE);
    cs[b*EE + e] = as;
  }
  grid.sync();

  // ---- fill static panel xstat[t][b][608] = [x_t | ctx | 0] bf16 ----
  for (int t2 = blk; t2 < TT; t2 += NBLK) {
    const float* cx = (t2 == 0) ? cm : cs;
    for (int b = 0; b < BBAT; ++b) {
      for (int k = tid; k < KS; k += NTHR) {
        float v;
        if (k < MM)        v = audio[((size_t)b*TT + t2)*MM + k];
        else if (k < IN0)  v = cx[b*EE + (k - MM)];
        else               v = 0.f;
        xstat[((size_t)t2*BBAT + b)*KS + k] = f2bf(v);
      }
    }
  }
  grid.sync();   // covers flag zeroing + xstat + initial h-buffers

  const f32x4 z4 = {0.f,0.f,0.f,0.f};
  f32x4 accP0 = z4, accP1 = z4;

  // ---- pre-loop: LSTM0(0) = static(0) (h0(-1)=0); publish h0(0) + flag ----
  mfma_static(xstat, W0, w, row, kg, accP0, accP1);
  {
    float* gw = Gred + (w << 10) + row;
    #pragma unroll
    for (int v = 0; v < 4; ++v) {
      gw[(((kg<<2)+v)    << 4)] = accP0[v];
      gw[(((kg<<2)+v+16) << 4)] = accP1[v];
    }
    __syncthreads();
    float s0 = 0.f;
    #pragma unroll
    for (int w8 = 0; w8 < 8; ++w8) s0 += Gred[(w8 << 10) + tid];
    float ga = s0;
    float gb = __shfl_xor(s0, 1);
    float gc = __shfl_xor(s0, 2);
    float gd = __shfl_xor(gb, 2);
    if (eg == 0) {
      f32x4 bi = *(const f32x4*)(b0s + (ep << 2));
      float gi = ga + bi[0], gf = gb + bi[1], gg = gc + bi[2], go = gd + bi[3];
      (void)gf;
      float cn = sigmf(gi) * tanhf(gg);   // c_old = 0
      c0l[ep*32 + eb] = cn;
      float hn = sigmf(go) * tanhf(cn);
      float hB = __shfl_xor(hn, 4);
      float hC = __shfl_xor(hn, 8);
      float hD = __shfl_xor(hB, 8);
      if ((tid & 15) == 0) {
        u64 hp = (u64)f2bf(hn) | ((u64)f2bf(hB) << 16) | ((u64)f2bf(hC) << 32) | ((u64)f2bf(hD) << 48);
        st64a(h0b + (cblk << 10) + (eb << 5) + colw, hp);   // h0(0) -> parity buf 0
      }
    }
  }
  __builtin_amdgcn_s_waitcnt(0);
  __syncthreads();
  if (tid == 0)
    __hip_atomic_fetch_add(flg + (size_t)cblk*4, 1u, __ATOMIC_RELAXED, __HIP_MEMORY_SCOPE_AGENT);
  accP0 = z4; accP1 = z4;
  mfma_static(xstat + (size_t)BBAT*KS, W0, w, row, kg, accP0, accP1);  // static(1)

  for (int t = 0; t < TT; ++t) {
    const unsigned short* h0R = h0b + (t&1)*BBAT*HH;           // h0(t), chunk-major
    const unsigned short* h1R = h1b + ((t&1)^1)*BBAT*HH;       // h1(t-1)
    unsigned short* h1W = h1b + (t&1)*BBAT*HH;                 // h1(t)
    unsigned short* h0Wn = h0b + ((t+1)&1)*BBAT*HH;            // h0(t+1)
    float* h1fW = h1f + (size_t)(t % 3)*BBAT*HH;

    // ===== per-wave dataflow poll: wave w needs chunks {w,w+8,w+16,w+24} =====
    {
      const int pc = w + ((lane & 3) << 3);
      if (lane < 4) {
        unsigned* fp = flg + ((size_t)t*32 + pc)*4;
        while (__hip_atomic_load(fp, __ATOMIC_RELAXED, __HIP_MEMORY_SCOPE_AGENT) < 8u)
          __builtin_amdgcn_s_sleep(1);
      } else if (lane < 8 && t > 0) {
        unsigned* fp = flg + H1OFFU + ((size_t)(t-1)*32 + pc)*4;
        while (__hip_atomic_load(fp, __ATOMIC_RELAXED, __HIP_MEMORY_SCOPE_AGENT) < 8u)
          __builtin_amdgcn_s_sleep(1);
      }
      asm volatile("" ::: "memory");   // loads below must not hoist above polls
    }

    // ===== coalesced coherent loads, 40 MFMA, reduce, shfl epilogues =====
    s16x8 A0h[4], A1h[4], A0g[4], A1g[4];
    {
      const unsigned short* ph0a  = h0R + (row << 5) + (kg << 3);
      const unsigned short* ph0b_ = h0R + ((row+16) << 5) + (kg << 3);
      const unsigned short* ph1a  = h1R + (row << 5) + (kg << 3);
      const unsigned short* ph1b_ = h1R + ((row+16) << 5) + (kg << 3);
      const int o0 = (w << 10), o1 = ((w+8) << 10), o2_ = ((w+16) << 10), o3 = ((w+24) << 10);
      LD4C(A0h[0],A0h[1],A0h[2],A0h[3], ph0a+o0, ph0a+o1, ph0a+o2_, ph0a+o3);
      LD4C(A1h[0],A1h[1],A1h[2],A1h[3], ph0b_+o0, ph0b_+o1, ph0b_+o2_, ph0b_+o3);
      LD4C(A0g[0],A0g[1],A0g[2],A0g[3], ph1a+o0, ph1a+o1, ph1a+o2_, ph1a+o3);
      LD4C(A1g[0],A1g[1],A1g[2],A1g[3], ph1b_+o0, ph1b_+o1, ph1b_+o2_, ph1b_+o3);
      WAIT16(A0h[0],A0h[1],A0h[2],A0h[3], A1h[0],A1h[1],A1h[2],A1h[3],
             A0g[0],A0g[1],A0g[2],A0g[3], A1g[0],A1g[1],A1g[2],A1g[3]);
    }
    f32x4 q0 = z4, q1 = z4;
    #pragma unroll
    for (int i = 0; i < 4; ++i) {
      const int off = ((w + (i << 3)) << 5) + (kg << 3);
      s16x8 b1 = *(const s16x8*)(W1I + row*W1STR + off);
      q0 = MFMA16(A0h[i], b1, q0);
      q1 = MFMA16(A1h[i], b1, q1);
      s16x8 b0 = *(const s16x8*)(W0 + row*W0S + KS + off);
      accP0 = MFMA16(A0h[i], b0, accP0);
      accP1 = MFMA16(A1h[i], b0, accP1);
      s16x8 b2 = *(const s16x8*)(W1H + row*W1STR + off);
      q0 = MFMA16(A0g[i], b2, q0);
      q1 = MFMA16(A1g[i], b2, q1);
    }
    { // two-plane partial write + single sync + per-thread sums
      float* gw = Gred + (w << 10) + row;
      #pragma unroll
      for (int v = 0; v < 4; ++v) {
        gw[(((kg<<2)+v)    << 4)]       = accP0[v];
        gw[(((kg<<2)+v+16) << 4)]       = accP1[v];
        gw[512 + (((kg<<2)+v)    << 4)] = q0[v];
        gw[512 + (((kg<<2)+v+16) << 4)] = q1[v];
      }
      __syncthreads();
      float s0 = 0.f, s1 = 0.f;
      #pragma unroll
      for (int w8 = 0; w8 < 8; ++w8) {
        s0 += Gred[(w8 << 10) + tid];
        s1 += Gred[(w8 << 10) + 512 + tid];
      }
      float a0g_ = s0;
      float b0g_ = __shfl_xor(s0, 1);
      float c0g_ = __shfl_xor(s0, 2);
      float d0g_ = __shfl_xor(b0g_, 2);
      float a1g_ = s1;
      float b1g_ = __shfl_xor(s1, 1);
      float c1g_ = __shfl_xor(s1, 2);
      float d1g_ = __shfl_xor(b1g_, 2);
      if (eg == 0) {
        // ---- LSTM1(t) epilogue -> h1(t), h1f ----
        f32x4 bi1 = *(const f32x4*)(b1s + (ep << 2));
        float gi = a1g_ + bi1[0], gf = b1g_ + bi1[1], gg = c1g_ + bi1[2], go = d1g_ + bi1[3];
        float cn1 = sigmf(gf) * c1l[ep*32 + eb] + sigmf(gi) * tanhf(gg);
        c1l[ep*32 + eb] = cn1;
        float hn1 = sigmf(go) * tanhf(cn1);
        // ---- LSTM0(t+1) epilogue -> h0(t+1) ----
        f32x4 bi0 = *(const f32x4*)(b0s + (ep << 2));
        float fi = a0g_ + bi0[0], ff = b0g_ + bi0[1], fg = c0g_ + bi0[2], fo = d0g_ + bi0[3];
        float cn0 = sigmf(ff) * c0l[ep*32 + eb] + sigmf(fi) * tanhf(fg);
        c0l[ep*32 + eb] = cn0;
        float hn0 = sigmf(fo) * tanhf(cn0);
        float h1B = __shfl_xor(hn1, 4);
        float h1C = __shfl_xor(hn1, 8);
        float h1D = __shfl_xor(h1B, 8);
        float h0B = __shfl_xor(hn0, 4);
        float h0C = __shfl_xor(hn0, 8);
        float h0D = __shfl_xor(h0B, 8);
        if ((tid & 15) == 0) {
          u64 hp1 = (u64)f2bf(hn1) | ((u64)f2bf(h1B) << 16) | ((u64)f2bf(h1C) << 32) | ((u64)f2bf(h1D) << 48);
          st64a(h1W + (cblk << 10) + (eb << 5) + colw, hp1);
          st64a(h1fW + (size_t)eb*HH + 4*j,     pk2f(hn1, h1B));
          st64a(h1fW + (size_t)eb*HH + 4*j + 2, pk2f(h1C, h1D));
          u64 hp0 = (u64)f2bf(hn0) | ((u64)f2bf(h0B) << 16) | ((u64)f2bf(h0C) << 32) | ((u64)f2bf(h0D) << 48);
          st64a(h0Wn + (cblk << 10) + (eb << 5) + colw, hp0);
        }
      }
    }
    // ===== publish: all stores drained, then post both chunk flags =====
    __builtin_amdgcn_s_waitcnt(0);
    __syncthreads();
    if (tid == 0) {
      __hip_atomic_fetch_add(flg + ((size_t)(t+1)*32 + cblk)*4, 1u, __ATOMIC_RELAXED, __HIP_MEMORY_SCOPE_AGENT);
      __hip_atomic_fetch_add(flg + H1OFFU + ((size_t)t*32 + cblk)*4, 1u, __ATOMIC_RELAXED, __HIP_MEMORY_SCOPE_AGENT);
    }

    // ===== window: FC pred(t-1), then static(t+2) =====
    if (t >= 1) {   // h1f(t-1): this block observed all h1[t-1] flags before its reduce
      const float* h1fF = h1f + (size_t)((t-1) % 3)*BBAT*HH;
      for (int u = w; u < 10; u += 8) {
        int idx = j*10 + u;
        int b = idx / MM, m = idx - b*MM;
        float pp = 0.f;
        #pragma unroll
        for (int cq = 0; cq < 4; ++cq) {
          float2 h0v = ld2f(h1fF + (size_t)b*HH + cq*256 + lane*4);
          float2 h1v = ld2f(h1fF + (size_t)b*HH + cq*256 + lane*4 + 2);
          float4 wv = *(const float4*)(Wfc + (size_t)m*HH + cq*256 + lane*4);
          pp = fmaf(h0v.x,wv.x, fmaf(h0v.y,wv.y, fmaf(h1v.x,wv.z, fmaf(h1v.y,wv.w, pp))));
        }
        #pragma unroll
        for (int o2 = 32; o2; o2 >>= 1) pp += __shfl_down(pp, o2);
        if (lane == 0) out[((size_t)b*TT + (t-1))*MM + m] = pp + bfc[m];
      }
    }
    accP0 = z4; accP1 = z4;
    if (t + 2 < TT)
      mfma_static(xstat + (size_t)(t+2)*BBAT*KS, W0, w, row, kg, accP0, accP1);
  }

  // ---- final: wait for all h1(TT-1) chunks, then FC pred(TT-1) ----
  if (tid < 32) {
    unsigned* fp = flg + H1OFFU + ((size_t)(TT-1)*32 + tid)*4;
    while (__hip_atomic_load(fp, __ATOMIC_RELAXED, __HIP_MEMORY_SCOPE_AGENT) < 8u)
      __builtin_amdgcn_s_sleep(1);
  }
  __syncthreads();
  {
    const float* h1fL = h1f + (size_t)((TT-1) % 3)*BBAT*HH;
    for (int u = w; u < 10; u += 8) {
      int idx = j*10 + u;
      int b = idx / MM, m = idx - b*MM;
      float pp = 0.f;
      #pragma unroll
      for (int cq = 0; cq < 4; ++cq) {
        float2 h0v = ld2f(h1fL + (size_t)b*HH + cq*256 + lane*4);
        float2 h1v = ld2f(h1fL + (size_t)b*HH + cq*256 + lane*4 + 2);
        float4 wv = *(const float4*)(Wfc + (size_t)m*HH + cq*256 + lane*4);
        pp = fmaf(h0v.x,wv.x, fmaf(h0v.y,wv.y, fmaf(h1v.x,wv.z, fmaf(h1v.y,wv.w, pp))));
      }
      #pragma unroll
      for (int o2 = 32; o2; o2 >>= 1) pp += __shfl_down(pp, o2);
      if (lane == 0) out[((size_t)b*TT + (TT-1))*MM + m] = pp + bfc[m];
    }
  }
}

extern "C" void kernel_launch(void* const* d_in, const int* in_sizes, int n_in,
                              void* d_out, int out_size, void* d_ws, size_t ws_size,
                              hipStream_t stream) {
  const float* enc  = (const float*)d_in[0];
  const float* audio= (const float*)d_in[1];
  const float* Wih0 = (const float*)d_in[2];
  const float* Whh0 = (const float*)d_in[3];
  const float* bih0 = (const float*)d_in[4];
  const float* bhh0 = (const float*)d_in[5];
  const float* Wih1 = (const float*)d_in[6];
  const float* Whh1 = (const float*)d_in[7];
  const float* bih1 = (const float*)d_in[8];
  const float* bhh1 = (const float*)d_in[9];
  const float* Wa   = (const float*)d_in[10];
  const float* ba   = (const float*)d_in[11];
  const float* Wfc  = (const float*)d_in[12];
  const float* bfc  = (const float*)d_in[13];
  float* out = (float*)d_out;
  float* ws  = (float*)d_ws;

  (void)hipFuncSetAttribute((const void*)decoder_kernel,
                            hipFuncAttributeMaxDynamicSharedMemorySize, LDS_TOTAL);

  void* args[] = { &enc,&audio,&Wih0,&Whh0,&bih0,&bhh0,&Wih1,&Whh1,&bih1,&bhh1,
                   &Wa,&ba,&Wfc,&bfc,&out,&ws };
  hipLaunchCooperativeKernel((const void*)decoder_kernel, dim3(NBLK), dim3(NTHR),
                             args, LDS_TOTAL, stream);
}